// Round 15
// baseline (741.976 us; speedup 1.0000x reference)
//
#include <hip/hip_runtime.h>
#include <hip/hip_bf16.h>

namespace {

constexpr int Dd = 1152;

typedef __attribute__((ext_vector_type(8))) short bf16x8;
typedef __attribute__((ext_vector_type(4))) float f32x4;

__device__ __forceinline__ void gload_lds16(const void* g, void* l) {
  __builtin_amdgcn_global_load_lds(
      (const __attribute__((address_space(1))) void*)g,
      (__attribute__((address_space(3))) void*)l, 16, 0, 0);
}

__device__ __forceinline__ float gelu_f(float x) {
  float x3 = x * x * x;
  float z2 = 1.5957691216057308f * (x + 0.044715f * x3);
  float e = __expf(fminf(z2, 30.0f));
  return x * e / (e + 1.0f);
}

// ---------------- fused norm + window scoring ----------------
__global__ __launch_bounds__(256) void normwin_kernel(const float* __restrict__ x,
    const float* __restrict__ noise, float* __restrict__ inv,
    __hip_bfloat16* __restrict__ xnh, __hip_bfloat16* __restrict__ xnl,
    int* __restrict__ dsti, int* __restrict__ srci) {
  const int gidx = blockIdx.x;  // b*256 + w
  const int b = gidx >> 8, w = gidx & 255;
  const int wy = w >> 4, wx = w & 15;
  const int t0 = wy * 64 + wx * 2;
  const int wid = threadIdx.x >> 6, lane = threadIdx.x & 63;
  const int tok = t0 + (wid >> 1) * 32 + (wid & 1);
  const int row = (b << 10) + tok;

  const float2* xr = (const float2*)(x + (size_t)row * Dd);
  float2 v[9];
  float s = 0.f;
  #pragma unroll
  for (int e = 0; e < 9; ++e) {
    v[e] = xr[lane + 64 * e];
    s += v[e].x * v[e].x + v[e].y * v[e].y;
  }
  #pragma unroll
  for (int m = 1; m < 64; m <<= 1) s += __shfl_xor(s, m);
  float iv = 1.0f / (sqrtf(s) + 1e-6f);
  if (lane == 0) inv[row] = iv;

  __shared__ float2 xns[4][576];
  ushort2* ph = (ushort2*)(xnh + (size_t)row * Dd);
  ushort2* pl = (ushort2*)(xnl + (size_t)row * Dd);
  #pragma unroll
  for (int e = 0; e < 9; ++e) {
    float ax = v[e].x * iv, ay = v[e].y * iv;
    xns[wid][lane + 64 * e] = make_float2(ax, ay);
    __hip_bfloat16 hx = __float2bfloat16(ax), hy = __float2bfloat16(ay);
    __hip_bfloat16 lx = __float2bfloat16(ax - __bfloat162float(hx));
    __hip_bfloat16 ly = __float2bfloat16(ay - __bfloat162float(hy));
    ph[lane + 64 * e] = make_ushort2(*(ushort*)&hx, *(ushort*)&hy);
    pl[lane + 64 * e] = make_ushort2(*(ushort*)&lx, *(ushort*)&ly);
  }
  __syncthreads();

  float dot = 0.f;
  #pragma unroll
  for (int e = 0; e < 9; ++e) {
    int i = lane + 64 * e;
    float2 a0 = xns[0][i], a1 = xns[1][i], a2 = xns[2][i], a3 = xns[3][i];
    float sx = a0.x + a1.x + a2.x + a3.x;
    float sy = a0.y + a1.y + a2.y + a3.y;
    dot += (v[e].x * iv) * sx + (v[e].y * iv) * sy;
  }
  #pragma unroll
  for (int m = 1; m < 64; m <<= 1) dot += __shfl_xor(dot, m);
  __shared__ float dots[4];
  if (lane == 0) dots[wid] = dot;
  __syncthreads();
  if (threadIdx.x == 0) {
    float best = -1e30f; int bj = 0;
    #pragma unroll
    for (int j = 0; j < 4; ++j) {
      float sc = 0.25f * dots[j] + 0.1f * noise[(size_t)gidx * 4 + j];
      if (sc > best) { best = sc; bj = j; }  // strict > = first-max
    }
    int tk[4] = {t0, t0 + 1, t0 + 32, t0 + 33};
    dsti[b * 256 + w] = tk[bj];
    int m = 0;
    #pragma unroll
    for (int j = 0; j < 4; ++j) if (j != bj) srci[b * 768 + w * 3 + (m++)] = tk[j];
  }
}

// ---------------- sim GEMM (split-bf16 MFMA): per-src (max, argmax) over 256 dst ----------
__global__ __launch_bounds__(256) void simgemm_kernel(
    const __hip_bfloat16* __restrict__ xnh, const __hip_bfloat16* __restrict__ xnl,
    const int* __restrict__ dsti, const int* __restrict__ srci,
    float* __restrict__ mx, int* __restrict__ best) {
  int b = blockIdx.x / 12;
  int m0 = (blockIdx.x % 12) * 64;
  __shared__ __align__(16) __hip_bfloat16 AsH[2][64 * 32];
  __shared__ __align__(16) __hip_bfloat16 AsL[2][64 * 32];
  __shared__ __align__(16) __hip_bfloat16 BsH[2][256 * 32];
  __shared__ __align__(16) __hip_bfloat16 BsL[2][256 * 32];
  const int tid = threadIdx.x, wid = tid >> 6, lane = tid & 63;
  const int g = lane >> 4, lr = lane & 15;

  const int slotRow = tid >> 2;        // 0..63
  const int colByte = (((tid & 3) ^ ((tid >> 3) & 3)) << 4);
  size_t aRow = (size_t)((b << 10) + srci[b * 768 + m0 + slotRow]) * Dd;
  size_t bRow[4];
  #pragma unroll
  for (int p = 0; p < 4; ++p)
    bRow[p] = (size_t)((b << 10) + dsti[b * 256 + p * 64 + slotRow]) * Dd;
  const char* xh = (const char*)xnh;
  const char* xl = (const char*)xnl;

  auto stage = [&](int buf, int k0) {
    size_t ka = (aRow + k0) * 2 + colByte;
    gload_lds16(xh + ka, (char*)AsH + buf * 4096 + wid * 1024);
    gload_lds16(xl + ka, (char*)AsL + buf * 4096 + wid * 1024);
    #pragma unroll
    for (int p = 0; p < 4; ++p) {
      size_t kb = (bRow[p] + k0) * 2 + colByte;
      gload_lds16(xh + kb, (char*)BsH + buf * 16384 + p * 4096 + wid * 1024);
      gload_lds16(xl + kb, (char*)BsL + buf * 16384 + p * 4096 + wid * 1024);
    }
  };

  f32x4 hh[16], hx[16];
  const f32x4 zf = {0.f, 0.f, 0.f, 0.f};
  #pragma unroll
  for (int nf = 0; nf < 16; ++nf) { hh[nf] = zf; hx[nf] = zf; }

  const int roff = ((g ^ ((lr >> 1) & 3)) << 3);
  stage(0, 0);
  asm volatile("s_waitcnt vmcnt(0)" ::: "memory");
  __syncthreads();
  int buf = 0;
  for (int ks = 0; ks < 36; ++ks) {
    if (ks + 1 < 36) stage(buf ^ 1, (ks + 1) * 32);
    bf16x8 ah = *(const bf16x8*)&AsH[buf][(wid * 16 + lr) * 32 + roff];
    bf16x8 al = *(const bf16x8*)&AsL[buf][(wid * 16 + lr) * 32 + roff];
    #pragma unroll
    for (int nf = 0; nf < 16; ++nf) {
      bf16x8 bh = *(const bf16x8*)&BsH[buf][(nf * 16 + lr) * 32 + roff];
      bf16x8 bl = *(const bf16x8*)&BsL[buf][(nf * 16 + lr) * 32 + roff];
      hh[nf] = __builtin_amdgcn_mfma_f32_16x16x32_bf16(ah, bh, hh[nf], 0, 0, 0);
      hx[nf] = __builtin_amdgcn_mfma_f32_16x16x32_bf16(ah, bl, hx[nf], 0, 0, 0);
      hx[nf] = __builtin_amdgcn_mfma_f32_16x16x32_bf16(al, bh, hx[nf], 0, 0, 0);
    }
    asm volatile("s_waitcnt vmcnt(0)" ::: "memory");
    __syncthreads();
    buf ^= 1;
  }

  #pragma unroll
  for (int j = 0; j < 4; ++j) {
    float bv = -1e30f; int bi = 0;
    #pragma unroll
    for (int nf = 0; nf < 16; ++nf) {
      float v = hh[nf][j] + hx[nf][j];
      if (v > bv) { bv = v; bi = nf * 16 + lr; }
    }
    #pragma unroll
    for (int m = 1; m < 16; m <<= 1) {
      float ov = __shfl_xor(bv, m);
      int oi = __shfl_xor(bi, m);
      if (ov > bv || (ov == bv && oi < bi)) { bv = ov; bi = oi; }
    }
    if (lr == 0) {
      int row = m0 + wid * 16 + g * 4 + j;
      mx[b * 768 + row] = bv;
      best[b * 768 + row] = bi;
    }
  }
}

// ---------------- rank (stable argsort of -mx) -> keep_token + src_row ----------------
__global__ __launch_bounds__(256) void rank_kernel(const float* __restrict__ mx,
    const int* __restrict__ best, const int* __restrict__ dsti,
    const int* __restrict__ srci, int* __restrict__ keep, int* __restrict__ srow) {
  int b = blockIdx.x;
  int tid = threadIdx.x;
  __shared__ float smx[768];
  for (int i = tid; i < 768; i += 256) smx[i] = mx[b * 768 + i];
  __syncthreads();
  if (tid < 256) {
    int t = dsti[b * 256 + tid];
    keep[b * 512 + tid] = t;
    srow[b * 1024 + t] = tid;
  }
  for (int i = tid; i < 768; i += 256) {
    float v = smx[i];
    int r = 0;
    for (int s = 0; s < 768; ++s) {
      float u = smx[s];
      r += (u > v) || (u == v && s < i);
    }
    int tok = srci[b * 768 + i];
    if (r >= 512) {
      keep[b * 512 + (r - 256)] = tok;      // xk row = 256 + (r-512)
      srow[b * 1024 + tok] = r - 256;
    } else {
      srow[b * 1024 + tok] = best[b * 768 + i];  // copy dst-row output
    }
  }
}

// ---------------- LayerNorm (optionally gathered) ----------------
template<int GATHER>
__global__ __launch_bounds__(256) void ln_kernel(const float* __restrict__ xin,
    const int* __restrict__ keep, const float* __restrict__ gw,
    const float* __restrict__ bw, __hip_bfloat16* __restrict__ yout) {
  int row = blockIdx.x;  // 0..8191
  const float* xr;
  if (GATHER) {
    int b = row >> 9, t = row & 511;
    int tok = keep[(b << 9) + t];
    xr = xin + (size_t)((b << 10) + tok) * Dd;
  } else {
    xr = xin + (size_t)row * Dd;
  }
  int tid = threadIdx.x;
  float v[5];
  float s = 0.f, s2 = 0.f;
  #pragma unroll
  for (int e = 0; e < 5; ++e) {
    int i = tid + e * 256;
    float val = (i < Dd) ? xr[i] : 0.f;
    v[e] = val; s += val; s2 += val * val;
  }
  #pragma unroll
  for (int m = 1; m < 64; m <<= 1) { s += __shfl_xor(s, m); s2 += __shfl_xor(s2, m); }
  __shared__ float ps[4], ps2[4];
  int wid = tid >> 6, lane = tid & 63;
  if (lane == 0) { ps[wid] = s; ps2[wid] = s2; }
  __syncthreads();
  s = ps[0] + ps[1] + ps[2] + ps[3];
  s2 = ps2[0] + ps2[1] + ps2[2] + ps2[3];
  constexpr float inv_d = 1.0f / Dd;
  float mu = s * inv_d;
  float var = s2 * inv_d - mu * mu;
  float rstd = rsqrtf(var + 1e-6f);
  __hip_bfloat16* yr = yout + (size_t)row * Dd;
  #pragma unroll
  for (int e = 0; e < 5; ++e) {
    int i = tid + e * 256;
    if (i < Dd) {
      yr[i] = __float2bfloat16((v[e] - mu) * rstd * gw[i] + bw[i]);
    }
  }
}

// ---------------- weight transpose + bf16 cast: w (K x N) -> wT (N x K) ----------------
__global__ __launch_bounds__(256) void wtrans_kernel(const float* __restrict__ w,
    __hip_bfloat16* __restrict__ wT, int K, int N) {
  __shared__ float tile[32][33];
  int nt = N >> 5;
  int tk = blockIdx.x / nt, tn = blockIdx.x % nt;
  int tid = threadIdx.x;
  #pragma unroll
  for (int e = 0; e < 4; ++e) {
    int idx = tid + e * 256;
    int r = idx >> 5, c = idx & 31;
    tile[r][c] = w[(size_t)(tk * 32 + r) * N + tn * 32 + c];
  }
  __syncthreads();
  #pragma unroll
  for (int e = 0; e < 4; ++e) {
    int idx = tid + e * 256;
    int r = idx >> 5, c = idx & 31;
    wT[(size_t)(tn * 32 + r) * K + tk * 32 + c] = __float2bfloat16(tile[c][r]);
  }
}

// ============ GEMM epilogue helper ============
template<int EPI>
__device__ __forceinline__ void epi_store(void* C, const float* res, int Nd,
                                          size_t row, size_t col, float v) {
  if (EPI == 0) {
    ((__hip_bfloat16*)C)[row * (size_t)Nd + col] = __float2bfloat16(v);
  } else if (EPI == 1) {
    ((float*)C)[row * (size_t)Nd + col] = v + res[row * (size_t)Nd + col];
  } else if (EPI == 2) {
    ((__hip_bfloat16*)C)[row * (size_t)Nd + col] = __float2bfloat16(gelu_f(v));
  }
}

// ---------------- GEMM 128x128, 4 waves, 3 blk/CU, reg-double-buffered overlap ----------
// (best-measured structure; all four GEMMs run on it)
template<int EPI>
__global__ __launch_bounds__(256, 3) void gemm128v_kernel(
    const __hip_bfloat16* __restrict__ A, const __hip_bfloat16* __restrict__ BT,
    const float* __restrict__ bias, const float* __restrict__ res,
    const int* __restrict__ keepIdx, const float* __restrict__ xsrc,
    void* __restrict__ C, int Md, int Nd, int Kd) {
  __shared__ __align__(16) __hip_bfloat16 As[3][128 * 32];
  __shared__ __align__(16) __hip_bfloat16 Bs[3][128 * 32];
  const int nb = Nd >> 7;
  const int q8 = gridDim.x >> 3;
  const int wg = (blockIdx.x & 7) * q8 + (blockIdx.x >> 3);
  const int bm = wg / nb, bnb = wg % nb;
  const int tid = threadIdx.x, wid = tid >> 6, lane = tid & 63;
  const int g = lane >> 4, lr = lane & 15;
  const int wm = wid >> 1, wn = wid & 1;  // wave tile 64x64
  const size_t m0 = (size_t)bm * 128, n0 = (size_t)bnb * 128;

  const int trow = tid >> 2;  // 0..63
  const int scol = (((tid & 3) ^ ((tid >> 3) & 3)) << 3);
  const char* Ab = (const char*)A;
  const char* Bb = (const char*)BT;

  auto stage = [&](int slot, int kt) {
    const size_t kb = ((size_t)kt << 5) + scol;
    #pragma unroll
    for (int c = 0; c < 2; ++c)
      gload_lds16(Ab + (((m0 + c * 64 + trow) * (size_t)Kd + kb) << 1),
                  (char*)As + slot * 8192 + c * 4096 + tid * 16);
    #pragma unroll
    for (int c = 0; c < 2; ++c)
      gload_lds16(Bb + (((n0 + c * 64 + trow) * (size_t)Kd + kb) << 1),
                  (char*)Bs + slot * 8192 + c * 4096 + tid * 16);
  };

  f32x4 acc[4][4];
  const f32x4 zf = {0.f, 0.f, 0.f, 0.f};
  #pragma unroll
  for (int mi = 0; mi < 4; ++mi)
    #pragma unroll
    for (int ni = 0; ni < 4; ++ni) acc[mi][ni] = zf;

  const int roff = ((g ^ ((lr >> 1) & 3)) << 3);
  const int nk = Kd >> 5;

  bf16x8 afA[4], bfA[4], afB[4], bfB[4];

#define DSREAD(AF, BF, SLOT) { \
  const __hip_bfloat16* Ac_ = As[SLOT]; \
  const __hip_bfloat16* Bc_ = Bs[SLOT]; \
  _Pragma("unroll") for (int mi_ = 0; mi_ < 4; ++mi_) \
    AF[mi_] = *(const bf16x8*)&Ac_[(wm * 64 + mi_ * 16 + lr) * 32 + roff]; \
  _Pragma("unroll") for (int ni_ = 0; ni_ < 4; ++ni_) \
    BF[ni_] = *(const bf16x8*)&Bc_[(wn * 64 + ni_ * 16 + lr) * 32 + roff]; }

#define MFMA16(AF, BF) { \
  __builtin_amdgcn_s_setprio(1); \
  _Pragma("unroll") for (int mi_ = 0; mi_ < 4; ++mi_) \
    _Pragma("unroll") for (int ni_ = 0; ni_ < 4; ++ni_) \
      acc[mi_][ni_] = __builtin_amdgcn_mfma_f32_16x16x32_bf16(AF[mi_], BF[ni_], acc[mi_][ni_], 0, 0, 0); \
  __builtin_amdgcn_s_setprio(0); }

#define GITER(KT, S0, S1, AFC, BFC, AFN, BFN) { \
  if ((KT) <= nk - 3)      { asm volatile("s_waitcnt vmcnt(4)" ::: "memory"); } \
  else if ((KT) == nk - 2) { asm volatile("s_waitcnt vmcnt(0)" ::: "memory"); } \
  asm volatile("s_waitcnt lgkmcnt(0)" ::: "memory"); \
  __builtin_amdgcn_s_barrier(); \
  asm volatile("" ::: "memory"); \
  if ((KT) + 1 < nk) DSREAD(AFN, BFN, (S1)); \
  if ((KT) + 3 < nk) stage((S0), (KT) + 3); \
  MFMA16(AFC, BFC); }

  stage(0, 0); stage(1, 1); stage(2, 2);
  asm volatile("s_waitcnt vmcnt(8)" ::: "memory");  // retire stage(0)
  __builtin_amdgcn_s_barrier();
  asm volatile("" ::: "memory");
  DSREAD(afA, bfA, 0);

  int s0 = 0, s1 = 1;
  for (int kt = 0; kt < nk; kt += 2) {
    GITER(kt, s0, s1, afA, bfA, afB, bfB);
    int s2 = (s1 == 2) ? 0 : s1 + 1;
    GITER(kt + 1, s1, s2, afB, bfB, afA, bfA);
    s0 = s2; s1 = (s2 == 2) ? 0 : s2 + 1;
  }
#undef GITER
#undef MFMA16
#undef DSREAD

  #pragma unroll
  for (int ni = 0; ni < 4; ++ni) {
    size_t col = n0 + wn * 64 + ni * 16 + lr;
    float bv = bias[col];
    #pragma unroll
    for (int mi = 0; mi < 4; ++mi) {
      #pragma unroll
      for (int j = 0; j < 4; ++j) {
        size_t row = m0 + wm * 64 + mi * 16 + g * 4 + j;
        float v = acc[mi][ni][j] + bv;
        if (EPI == 3) {
          int b = (int)(row >> 9);
          int tok = keepIdx[row];
          const float* rr = xsrc + ((size_t)(b << 10) + tok) * Dd;
          ((float*)C)[row * (size_t)Nd + col] = v + rr[col];
        } else {
          epi_store<EPI>(C, res, Nd, row, col, v);
        }
      }
    }
  }
}

// ---------------- V transpose per (b,h): qkv v-slice -> vT[bh][80][512] ----------------
__global__ __launch_bounds__(256) void vtrans_kernel(const __hip_bfloat16* __restrict__ qkv,
                                                     __hip_bfloat16* __restrict__ vT) {
  int bh = blockIdx.x;
  int b = bh >> 4, h = bh & 15;
  __shared__ __align__(16) __hip_bfloat16 Vl[256 * 72];
  int tid = threadIdx.x;
  const __hip_bfloat16 zb = __float2bfloat16(0.0f);
  for (int half = 0; half < 2; ++half) {
    __syncthreads();
    for (int idx = tid; idx < 256 * 18; idx += 256) {
      int t = idx / 18, c = idx % 18;
      *(ushort4*)&Vl[t * 72 + c * 4] =
          *(const ushort4*)&qkv[((size_t)(b * 512 + half * 256 + t)) * 3456 + 2304 + h * 72 + c * 4];
    }
    __syncthreads();
    for (int idx = tid; idx < 80 * 256; idx += 256) {
      int d = idx >> 8, t = idx & 255;
      vT[((size_t)bh * 80 + d) * 512 + half * 256 + t] = (d < 72) ? Vl[t * 72 + d] : zb;
    }
  }
}

// ---------------- flash attention per (b,h,q-tile 64) ----------------
// Qs/Ks stride 104 elem (208 B): bank-group walk (row*52)%32 covers all 8 groups x2
// lanes = conflict-free (stride 96 was 8-way conflicted: (row*48)%32 in {0,16}).
__global__ __launch_bounds__(256) void attn_kernel(const __hip_bfloat16* __restrict__ qkv,
    const __hip_bfloat16* __restrict__ vT, __hip_bfloat16* __restrict__ o) {
  const int blk = blockIdx.x;
  const int qt = blk & 7, bh = blk >> 3;
  const int b = bh >> 4, h = bh & 15;
  __shared__ __align__(16) __hip_bfloat16 Qs[64][104];
  __shared__ __align__(16) __hip_bfloat16 Ks[64][104];
  __shared__ __align__(16) __hip_bfloat16 Vs[80][72];
  __shared__ __align__(16) __hip_bfloat16 Ps[4][16][72];
  const int tid = threadIdx.x, wid = tid >> 6, lane = tid & 63;
  const int g = lane >> 4, lr = lane & 15;
  const __hip_bfloat16 zb = __float2bfloat16(0.0f);

  for (int idx = tid; idx < 64 * 18; idx += 256) {
    int r = idx / 18, c = idx % 18;
    *(ushort4*)&Qs[r][c * 4] =
        *(const ushort4*)&qkv[((size_t)(b * 512 + qt * 64 + r)) * 3456 + h * 72 + c * 4];
  }
  for (int idx = tid; idx < 64 * 32; idx += 256) {
    int r = idx / 32, d = 72 + idx % 32;
    Qs[r][d] = zb; Ks[r][d] = zb;
  }

  f32x4 ov[5];
  const f32x4 zf = {0.f, 0.f, 0.f, 0.f};
  #pragma unroll
  for (int ni = 0; ni < 5; ++ni) ov[ni] = zf;
  float m_[4], l_[4];
  #pragma unroll
  for (int j = 0; j < 4; ++j) { m_[j] = -3.0e38f; l_[j] = 0.f; }
  const float scale = 0.11785113019775793f;  // 1/sqrt(72)

  for (int c = 0; c < 8; ++c) {
    __syncthreads();
    for (int idx = tid; idx < 64 * 18; idx += 256) {
      int r = idx / 18, cc = idx % 18;
      *(ushort4*)&Ks[r][cc * 4] =
          *(const ushort4*)&qkv[((size_t)(b * 512 + c * 64 + r)) * 3456 + 1152 + h * 72 + cc * 4];
    }
    for (int idx = tid; idx < 80 * 8; idx += 256) {
      int d = idx >> 3, t8 = idx & 7;
      *(uint4*)&Vs[d][t8 * 8] =
          *(const uint4*)&vT[((size_t)bh * 80 + d) * 512 + c * 64 + t8 * 8];
    }
    __syncthreads();

    f32x4 sf[4];
    #pragma unroll
    for (int nf = 0; nf < 4; ++nf) sf[nf] = zf;
    #pragma unroll
    for (int ks = 0; ks < 3; ++ks) {
      bf16x8 qa = *(const bf16x8*)&Qs[wid * 16 + lr][ks * 32 + g * 8];
      #pragma unroll
      for (int nf = 0; nf < 4; ++nf) {
        bf16x8 kb = *(const bf16x8*)&Ks[nf * 16 + lr][ks * 32 + g * 8];
        sf[nf] = __builtin_amdgcn_mfma_f32_16x16x32_bf16(qa, kb, sf[nf], 0, 0, 0);
      }
    }

    float cm[4];
    #pragma unroll
    for (int j = 0; j < 4; ++j)
      cm[j] = fmaxf(fmaxf(sf[0][j], sf[1][j]), fmaxf(sf[2][j], sf[3][j])) * scale;
    #pragma unroll
    for (int mm = 1; mm < 16; mm <<= 1)
      #pragma unroll
      for (int j = 0; j < 4; ++j) cm[j] = fmaxf(cm[j], __shfl_xor(cm[j], mm));
    float fac[4], rs[4];
    #pragma unroll
    for (int j = 0; j < 4; ++j) {
      float nm = fmaxf(m_[j], cm[j]);
      fac[j] = __expf(m_[j] - nm);
      m_[j] = nm;
      rs[j] = 0.f;
    }
    #pragma unroll
    for (int nf = 0; nf < 4; ++nf)
      #pragma unroll
      for (int j = 0; j < 4; ++j) {
        float pv = __expf(sf[nf][j] * scale - m_[j]);
        rs[j] += pv;
        Ps[wid][g * 4 + j][nf * 16 + lr] = __float2bfloat16(pv);
      }
    #pragma unroll
    for (int mm = 1; mm < 16; mm <<= 1)
      #pragma unroll
      for (int j = 0; j < 4; ++j) rs[j] += __shfl_xor(rs[j], mm);
    #pragma unroll
    for (int j = 0; j < 4; ++j) l_[j] = l_[j] * fac[j] + rs[j];
    #pragma unroll
    for (int ni = 0; ni < 5; ++ni)
      #pragma unroll
      for (int j = 0; j < 4; ++j) ov[ni][j] *= fac[j];

    #pragma unroll
    for (int k2 = 0; k2 < 2; ++k2) {
      bf16x8 pa = *(const bf16x8*)&Ps[wid][lr][k2 * 32 + g * 8];
      #pragma unroll
      for (int ni = 0; ni < 5; ++ni) {
        bf16x8 vb = *(const bf16x8*)&Vs[ni * 16 + lr][k2 * 32 + g * 8];
        ov[ni] = __builtin_amdgcn_mfma_f32_16x16x32_bf16(pa, vb, ov[ni], 0, 0, 0);
      }
    }
  }

  #pragma unroll
  for (int ni = 0; ni < 5; ++ni) {
    int d = ni * 16 + lr;
    if (d < 72) {
      #pragma unroll
      for (int j = 0; j < 4; ++j) {
        int t = qt * 64 + wid * 16 + g * 4 + j;
        o[((size_t)(b * 512 + t)) * 1152 + h * 72 + d] = __float2bfloat16(ov[ni][j] / l_[j]);
      }
    }
  }
}

// ---------------- final recovery: out[b,n,:] = yout[b, src_row[b,n], :] ----------------
__global__ __launch_bounds__(256) void recover_kernel(const float* __restrict__ yout,
    const int* __restrict__ srow, float* __restrict__ out) {
  int idx = blockIdx.x * 256 + threadIdx.x;  // over B*N*288 float4s
  int q = idx % 288;
  int bnv = idx / 288;  // b*1024+n
  int r = srow[bnv];
  int b = bnv >> 10;
  const float4* src = (const float4*)yout + ((size_t)((b << 9) + r)) * 288 + q;
  ((float4*)out)[idx] = *src;
}

}  // namespace

extern "C" void kernel_launch(void* const* d_in, const int* in_sizes, int n_in,
                              void* d_out, int out_size, void* d_ws, size_t ws_size,
                              hipStream_t stream) {
  (void)in_sizes; (void)n_in; (void)out_size; (void)ws_size;
  const float* x      = (const float*)d_in[0];
  const float* noise  = (const float*)d_in[1];
  const float* ln1_g  = (const float*)d_in[2];
  const float* ln1_b  = (const float*)d_in[3];
  const float* ln2_g  = (const float*)d_in[4];
  const float* ln2_b  = (const float*)d_in[5];
  const float* w_qkv  = (const float*)d_in[6];
  const float* b_qkv  = (const float*)d_in[7];
  const float* w_proj = (const float*)d_in[8];
  const float* b_proj = (const float*)d_in[9];
  const float* w_fc1  = (const float*)d_in[10];
  const float* b_fc1  = (const float*)d_in[11];
  const float* w_fc2  = (const float*)d_in[12];
  const float* b_fc2  = (const float*)d_in[13];
  float* out = (float*)d_out;

  char* p = (char*)d_ws;
  auto alloc = [&](size_t bytes) {
    char* r = p;
    p += (bytes + 255) & ~(size_t)255;
    return r;
  };
  __hip_bfloat16* wqkvT  = (__hip_bfloat16*)alloc((size_t)3584 * 1152 * 2);
  __hip_bfloat16* wprojT = (__hip_bfloat16*)alloc((size_t)1280 * 1152 * 2);
  __hip_bfloat16* wfc1T  = (__hip_bfloat16*)alloc((size_t)4608 * 1152 * 2);
  __hip_bfloat16* wfc2T  = (__hip_bfloat16*)alloc((size_t)1280 * 4608 * 2);
  float* inv = (float*)alloc(16384 * 4);
  int* dsti  = (int*)alloc(4096 * 4);
  int* srci  = (int*)alloc(12288 * 4);
  float* mx  = (float*)alloc(12288 * 4);
  int* best  = (int*)alloc(12288 * 4);
  int* keep  = (int*)alloc(8192 * 4);
  int* srow  = (int*)alloc(16384 * 4);
  float* yout = (float*)alloc((size_t)8192 * 1152 * 4);
  __hip_bfloat16* y1   = (__hip_bfloat16*)alloc((size_t)8192 * 1152 * 2);  // also y2
  __hip_bfloat16* qkvb = (__hip_bfloat16*)alloc((size_t)8192 * 4608 * 2);  // also h (fc1 out)
  __hip_bfloat16* vT   = (__hip_bfloat16*)alloc((size_t)256 * 80 * 512 * 2);
  __hip_bfloat16* ob   = (__hip_bfloat16*)alloc((size_t)8192 * 1152 * 2);
  float* x2 = (float*)alloc((size_t)8192 * 1152 * 4);

  // xn hi/lo planes alias qkvb (dead until gemm writes it, exactly 2x 37.75MB)
  __hip_bfloat16* xnh = qkvb;
  __hip_bfloat16* xnl = qkvb + (size_t)16 * 1024 * 1152;

  // weights -> bf16 transposed
  wtrans_kernel<<<36 * 108, 256, 0, stream>>>(w_qkv, wqkvT, 1152, 3456);
  wtrans_kernel<<<36 * 36, 256, 0, stream>>>(w_proj, wprojT, 1152, 1152);
  wtrans_kernel<<<36 * 144, 256, 0, stream>>>(w_fc1, wfc1T, 1152, 4608);
  wtrans_kernel<<<144 * 36, 256, 0, stream>>>(w_fc2, wfc2T, 4608, 1152);

  // SiTo indices (norm + window fused)
  normwin_kernel<<<4096, 256, 0, stream>>>(x, noise, inv, xnh, xnl, dsti, srci);
  simgemm_kernel<<<16 * 12, 256, 0, stream>>>(xnh, xnl, dsti, srci, mx, best);
  rank_kernel<<<16, 256, 0, stream>>>(mx, best, dsti, srci, keep, srow);

  // DiT block on kept tokens — all GEMMs on gemm128v (best measured structure)
  ln_kernel<1><<<8192, 256, 0, stream>>>(x, keep, ln1_g, ln1_b, y1);
  gemm128v_kernel<0><<<64 * 27, 256, 0, stream>>>(y1, wqkvT, b_qkv, nullptr, nullptr, nullptr,
                                                  qkvb, 8192, 3456, 1152);
  vtrans_kernel<<<256, 256, 0, stream>>>(qkvb, vT);
  attn_kernel<<<2048, 256, 0, stream>>>(qkvb, vT, ob);
  gemm128v_kernel<3><<<64 * 9, 256, 0, stream>>>(ob, wprojT, b_proj, nullptr, keep, x,
                                                 x2, 8192, 1152, 1152);
  ln_kernel<0><<<8192, 256, 0, stream>>>(x2, nullptr, ln2_g, ln2_b, y1);
  gemm128v_kernel<2><<<64 * 36, 256, 0, stream>>>(y1, wfc1T, b_fc1, nullptr, nullptr, nullptr,
                                                  qkvb, 8192, 4608, 1152);
  gemm128v_kernel<1><<<64 * 9, 256, 0, stream>>>(qkvb, wfc2T, b_fc2, x2, nullptr, nullptr,
                                                 yout, 8192, 1152, 4608);

  // scatter-as-gather recovery
  recover_kernel<<<18432, 256, 0, stream>>>(yout, srow, out);
}

// Round 16
// 734.212 us; speedup vs baseline: 1.0106x; 1.0106x over previous
//
#include <hip/hip_runtime.h>
#include <hip/hip_bf16.h>

namespace {

constexpr int Dd = 1152;

typedef __attribute__((ext_vector_type(8))) short bf16x8;
typedef __attribute__((ext_vector_type(4))) float f32x4;

__device__ __forceinline__ void gload_lds16(const void* g, void* l) {
  __builtin_amdgcn_global_load_lds(
      (const __attribute__((address_space(1))) void*)g,
      (__attribute__((address_space(3))) void*)l, 16, 0, 0);
}

__device__ __forceinline__ float gelu_f(float x) {
  float x3 = x * x * x;
  float z2 = 1.5957691216057308f * (x + 0.044715f * x3);
  float e = __expf(fminf(z2, 30.0f));
  return x * e / (e + 1.0f);
}

// ---------------- fused norm + window scoring ----------------
__global__ __launch_bounds__(256) void normwin_kernel(const float* __restrict__ x,
    const float* __restrict__ noise, float* __restrict__ inv,
    __hip_bfloat16* __restrict__ xnh, __hip_bfloat16* __restrict__ xnl,
    int* __restrict__ dsti, int* __restrict__ srci) {
  const int gidx = blockIdx.x;  // b*256 + w
  const int b = gidx >> 8, w = gidx & 255;
  const int wy = w >> 4, wx = w & 15;
  const int t0 = wy * 64 + wx * 2;
  const int wid = threadIdx.x >> 6, lane = threadIdx.x & 63;
  const int tok = t0 + (wid >> 1) * 32 + (wid & 1);
  const int row = (b << 10) + tok;

  const float2* xr = (const float2*)(x + (size_t)row * Dd);
  float2 v[9];
  float s = 0.f;
  #pragma unroll
  for (int e = 0; e < 9; ++e) {
    v[e] = xr[lane + 64 * e];
    s += v[e].x * v[e].x + v[e].y * v[e].y;
  }
  #pragma unroll
  for (int m = 1; m < 64; m <<= 1) s += __shfl_xor(s, m);
  float iv = 1.0f / (sqrtf(s) + 1e-6f);
  if (lane == 0) inv[row] = iv;

  __shared__ float2 xns[4][576];
  ushort2* ph = (ushort2*)(xnh + (size_t)row * Dd);
  ushort2* pl = (ushort2*)(xnl + (size_t)row * Dd);
  #pragma unroll
  for (int e = 0; e < 9; ++e) {
    float ax = v[e].x * iv, ay = v[e].y * iv;
    xns[wid][lane + 64 * e] = make_float2(ax, ay);
    __hip_bfloat16 hx = __float2bfloat16(ax), hy = __float2bfloat16(ay);
    __hip_bfloat16 lx = __float2bfloat16(ax - __bfloat162float(hx));
    __hip_bfloat16 ly = __float2bfloat16(ay - __bfloat162float(hy));
    ph[lane + 64 * e] = make_ushort2(*(ushort*)&hx, *(ushort*)&hy);
    pl[lane + 64 * e] = make_ushort2(*(ushort*)&lx, *(ushort*)&ly);
  }
  __syncthreads();

  float dot = 0.f;
  #pragma unroll
  for (int e = 0; e < 9; ++e) {
    int i = lane + 64 * e;
    float2 a0 = xns[0][i], a1 = xns[1][i], a2 = xns[2][i], a3 = xns[3][i];
    float sx = a0.x + a1.x + a2.x + a3.x;
    float sy = a0.y + a1.y + a2.y + a3.y;
    dot += (v[e].x * iv) * sx + (v[e].y * iv) * sy;
  }
  #pragma unroll
  for (int m = 1; m < 64; m <<= 1) dot += __shfl_xor(dot, m);
  __shared__ float dots[4];
  if (lane == 0) dots[wid] = dot;
  __syncthreads();
  if (threadIdx.x == 0) {
    float best = -1e30f; int bj = 0;
    #pragma unroll
    for (int j = 0; j < 4; ++j) {
      float sc = 0.25f * dots[j] + 0.1f * noise[(size_t)gidx * 4 + j];
      if (sc > best) { best = sc; bj = j; }  // strict > = first-max
    }
    int tk[4] = {t0, t0 + 1, t0 + 32, t0 + 33};
    dsti[b * 256 + w] = tk[bj];
    int m = 0;
    #pragma unroll
    for (int j = 0; j < 4; ++j) if (j != bj) srci[b * 768 + w * 3 + (m++)] = tk[j];
  }
}

// ---------------- sim GEMM (split-bf16 MFMA): per-src (max, argmax) over 256 dst ----------
__global__ __launch_bounds__(256) void simgemm_kernel(
    const __hip_bfloat16* __restrict__ xnh, const __hip_bfloat16* __restrict__ xnl,
    const int* __restrict__ dsti, const int* __restrict__ srci,
    float* __restrict__ mx, int* __restrict__ best) {
  int b = blockIdx.x / 12;
  int m0 = (blockIdx.x % 12) * 64;
  __shared__ __align__(16) __hip_bfloat16 AsH[2][64 * 32];
  __shared__ __align__(16) __hip_bfloat16 AsL[2][64 * 32];
  __shared__ __align__(16) __hip_bfloat16 BsH[2][256 * 32];
  __shared__ __align__(16) __hip_bfloat16 BsL[2][256 * 32];
  const int tid = threadIdx.x, wid = tid >> 6, lane = tid & 63;
  const int g = lane >> 4, lr = lane & 15;

  const int slotRow = tid >> 2;        // 0..63
  const int colByte = (((tid & 3) ^ ((tid >> 3) & 3)) << 4);
  size_t aRow = (size_t)((b << 10) + srci[b * 768 + m0 + slotRow]) * Dd;
  size_t bRow[4];
  #pragma unroll
  for (int p = 0; p < 4; ++p)
    bRow[p] = (size_t)((b << 10) + dsti[b * 256 + p * 64 + slotRow]) * Dd;
  const char* xh = (const char*)xnh;
  const char* xl = (const char*)xnl;

  auto stage = [&](int buf, int k0) {
    size_t ka = (aRow + k0) * 2 + colByte;
    gload_lds16(xh + ka, (char*)AsH + buf * 4096 + wid * 1024);
    gload_lds16(xl + ka, (char*)AsL + buf * 4096 + wid * 1024);
    #pragma unroll
    for (int p = 0; p < 4; ++p) {
      size_t kb = (bRow[p] + k0) * 2 + colByte;
      gload_lds16(xh + kb, (char*)BsH + buf * 16384 + p * 4096 + wid * 1024);
      gload_lds16(xl + kb, (char*)BsL + buf * 16384 + p * 4096 + wid * 1024);
    }
  };

  f32x4 hh[16], hx[16];
  const f32x4 zf = {0.f, 0.f, 0.f, 0.f};
  #pragma unroll
  for (int nf = 0; nf < 16; ++nf) { hh[nf] = zf; hx[nf] = zf; }

  const int roff = ((g ^ ((lr >> 1) & 3)) << 3);
  stage(0, 0);
  asm volatile("s_waitcnt vmcnt(0)" ::: "memory");
  __syncthreads();
  int buf = 0;
  for (int ks = 0; ks < 36; ++ks) {
    if (ks + 1 < 36) stage(buf ^ 1, (ks + 1) * 32);
    bf16x8 ah = *(const bf16x8*)&AsH[buf][(wid * 16 + lr) * 32 + roff];
    bf16x8 al = *(const bf16x8*)&AsL[buf][(wid * 16 + lr) * 32 + roff];
    #pragma unroll
    for (int nf = 0; nf < 16; ++nf) {
      bf16x8 bh = *(const bf16x8*)&BsH[buf][(nf * 16 + lr) * 32 + roff];
      bf16x8 bl = *(const bf16x8*)&BsL[buf][(nf * 16 + lr) * 32 + roff];
      hh[nf] = __builtin_amdgcn_mfma_f32_16x16x32_bf16(ah, bh, hh[nf], 0, 0, 0);
      hx[nf] = __builtin_amdgcn_mfma_f32_16x16x32_bf16(ah, bl, hx[nf], 0, 0, 0);
      hx[nf] = __builtin_amdgcn_mfma_f32_16x16x32_bf16(al, bh, hx[nf], 0, 0, 0);
    }
    asm volatile("s_waitcnt vmcnt(0)" ::: "memory");
    __syncthreads();
    buf ^= 1;
  }

  #pragma unroll
  for (int j = 0; j < 4; ++j) {
    float bv = -1e30f; int bi = 0;
    #pragma unroll
    for (int nf = 0; nf < 16; ++nf) {
      float v = hh[nf][j] + hx[nf][j];
      if (v > bv) { bv = v; bi = nf * 16 + lr; }
    }
    #pragma unroll
    for (int m = 1; m < 16; m <<= 1) {
      float ov = __shfl_xor(bv, m);
      int oi = __shfl_xor(bi, m);
      if (ov > bv || (ov == bv && oi < bi)) { bv = ov; bi = oi; }
    }
    if (lr == 0) {
      int row = m0 + wid * 16 + g * 4 + j;
      mx[b * 768 + row] = bv;
      best[b * 768 + row] = bi;
    }
  }
}

// ---------------- rank (stable argsort of -mx) -> keep_token + src_row ----------------
__global__ __launch_bounds__(256) void rank_kernel(const float* __restrict__ mx,
    const int* __restrict__ best, const int* __restrict__ dsti,
    const int* __restrict__ srci, int* __restrict__ keep, int* __restrict__ srow) {
  int b = blockIdx.x;
  int tid = threadIdx.x;
  __shared__ float smx[768];
  for (int i = tid; i < 768; i += 256) smx[i] = mx[b * 768 + i];
  __syncthreads();
  if (tid < 256) {
    int t = dsti[b * 256 + tid];
    keep[b * 512 + tid] = t;
    srow[b * 1024 + t] = tid;
  }
  for (int i = tid; i < 768; i += 256) {
    float v = smx[i];
    int r = 0;
    for (int s = 0; s < 768; ++s) {
      float u = smx[s];
      r += (u > v) || (u == v && s < i);
    }
    int tok = srci[b * 768 + i];
    if (r >= 512) {
      keep[b * 512 + (r - 256)] = tok;      // xk row = 256 + (r-512)
      srow[b * 1024 + tok] = r - 256;
    } else {
      srow[b * 1024 + tok] = best[b * 768 + i];  // copy dst-row output
    }
  }
}

// ---------------- LayerNorm (optionally gathered) ----------------
template<int GATHER>
__global__ __launch_bounds__(256) void ln_kernel(const float* __restrict__ xin,
    const int* __restrict__ keep, const float* __restrict__ gw,
    const float* __restrict__ bw, __hip_bfloat16* __restrict__ yout) {
  int row = blockIdx.x;  // 0..8191
  const float* xr;
  if (GATHER) {
    int b = row >> 9, t = row & 511;
    int tok = keep[(b << 9) + t];
    xr = xin + (size_t)((b << 10) + tok) * Dd;
  } else {
    xr = xin + (size_t)row * Dd;
  }
  int tid = threadIdx.x;
  float v[5];
  float s = 0.f, s2 = 0.f;
  #pragma unroll
  for (int e = 0; e < 5; ++e) {
    int i = tid + e * 256;
    float val = (i < Dd) ? xr[i] : 0.f;
    v[e] = val; s += val; s2 += val * val;
  }
  #pragma unroll
  for (int m = 1; m < 64; m <<= 1) { s += __shfl_xor(s, m); s2 += __shfl_xor(s2, m); }
  __shared__ float ps[4], ps2[4];
  int wid = tid >> 6, lane = tid & 63;
  if (lane == 0) { ps[wid] = s; ps2[wid] = s2; }
  __syncthreads();
  s = ps[0] + ps[1] + ps[2] + ps[3];
  s2 = ps2[0] + ps2[1] + ps2[2] + ps2[3];
  constexpr float inv_d = 1.0f / Dd;
  float mu = s * inv_d;
  float var = s2 * inv_d - mu * mu;
  float rstd = rsqrtf(var + 1e-6f);
  __hip_bfloat16* yr = yout + (size_t)row * Dd;
  #pragma unroll
  for (int e = 0; e < 5; ++e) {
    int i = tid + e * 256;
    if (i < Dd) {
      yr[i] = __float2bfloat16((v[e] - mu) * rstd * gw[i] + bw[i]);
    }
  }
}

// ---------------- weight transpose + bf16 cast: w (K x N) -> wT (N x K) ----------------
__global__ __launch_bounds__(256) void wtrans_kernel(const float* __restrict__ w,
    __hip_bfloat16* __restrict__ wT, int K, int N) {
  __shared__ float tile[32][33];
  int nt = N >> 5;
  int tk = blockIdx.x / nt, tn = blockIdx.x % nt;
  int tid = threadIdx.x;
  #pragma unroll
  for (int e = 0; e < 4; ++e) {
    int idx = tid + e * 256;
    int r = idx >> 5, c = idx & 31;
    tile[r][c] = w[(size_t)(tk * 32 + r) * N + tn * 32 + c];
  }
  __syncthreads();
  #pragma unroll
  for (int e = 0; e < 4; ++e) {
    int idx = tid + e * 256;
    int r = idx >> 5, c = idx & 31;
    wT[(size_t)(tn * 32 + r) * K + tk * 32 + c] = __float2bfloat16(tile[c][r]);
  }
}

// ============ GEMM epilogue helper ============
template<int EPI>
__device__ __forceinline__ void epi_store(void* C, const float* res, int Nd,
                                          size_t row, size_t col, float v) {
  if (EPI == 0) {
    ((__hip_bfloat16*)C)[row * (size_t)Nd + col] = __float2bfloat16(v);
  } else if (EPI == 1) {
    ((float*)C)[row * (size_t)Nd + col] = v + res[row * (size_t)Nd + col];
  } else if (EPI == 2) {
    ((__hip_bfloat16*)C)[row * (size_t)Nd + col] = __float2bfloat16(gelu_f(v));
  }
}

// ---------------- GEMM 128x256 lockstep (8 waves, 2 blk/CU) — qkv (best for N=3456) -----
template<int EPI>
__global__ __launch_bounds__(512, 4) void gemm128_kernel(
    const __hip_bfloat16* __restrict__ A, const __hip_bfloat16* __restrict__ BT,
    const float* __restrict__ bias, const float* __restrict__ res,
    void* __restrict__ C, int Md, int Nd, int NdPad, int Kd) {
  constexpr int BM = 128;
  __shared__ __align__(16) __hip_bfloat16 As[3][BM * 32];
  __shared__ __align__(16) __hip_bfloat16 Bs[3][256 * 32];
  const int nb = NdPad >> 8;
  const int q8 = gridDim.x >> 3;
  const int wg = (blockIdx.x & 7) * q8 + (blockIdx.x >> 3);
  const int bm = wg / nb, bnb = wg % nb;
  const int tid = threadIdx.x, wid = tid >> 6, lane = tid & 63;
  const int g = lane >> 4, lr = lane & 15;
  const int wm = wid >> 2, wn = wid & 3;
  const size_t m0 = (size_t)bm * BM, n0 = (size_t)bnb * 256;

  const int trow = tid >> 2;
  const int scol = (((tid & 3) ^ ((tid >> 3) & 3)) << 3);
  const char* Ab = (const char*)A;
  const char* Bb = (const char*)BT;

  auto stage = [&](int slot, int kt) {
    const size_t kb = ((size_t)kt << 5) + scol;
    gload_lds16(Ab + (((m0 + trow) * (size_t)Kd + kb) << 1),
                (char*)As + slot * 8192 + wid * 1024);
    gload_lds16(Bb + (((n0 + trow) * (size_t)Kd + kb) << 1),
                (char*)Bs + slot * 16384 + wid * 1024);
    gload_lds16(Bb + (((n0 + 128 + trow) * (size_t)Kd + kb) << 1),
                (char*)Bs + slot * 16384 + 8192 + wid * 1024);
  };

  f32x4 acc[4][4];
  const f32x4 zf = {0.f, 0.f, 0.f, 0.f};
  #pragma unroll
  for (int mi = 0; mi < 4; ++mi)
    #pragma unroll
    for (int ni = 0; ni < 4; ++ni) acc[mi][ni] = zf;

  const int nk = Kd >> 5;
  stage(0, 0);
  stage(1, 1);
  asm volatile("s_waitcnt vmcnt(3)" ::: "memory");
  __builtin_amdgcn_s_barrier();

  int cur = 0;
  const int roff = ((g ^ ((lr >> 1) & 3)) << 3);
  for (int kt = 0; kt < nk; ++kt) {
    const __hip_bfloat16* Ac = As[cur];
    const __hip_bfloat16* Bc = Bs[cur];
    bf16x8 af[4], bf[4];
    #pragma unroll
    for (int mi = 0; mi < 4; ++mi)
      af[mi] = *(const bf16x8*)&Ac[(wm * 64 + mi * 16 + lr) * 32 + roff];
    #pragma unroll
    for (int ni = 0; ni < 4; ++ni)
      bf[ni] = *(const bf16x8*)&Bc[(wn * 64 + ni * 16 + lr) * 32 + roff];
    if (kt + 2 < nk) stage(cur == 0 ? 2 : cur - 1, kt + 2);
    __builtin_amdgcn_s_barrier();
    __builtin_amdgcn_s_setprio(1);
    #pragma unroll
    for (int mi = 0; mi < 4; ++mi)
      #pragma unroll
      for (int ni = 0; ni < 4; ++ni)
        acc[mi][ni] = __builtin_amdgcn_mfma_f32_16x16x32_bf16(af[mi], bf[ni], acc[mi][ni], 0, 0, 0);
    __builtin_amdgcn_s_setprio(0);
    if (kt + 2 < nk)      asm volatile("s_waitcnt vmcnt(3)" ::: "memory");
    else if (kt + 1 < nk) asm volatile("s_waitcnt vmcnt(0)" ::: "memory");
    __builtin_amdgcn_s_barrier();
    cur = (cur == 2) ? 0 : cur + 1;
  }

  #pragma unroll
  for (int ni = 0; ni < 4; ++ni) {
    size_t col = n0 + wn * 64 + ni * 16 + lr;
    if (col < (size_t)Nd) {
      float bv = bias[col];
      #pragma unroll
      for (int mi = 0; mi < 4; ++mi) {
        #pragma unroll
        for (int j = 0; j < 4; ++j) {
          size_t row = m0 + wm * 64 + mi * 16 + g * 4 + j;
          float v = acc[mi][ni][j] + bv;
          epi_store<EPI>(C, res, Nd, row, col, v);
        }
      }
    }
  }
}

// ---------------- GEMM 128x128, 4 waves, 3 blk/CU, reg-double-buffered overlap ----------
template<int EPI>
__global__ __launch_bounds__(256, 3) void gemm128v_kernel(
    const __hip_bfloat16* __restrict__ A, const __hip_bfloat16* __restrict__ BT,
    const float* __restrict__ bias, const float* __restrict__ res,
    const int* __restrict__ keepIdx, const float* __restrict__ xsrc,
    void* __restrict__ C, int Md, int Nd, int Kd) {
  __shared__ __align__(16) __hip_bfloat16 As[3][128 * 32];
  __shared__ __align__(16) __hip_bfloat16 Bs[3][128 * 32];
  const int nb = Nd >> 7;
  const int q8 = gridDim.x >> 3;
  const int wg = (blockIdx.x & 7) * q8 + (blockIdx.x >> 3);
  const int bm = wg / nb, bnb = wg % nb;
  const int tid = threadIdx.x, wid = tid >> 6, lane = tid & 63;
  const int g = lane >> 4, lr = lane & 15;
  const int wm = wid >> 1, wn = wid & 1;  // wave tile 64x64
  const size_t m0 = (size_t)bm * 128, n0 = (size_t)bnb * 128;

  const int trow = tid >> 2;  // 0..63
  const int scol = (((tid & 3) ^ ((tid >> 3) & 3)) << 3);
  const char* Ab = (const char*)A;
  const char* Bb = (const char*)BT;

  auto stage = [&](int slot, int kt) {
    const size_t kb = ((size_t)kt << 5) + scol;
    #pragma unroll
    for (int c = 0; c < 2; ++c)
      gload_lds16(Ab + (((m0 + c * 64 + trow) * (size_t)Kd + kb) << 1),
                  (char*)As + slot * 8192 + c * 4096 + tid * 16);
    #pragma unroll
    for (int c = 0; c < 2; ++c)
      gload_lds16(Bb + (((n0 + c * 64 + trow) * (size_t)Kd + kb) << 1),
                  (char*)Bs + slot * 8192 + c * 4096 + tid * 16);
  };

  f32x4 acc[4][4];
  const f32x4 zf = {0.f, 0.f, 0.f, 0.f};
  #pragma unroll
  for (int mi = 0; mi < 4; ++mi)
    #pragma unroll
    for (int ni = 0; ni < 4; ++ni) acc[mi][ni] = zf;

  const int roff = ((g ^ ((lr >> 1) & 3)) << 3);
  const int nk = Kd >> 5;

  bf16x8 afA[4], bfA[4], afB[4], bfB[4];

#define DSREAD(AF, BF, SLOT) { \
  const __hip_bfloat16* Ac_ = As[SLOT]; \
  const __hip_bfloat16* Bc_ = Bs[SLOT]; \
  _Pragma("unroll") for (int mi_ = 0; mi_ < 4; ++mi_) \
    AF[mi_] = *(const bf16x8*)&Ac_[(wm * 64 + mi_ * 16 + lr) * 32 + roff]; \
  _Pragma("unroll") for (int ni_ = 0; ni_ < 4; ++ni_) \
    BF[ni_] = *(const bf16x8*)&Bc_[(wn * 64 + ni_ * 16 + lr) * 32 + roff]; }

#define MFMA16(AF, BF) { \
  __builtin_amdgcn_s_setprio(1); \
  _Pragma("unroll") for (int mi_ = 0; mi_ < 4; ++mi_) \
    _Pragma("unroll") for (int ni_ = 0; ni_ < 4; ++ni_) \
      acc[mi_][ni_] = __builtin_amdgcn_mfma_f32_16x16x32_bf16(AF[mi_], BF[ni_], acc[mi_][ni_], 0, 0, 0); \
  __builtin_amdgcn_s_setprio(0); }

#define GITER(KT, S0, S1, AFC, BFC, AFN, BFN) { \
  if ((KT) <= nk - 3)      { asm volatile("s_waitcnt vmcnt(4)" ::: "memory"); } \
  else if ((KT) == nk - 2) { asm volatile("s_waitcnt vmcnt(0)" ::: "memory"); } \
  asm volatile("s_waitcnt lgkmcnt(0)" ::: "memory"); \
  __builtin_amdgcn_s_barrier(); \
  asm volatile("" ::: "memory"); \
  if ((KT) + 1 < nk) DSREAD(AFN, BFN, (S1)); \
  if ((KT) + 3 < nk) stage((S0), (KT) + 3); \
  MFMA16(AFC, BFC); }

  stage(0, 0); stage(1, 1); stage(2, 2);
  asm volatile("s_waitcnt vmcnt(8)" ::: "memory");  // retire stage(0)
  __builtin_amdgcn_s_barrier();
  asm volatile("" ::: "memory");
  DSREAD(afA, bfA, 0);

  int s0 = 0, s1 = 1;
  for (int kt = 0; kt < nk; kt += 2) {
    GITER(kt, s0, s1, afA, bfA, afB, bfB);
    int s2 = (s1 == 2) ? 0 : s1 + 1;
    GITER(kt + 1, s1, s2, afB, bfB, afA, bfA);
    s0 = s2; s1 = (s2 == 2) ? 0 : s2 + 1;
  }
#undef GITER
#undef MFMA16
#undef DSREAD

  #pragma unroll
  for (int ni = 0; ni < 4; ++ni) {
    size_t col = n0 + wn * 64 + ni * 16 + lr;
    float bv = bias[col];
    #pragma unroll
    for (int mi = 0; mi < 4; ++mi) {
      #pragma unroll
      for (int j = 0; j < 4; ++j) {
        size_t row = m0 + wm * 64 + mi * 16 + g * 4 + j;
        float v = acc[mi][ni][j] + bv;
        if (EPI == 3) {
          int b = (int)(row >> 9);
          int tok = keepIdx[row];
          const float* rr = xsrc + ((size_t)(b << 10) + tok) * Dd;
          ((float*)C)[row * (size_t)Nd + col] = v + rr[col];
        } else {
          epi_store<EPI>(C, res, Nd, row, col, v);
        }
      }
    }
  }
}

// ---------------- V transpose per (b,h): qkv v-slice -> vT[bh][80][512] ----------------
__global__ __launch_bounds__(256) void vtrans_kernel(const __hip_bfloat16* __restrict__ qkv,
                                                     __hip_bfloat16* __restrict__ vT) {
  int bh = blockIdx.x;
  int b = bh >> 4, h = bh & 15;
  __shared__ __align__(16) __hip_bfloat16 Vl[256 * 72];
  int tid = threadIdx.x;
  const __hip_bfloat16 zb = __float2bfloat16(0.0f);
  for (int half = 0; half < 2; ++half) {
    __syncthreads();
    for (int idx = tid; idx < 256 * 18; idx += 256) {
      int t = idx / 18, c = idx % 18;
      *(ushort4*)&Vl[t * 72 + c * 4] =
          *(const ushort4*)&qkv[((size_t)(b * 512 + half * 256 + t)) * 3456 + 2304 + h * 72 + c * 4];
    }
    __syncthreads();
    for (int idx = tid; idx < 80 * 256; idx += 256) {
      int d = idx >> 8, t = idx & 255;
      vT[((size_t)bh * 80 + d) * 512 + half * 256 + t] = (d < 72) ? Vl[t * 72 + d] : zb;
    }
  }
}

// ---------------- flash attention per (b,h,q-tile 64) ----------------
// Qs/Ks stride 104 elem (208 B): bank-group walk (row*52)%32 covers all 8 groups x2
// lanes = conflict-free.
__global__ __launch_bounds__(256) void attn_kernel(const __hip_bfloat16* __restrict__ qkv,
    const __hip_bfloat16* __restrict__ vT, __hip_bfloat16* __restrict__ o) {
  const int blk = blockIdx.x;
  const int qt = blk & 7, bh = blk >> 3;
  const int b = bh >> 4, h = bh & 15;
  __shared__ __align__(16) __hip_bfloat16 Qs[64][104];
  __shared__ __align__(16) __hip_bfloat16 Ks[64][104];
  __shared__ __align__(16) __hip_bfloat16 Vs[80][72];
  __shared__ __align__(16) __hip_bfloat16 Ps[4][16][72];
  const int tid = threadIdx.x, wid = tid >> 6, lane = tid & 63;
  const int g = lane >> 4, lr = lane & 15;
  const __hip_bfloat16 zb = __float2bfloat16(0.0f);

  for (int idx = tid; idx < 64 * 18; idx += 256) {
    int r = idx / 18, c = idx % 18;
    *(ushort4*)&Qs[r][c * 4] =
        *(const ushort4*)&qkv[((size_t)(b * 512 + qt * 64 + r)) * 3456 + h * 72 + c * 4];
  }
  for (int idx = tid; idx < 64 * 32; idx += 256) {
    int r = idx / 32, d = 72 + idx % 32;
    Qs[r][d] = zb; Ks[r][d] = zb;
  }

  f32x4 ov[5];
  const f32x4 zf = {0.f, 0.f, 0.f, 0.f};
  #pragma unroll
  for (int ni = 0; ni < 5; ++ni) ov[ni] = zf;
  float m_[4], l_[4];
  #pragma unroll
  for (int j = 0; j < 4; ++j) { m_[j] = -3.0e38f; l_[j] = 0.f; }
  const float scale = 0.11785113019775793f;  // 1/sqrt(72)

  for (int c = 0; c < 8; ++c) {
    __syncthreads();
    for (int idx = tid; idx < 64 * 18; idx += 256) {
      int r = idx / 18, cc = idx % 18;
      *(ushort4*)&Ks[r][cc * 4] =
          *(const ushort4*)&qkv[((size_t)(b * 512 + c * 64 + r)) * 3456 + 1152 + h * 72 + cc * 4];
    }
    for (int idx = tid; idx < 80 * 8; idx += 256) {
      int d = idx >> 3, t8 = idx & 7;
      *(uint4*)&Vs[d][t8 * 8] =
          *(const uint4*)&vT[((size_t)bh * 80 + d) * 512 + c * 64 + t8 * 8];
    }
    __syncthreads();

    f32x4 sf[4];
    #pragma unroll
    for (int nf = 0; nf < 4; ++nf) sf[nf] = zf;
    #pragma unroll
    for (int ks = 0; ks < 3; ++ks) {
      bf16x8 qa = *(const bf16x8*)&Qs[wid * 16 + lr][ks * 32 + g * 8];
      #pragma unroll
      for (int nf = 0; nf < 4; ++nf) {
        bf16x8 kb = *(const bf16x8*)&Ks[nf * 16 + lr][ks * 32 + g * 8];
        sf[nf] = __builtin_amdgcn_mfma_f32_16x16x32_bf16(qa, kb, sf[nf], 0, 0, 0);
      }
    }

    float cm[4];
    #pragma unroll
    for (int j = 0; j < 4; ++j)
      cm[j] = fmaxf(fmaxf(sf[0][j], sf[1][j]), fmaxf(sf[2][j], sf[3][j])) * scale;
    #pragma unroll
    for (int mm = 1; mm < 16; mm <<= 1)
      #pragma unroll
      for (int j = 0; j < 4; ++j) cm[j] = fmaxf(cm[j], __shfl_xor(cm[j], mm));
    float fac[4], rs[4];
    #pragma unroll
    for (int j = 0; j < 4; ++j) {
      float nm = fmaxf(m_[j], cm[j]);
      fac[j] = __expf(m_[j] - nm);
      m_[j] = nm;
      rs[j] = 0.f;
    }
    #pragma unroll
    for (int nf = 0; nf < 4; ++nf)
      #pragma unroll
      for (int j = 0; j < 4; ++j) {
        float pv = __expf(sf[nf][j] * scale - m_[j]);
        rs[j] += pv;
        Ps[wid][g * 4 + j][nf * 16 + lr] = __float2bfloat16(pv);
      }
    #pragma unroll
    for (int mm = 1; mm < 16; mm <<= 1)
      #pragma unroll
      for (int j = 0; j < 4; ++j) rs[j] += __shfl_xor(rs[j], mm);
    #pragma unroll
    for (int j = 0; j < 4; ++j) l_[j] = l_[j] * fac[j] + rs[j];
    #pragma unroll
    for (int ni = 0; ni < 5; ++ni)
      #pragma unroll
      for (int j = 0; j < 4; ++j) ov[ni][j] *= fac[j];

    #pragma unroll
    for (int k2 = 0; k2 < 2; ++k2) {
      bf16x8 pa = *(const bf16x8*)&Ps[wid][lr][k2 * 32 + g * 8];
      #pragma unroll
      for (int ni = 0; ni < 5; ++ni) {
        bf16x8 vb = *(const bf16x8*)&Vs[ni * 16 + lr][k2 * 32 + g * 8];
        ov[ni] = __builtin_amdgcn_mfma_f32_16x16x32_bf16(pa, vb, ov[ni], 0, 0, 0);
      }
    }
  }

  #pragma unroll
  for (int ni = 0; ni < 5; ++ni) {
    int d = ni * 16 + lr;
    if (d < 72) {
      #pragma unroll
      for (int j = 0; j < 4; ++j) {
        int t = qt * 64 + wid * 16 + g * 4 + j;
        o[((size_t)(b * 512 + t)) * 1152 + h * 72 + d] = __float2bfloat16(ov[ni][j] / l_[j]);
      }
    }
  }
}

// ---------------- final recovery: out[b,n,:] = yout[b, src_row[b,n], :] ----------------
__global__ __launch_bounds__(256) void recover_kernel(const float* __restrict__ yout,
    const int* __restrict__ srow, float* __restrict__ out) {
  int idx = blockIdx.x * 256 + threadIdx.x;  // over B*N*288 float4s
  int q = idx % 288;
  int bnv = idx / 288;  // b*1024+n
  int r = srow[bnv];
  int b = bnv >> 10;
  const float4* src = (const float4*)yout + ((size_t)((b << 9) + r)) * 288 + q;
  ((float4*)out)[idx] = *src;
}

}  // namespace

extern "C" void kernel_launch(void* const* d_in, const int* in_sizes, int n_in,
                              void* d_out, int out_size, void* d_ws, size_t ws_size,
                              hipStream_t stream) {
  (void)in_sizes; (void)n_in; (void)out_size; (void)ws_size;
  const float* x      = (const float*)d_in[0];
  const float* noise  = (const float*)d_in[1];
  const float* ln1_g  = (const float*)d_in[2];
  const float* ln1_b  = (const float*)d_in[3];
  const float* ln2_g  = (const float*)d_in[4];
  const float* ln2_b  = (const float*)d_in[5];
  const float* w_qkv  = (const float*)d_in[6];
  const float* b_qkv  = (const float*)d_in[7];
  const float* w_proj = (const float*)d_in[8];
  const float* b_proj = (const float*)d_in[9];
  const float* w_fc1  = (const float*)d_in[10];
  const float* b_fc1  = (const float*)d_in[11];
  const float* w_fc2  = (const float*)d_in[12];
  const float* b_fc2  = (const float*)d_in[13];
  float* out = (float*)d_out;

  char* p = (char*)d_ws;
  auto alloc = [&](size_t bytes) {
    char* r = p;
    p += (bytes + 255) & ~(size_t)255;
    return r;
  };
  __hip_bfloat16* wqkvT  = (__hip_bfloat16*)alloc((size_t)3584 * 1152 * 2);
  __hip_bfloat16* wprojT = (__hip_bfloat16*)alloc((size_t)1280 * 1152 * 2);
  __hip_bfloat16* wfc1T  = (__hip_bfloat16*)alloc((size_t)4608 * 1152 * 2);
  __hip_bfloat16* wfc2T  = (__hip_bfloat16*)alloc((size_t)1280 * 4608 * 2);
  float* inv = (float*)alloc(16384 * 4);
  int* dsti  = (int*)alloc(4096 * 4);
  int* srci  = (int*)alloc(12288 * 4);
  float* mx  = (float*)alloc(12288 * 4);
  int* best  = (int*)alloc(12288 * 4);
  int* keep  = (int*)alloc(8192 * 4);
  int* srow  = (int*)alloc(16384 * 4);
  float* yout = (float*)alloc((size_t)8192 * 1152 * 4);
  __hip_bfloat16* y1   = (__hip_bfloat16*)alloc((size_t)8192 * 1152 * 2);  // also y2
  __hip_bfloat16* qkvb = (__hip_bfloat16*)alloc((size_t)8192 * 4608 * 2);  // also h (fc1 out)
  __hip_bfloat16* vT   = (__hip_bfloat16*)alloc((size_t)256 * 80 * 512 * 2);
  __hip_bfloat16* ob   = (__hip_bfloat16*)alloc((size_t)8192 * 1152 * 2);
  float* x2 = (float*)alloc((size_t)8192 * 1152 * 4);

  // xn hi/lo planes alias qkvb (dead until gemm writes it, exactly 2x 37.75MB)
  __hip_bfloat16* xnh = qkvb;
  __hip_bfloat16* xnl = qkvb + (size_t)16 * 1024 * 1152;

  // weights -> bf16 transposed
  wtrans_kernel<<<36 * 108, 256, 0, stream>>>(w_qkv, wqkvT, 1152, 3456);
  wtrans_kernel<<<36 * 36, 256, 0, stream>>>(w_proj, wprojT, 1152, 1152);
  wtrans_kernel<<<36 * 144, 256, 0, stream>>>(w_fc1, wfc1T, 1152, 4608);
  wtrans_kernel<<<144 * 36, 256, 0, stream>>>(w_fc2, wfc2T, 4608, 1152);

  // SiTo indices (norm + window fused)
  normwin_kernel<<<4096, 256, 0, stream>>>(x, noise, inv, xnh, xnl, dsti, srci);
  simgemm_kernel<<<16 * 12, 256, 0, stream>>>(xnh, xnl, dsti, srci, mx, best);
  rank_kernel<<<16, 256, 0, stream>>>(mx, best, dsti, srci, keep, srow);

  // DiT block on kept tokens
  ln_kernel<1><<<8192, 256, 0, stream>>>(x, keep, ln1_g, ln1_b, y1);
  gemm128_kernel<0><<<64 * 14, 512, 0, stream>>>(y1, wqkvT, b_qkv, nullptr,
                                                 qkvb, 8192, 3456, 3584, 1152);
  vtrans_kernel<<<256, 256, 0, stream>>>(qkvb, vT);
  attn_kernel<<<2048, 256, 0, stream>>>(qkvb, vT, ob);
  gemm128v_kernel<3><<<64 * 9, 256, 0, stream>>>(ob, wprojT, b_proj, nullptr, keep, x,
                                                 x2, 8192, 1152, 1152);
  ln_kernel<0><<<8192, 256, 0, stream>>>(x2, nullptr, ln2_g, ln2_b, y1);
  gemm128v_kernel<2><<<64 * 36, 256, 0, stream>>>(y1, wfc1T, b_fc1, nullptr, nullptr, nullptr,
                                                  qkvb, 8192, 4608, 1152);
  gemm128v_kernel<1><<<64 * 9, 256, 0, stream>>>(qkvb, wfc2T, b_fc2, x2, nullptr, nullptr,
                                                 yout, 8192, 1152, 4608);

  // scatter-as-gather recovery
  recover_kernel<<<18432, 256, 0, stream>>>(yout, srow, out);
}

// Round 17
// 700.625 us; speedup vs baseline: 1.0590x; 1.0479x over previous
//
#include <hip/hip_runtime.h>
#include <hip/hip_bf16.h>

namespace {

constexpr int Dd = 1152;

typedef __attribute__((ext_vector_type(8))) short bf16x8;
typedef __attribute__((ext_vector_type(4))) float f32x4;

__device__ __forceinline__ void gload_lds16(const void* g, void* l) {
  __builtin_amdgcn_global_load_lds(
      (const __attribute__((address_space(1))) void*)g,
      (__attribute__((address_space(3))) void*)l, 16, 0, 0);
}

__device__ __forceinline__ float gelu_f(float x) {
  float x3 = x * x * x;
  float z2 = 1.5957691216057308f * (x + 0.044715f * x3);
  float e = __expf(fminf(z2, 30.0f));
  return x * e / (e + 1.0f);
}

// ---------------- fused norm + window scoring ----------------
__global__ __launch_bounds__(256) void normwin_kernel(const float* __restrict__ x,
    const float* __restrict__ noise, float* __restrict__ inv,
    __hip_bfloat16* __restrict__ xnh, __hip_bfloat16* __restrict__ xnl,
    int* __restrict__ dsti, int* __restrict__ srci) {
  const int gidx = blockIdx.x;  // b*256 + w
  const int b = gidx >> 8, w = gidx & 255;
  const int wy = w >> 4, wx = w & 15;
  const int t0 = wy * 64 + wx * 2;
  const int wid = threadIdx.x >> 6, lane = threadIdx.x & 63;
  const int tok = t0 + (wid >> 1) * 32 + (wid & 1);
  const int row = (b << 10) + tok;

  const float2* xr = (const float2*)(x + (size_t)row * Dd);
  float2 v[9];
  float s = 0.f;
  #pragma unroll
  for (int e = 0; e < 9; ++e) {
    v[e] = xr[lane + 64 * e];
    s += v[e].x * v[e].x + v[e].y * v[e].y;
  }
  #pragma unroll
  for (int m = 1; m < 64; m <<= 1) s += __shfl_xor(s, m);
  float iv = 1.0f / (sqrtf(s) + 1e-6f);
  if (lane == 0) inv[row] = iv;

  __shared__ float2 xns[4][576];
  ushort2* ph = (ushort2*)(xnh + (size_t)row * Dd);
  ushort2* pl = (ushort2*)(xnl + (size_t)row * Dd);
  #pragma unroll
  for (int e = 0; e < 9; ++e) {
    float ax = v[e].x * iv, ay = v[e].y * iv;
    xns[wid][lane + 64 * e] = make_float2(ax, ay);
    __hip_bfloat16 hx = __float2bfloat16(ax), hy = __float2bfloat16(ay);
    __hip_bfloat16 lx = __float2bfloat16(ax - __bfloat162float(hx));
    __hip_bfloat16 ly = __float2bfloat16(ay - __bfloat162float(hy));
    ph[lane + 64 * e] = make_ushort2(*(ushort*)&hx, *(ushort*)&hy);
    pl[lane + 64 * e] = make_ushort2(*(ushort*)&lx, *(ushort*)&ly);
  }
  __syncthreads();

  float dot = 0.f;
  #pragma unroll
  for (int e = 0; e < 9; ++e) {
    int i = lane + 64 * e;
    float2 a0 = xns[0][i], a1 = xns[1][i], a2 = xns[2][i], a3 = xns[3][i];
    float sx = a0.x + a1.x + a2.x + a3.x;
    float sy = a0.y + a1.y + a2.y + a3.y;
    dot += (v[e].x * iv) * sx + (v[e].y * iv) * sy;
  }
  #pragma unroll
  for (int m = 1; m < 64; m <<= 1) dot += __shfl_xor(dot, m);
  __shared__ float dots[4];
  if (lane == 0) dots[wid] = dot;
  __syncthreads();
  if (threadIdx.x == 0) {
    float best = -1e30f; int bj = 0;
    #pragma unroll
    for (int j = 0; j < 4; ++j) {
      float sc = 0.25f * dots[j] + 0.1f * noise[(size_t)gidx * 4 + j];
      if (sc > best) { best = sc; bj = j; }  // strict > = first-max
    }
    int tk[4] = {t0, t0 + 1, t0 + 32, t0 + 33};
    dsti[b * 256 + w] = tk[bj];
    int m = 0;
    #pragma unroll
    for (int j = 0; j < 4; ++j) if (j != bj) srci[b * 768 + w * 3 + (m++)] = tk[j];
  }
}

// ---------------- sim GEMM (split-bf16 MFMA): per-src (max, argmax) over 256 dst ----------
__global__ __launch_bounds__(256) void simgemm_kernel(
    const __hip_bfloat16* __restrict__ xnh, const __hip_bfloat16* __restrict__ xnl,
    const int* __restrict__ dsti, const int* __restrict__ srci,
    float* __restrict__ mx, int* __restrict__ best) {
  int b = blockIdx.x / 12;
  int m0 = (blockIdx.x % 12) * 64;
  __shared__ __align__(16) __hip_bfloat16 AsH[2][64 * 32];
  __shared__ __align__(16) __hip_bfloat16 AsL[2][64 * 32];
  __shared__ __align__(16) __hip_bfloat16 BsH[2][256 * 32];
  __shared__ __align__(16) __hip_bfloat16 BsL[2][256 * 32];
  const int tid = threadIdx.x, wid = tid >> 6, lane = tid & 63;
  const int g = lane >> 4, lr = lane & 15;

  const int slotRow = tid >> 2;        // 0..63
  const int colByte = (((tid & 3) ^ ((tid >> 3) & 3)) << 4);
  size_t aRow = (size_t)((b << 10) + srci[b * 768 + m0 + slotRow]) * Dd;
  size_t bRow[4];
  #pragma unroll
  for (int p = 0; p < 4; ++p)
    bRow[p] = (size_t)((b << 10) + dsti[b * 256 + p * 64 + slotRow]) * Dd;
  const char* xh = (const char*)xnh;
  const char* xl = (const char*)xnl;

  auto stage = [&](int buf, int k0) {
    size_t ka = (aRow + k0) * 2 + colByte;
    gload_lds16(xh + ka, (char*)AsH + buf * 4096 + wid * 1024);
    gload_lds16(xl + ka, (char*)AsL + buf * 4096 + wid * 1024);
    #pragma unroll
    for (int p = 0; p < 4; ++p) {
      size_t kb = (bRow[p] + k0) * 2 + colByte;
      gload_lds16(xh + kb, (char*)BsH + buf * 16384 + p * 4096 + wid * 1024);
      gload_lds16(xl + kb, (char*)BsL + buf * 16384 + p * 4096 + wid * 1024);
    }
  };

  f32x4 hh[16], hx[16];
  const f32x4 zf = {0.f, 0.f, 0.f, 0.f};
  #pragma unroll
  for (int nf = 0; nf < 16; ++nf) { hh[nf] = zf; hx[nf] = zf; }

  const int roff = ((g ^ ((lr >> 1) & 3)) << 3);
  stage(0, 0);
  asm volatile("s_waitcnt vmcnt(0)" ::: "memory");
  __syncthreads();
  int buf = 0;
  for (int ks = 0; ks < 36; ++ks) {
    if (ks + 1 < 36) stage(buf ^ 1, (ks + 1) * 32);
    bf16x8 ah = *(const bf16x8*)&AsH[buf][(wid * 16 + lr) * 32 + roff];
    bf16x8 al = *(const bf16x8*)&AsL[buf][(wid * 16 + lr) * 32 + roff];
    #pragma unroll
    for (int nf = 0; nf < 16; ++nf) {
      bf16x8 bh = *(const bf16x8*)&BsH[buf][(nf * 16 + lr) * 32 + roff];
      bf16x8 bl = *(const bf16x8*)&BsL[buf][(nf * 16 + lr) * 32 + roff];
      hh[nf] = __builtin_amdgcn_mfma_f32_16x16x32_bf16(ah, bh, hh[nf], 0, 0, 0);
      hx[nf] = __builtin_amdgcn_mfma_f32_16x16x32_bf16(ah, bl, hx[nf], 0, 0, 0);
      hx[nf] = __builtin_amdgcn_mfma_f32_16x16x32_bf16(al, bh, hx[nf], 0, 0, 0);
    }
    asm volatile("s_waitcnt vmcnt(0)" ::: "memory");
    __syncthreads();
    buf ^= 1;
  }

  #pragma unroll
  for (int j = 0; j < 4; ++j) {
    float bv = -1e30f; int bi = 0;
    #pragma unroll
    for (int nf = 0; nf < 16; ++nf) {
      float v = hh[nf][j] + hx[nf][j];
      if (v > bv) { bv = v; bi = nf * 16 + lr; }
    }
    #pragma unroll
    for (int m = 1; m < 16; m <<= 1) {
      float ov = __shfl_xor(bv, m);
      int oi = __shfl_xor(bi, m);
      if (ov > bv || (ov == bv && oi < bi)) { bv = ov; bi = oi; }
    }
    if (lr == 0) {
      int row = m0 + wid * 16 + g * 4 + j;
      mx[b * 768 + row] = bv;
      best[b * 768 + row] = bi;
    }
  }
}

// ---------------- rank (stable argsort of -mx) -> keep_token + src_row ----------------
__global__ __launch_bounds__(256) void rank_kernel(const float* __restrict__ mx,
    const int* __restrict__ best, const int* __restrict__ dsti,
    const int* __restrict__ srci, int* __restrict__ keep, int* __restrict__ srow) {
  int b = blockIdx.x;
  int tid = threadIdx.x;
  __shared__ float smx[768];
  for (int i = tid; i < 768; i += 256) smx[i] = mx[b * 768 + i];
  __syncthreads();
  if (tid < 256) {
    int t = dsti[b * 256 + tid];
    keep[b * 512 + tid] = t;
    srow[b * 1024 + t] = tid;
  }
  for (int i = tid; i < 768; i += 256) {
    float v = smx[i];
    int r = 0;
    for (int s = 0; s < 768; ++s) {
      float u = smx[s];
      r += (u > v) || (u == v && s < i);
    }
    int tok = srci[b * 768 + i];
    if (r >= 512) {
      keep[b * 512 + (r - 256)] = tok;      // xk row = 256 + (r-512)
      srow[b * 1024 + tok] = r - 256;
    } else {
      srow[b * 1024 + tok] = best[b * 768 + i];  // copy dst-row output
    }
  }
}

// ---------------- LayerNorm (optionally gathered) ----------------
template<int GATHER>
__global__ __launch_bounds__(256) void ln_kernel(const float* __restrict__ xin,
    const int* __restrict__ keep, const float* __restrict__ gw,
    const float* __restrict__ bw, __hip_bfloat16* __restrict__ yout) {
  int row = blockIdx.x;  // 0..8191
  const float* xr;
  if (GATHER) {
    int b = row >> 9, t = row & 511;
    int tok = keep[(b << 9) + t];
    xr = xin + (size_t)((b << 10) + tok) * Dd;
  } else {
    xr = xin + (size_t)row * Dd;
  }
  int tid = threadIdx.x;
  float v[5];
  float s = 0.f, s2 = 0.f;
  #pragma unroll
  for (int e = 0; e < 5; ++e) {
    int i = tid + e * 256;
    float val = (i < Dd) ? xr[i] : 0.f;
    v[e] = val; s += val; s2 += val * val;
  }
  #pragma unroll
  for (int m = 1; m < 64; m <<= 1) { s += __shfl_xor(s, m); s2 += __shfl_xor(s2, m); }
  __shared__ float ps[4], ps2[4];
  int wid = tid >> 6, lane = tid & 63;
  if (lane == 0) { ps[wid] = s; ps2[wid] = s2; }
  __syncthreads();
  s = ps[0] + ps[1] + ps[2] + ps[3];
  s2 = ps2[0] + ps2[1] + ps2[2] + ps2[3];
  constexpr float inv_d = 1.0f / Dd;
  float mu = s * inv_d;
  float var = s2 * inv_d - mu * mu;
  float rstd = rsqrtf(var + 1e-6f);
  __hip_bfloat16* yr = yout + (size_t)row * Dd;
  #pragma unroll
  for (int e = 0; e < 5; ++e) {
    int i = tid + e * 256;
    if (i < Dd) {
      yr[i] = __float2bfloat16((v[e] - mu) * rstd * gw[i] + bw[i]);
    }
  }
}

// ---------------- fused weight transpose + bf16 cast for all four weights ----------------
// segment table: [0,3888): qkv (K1152,N3456); [3888,5184): proj (1152,1152);
// [5184,10368): fc1 (1152,4608); [10368,15552): fc2 (4608,1152)
__global__ __launch_bounds__(256) void wtrans_all_kernel(
    const float* __restrict__ w0, __hip_bfloat16* __restrict__ o0,
    const float* __restrict__ w1, __hip_bfloat16* __restrict__ o1,
    const float* __restrict__ w2, __hip_bfloat16* __restrict__ o2,
    const float* __restrict__ w3, __hip_bfloat16* __restrict__ o3) {
  __shared__ float tile[32][33];
  int bid = blockIdx.x;
  const float* w; __hip_bfloat16* wT; int K, N, local;
  if (bid < 3888)       { w = w0; wT = o0; K = 1152; N = 3456; local = bid; }
  else if (bid < 5184)  { w = w1; wT = o1; K = 1152; N = 1152; local = bid - 3888; }
  else if (bid < 10368) { w = w2; wT = o2; K = 1152; N = 4608; local = bid - 5184; }
  else                  { w = w3; wT = o3; K = 4608; N = 1152; local = bid - 10368; }
  int nt = N >> 5;
  int tk = local / nt, tn = local % nt;
  int tid = threadIdx.x;
  #pragma unroll
  for (int e = 0; e < 4; ++e) {
    int idx = tid + e * 256;
    int r = idx >> 5, c = idx & 31;
    tile[r][c] = w[(size_t)(tk * 32 + r) * N + tn * 32 + c];
  }
  __syncthreads();
  #pragma unroll
  for (int e = 0; e < 4; ++e) {
    int idx = tid + e * 256;
    int r = idx >> 5, c = idx & 31;
    wT[(size_t)(tn * 32 + r) * K + tk * 32 + c] = __float2bfloat16(tile[c][r]);
  }
}

// ============ GEMM epilogue helper ============
template<int EPI>
__device__ __forceinline__ void epi_store(void* C, const float* res, int Nd,
                                          size_t row, size_t col, float v) {
  if (EPI == 0) {
    ((__hip_bfloat16*)C)[row * (size_t)Nd + col] = __float2bfloat16(v);
  } else if (EPI == 1) {
    ((float*)C)[row * (size_t)Nd + col] = v + res[row * (size_t)Nd + col];
  } else if (EPI == 2) {
    ((__hip_bfloat16*)C)[row * (size_t)Nd + col] = __float2bfloat16(gelu_f(v));
  }
}

// ---------------- GEMM 128x256 lockstep (8 waves, 2 blk/CU) — qkv ----------
// EPI==4: cols < 2304 (Q,K) -> qkvb bf16; cols >= 2304 (V) -> direct transposed
// store into vT[bh][d][t] (fuses away the vtrans kernel).
template<int EPI>
__global__ __launch_bounds__(512, 4) void gemm128_kernel(
    const __hip_bfloat16* __restrict__ A, const __hip_bfloat16* __restrict__ BT,
    const float* __restrict__ bias, const float* __restrict__ res,
    __hip_bfloat16* __restrict__ vTout,
    void* __restrict__ C, int Md, int Nd, int NdPad, int Kd) {
  constexpr int BM = 128;
  __shared__ __align__(16) __hip_bfloat16 As[3][BM * 32];
  __shared__ __align__(16) __hip_bfloat16 Bs[3][256 * 32];
  const int nb = NdPad >> 8;
  const int q8 = gridDim.x >> 3;
  const int wg = (blockIdx.x & 7) * q8 + (blockIdx.x >> 3);
  const int bm = wg / nb, bnb = wg % nb;
  const int tid = threadIdx.x, wid = tid >> 6, lane = tid & 63;
  const int g = lane >> 4, lr = lane & 15;
  const int wm = wid >> 2, wn = wid & 3;
  const size_t m0 = (size_t)bm * BM, n0 = (size_t)bnb * 256;

  const int trow = tid >> 2;
  const int scol = (((tid & 3) ^ ((tid >> 3) & 3)) << 3);
  const char* Ab = (const char*)A;
  const char* Bb = (const char*)BT;

  auto stage = [&](int slot, int kt) {
    const size_t kb = ((size_t)kt << 5) + scol;
    gload_lds16(Ab + (((m0 + trow) * (size_t)Kd + kb) << 1),
                (char*)As + slot * 8192 + wid * 1024);
    gload_lds16(Bb + (((n0 + trow) * (size_t)Kd + kb) << 1),
                (char*)Bs + slot * 16384 + wid * 1024);
    gload_lds16(Bb + (((n0 + 128 + trow) * (size_t)Kd + kb) << 1),
                (char*)Bs + slot * 16384 + 8192 + wid * 1024);
  };

  f32x4 acc[4][4];
  const f32x4 zf = {0.f, 0.f, 0.f, 0.f};
  #pragma unroll
  for (int mi = 0; mi < 4; ++mi)
    #pragma unroll
    for (int ni = 0; ni < 4; ++ni) acc[mi][ni] = zf;

  const int nk = Kd >> 5;
  stage(0, 0);
  stage(1, 1);
  asm volatile("s_waitcnt vmcnt(3)" ::: "memory");
  __builtin_amdgcn_s_barrier();

  int cur = 0;
  const int roff = ((g ^ ((lr >> 1) & 3)) << 3);
  for (int kt = 0; kt < nk; ++kt) {
    const __hip_bfloat16* Ac = As[cur];
    const __hip_bfloat16* Bc = Bs[cur];
    bf16x8 af[4], bf[4];
    #pragma unroll
    for (int mi = 0; mi < 4; ++mi)
      af[mi] = *(const bf16x8*)&Ac[(wm * 64 + mi * 16 + lr) * 32 + roff];
    #pragma unroll
    for (int ni = 0; ni < 4; ++ni)
      bf[ni] = *(const bf16x8*)&Bc[(wn * 64 + ni * 16 + lr) * 32 + roff];
    if (kt + 2 < nk) stage(cur == 0 ? 2 : cur - 1, kt + 2);
    __builtin_amdgcn_s_barrier();
    __builtin_amdgcn_s_setprio(1);
    #pragma unroll
    for (int mi = 0; mi < 4; ++mi)
      #pragma unroll
      for (int ni = 0; ni < 4; ++ni)
        acc[mi][ni] = __builtin_amdgcn_mfma_f32_16x16x32_bf16(af[mi], bf[ni], acc[mi][ni], 0, 0, 0);
    __builtin_amdgcn_s_setprio(0);
    if (kt + 2 < nk)      asm volatile("s_waitcnt vmcnt(3)" ::: "memory");
    else if (kt + 1 < nk) asm volatile("s_waitcnt vmcnt(0)" ::: "memory");
    __builtin_amdgcn_s_barrier();
    cur = (cur == 2) ? 0 : cur + 1;
  }

  #pragma unroll
  for (int ni = 0; ni < 4; ++ni) {
    size_t col = n0 + wn * 64 + ni * 16 + lr;
    if (col < (size_t)Nd) {
      float bv = bias[col];
      if (EPI == 4 && col >= 2304) {
        int vc = (int)col - 2304;
        int h = vc / 72, d = vc % 72;
        #pragma unroll
        for (int mi = 0; mi < 4; ++mi) {
          #pragma unroll
          for (int j = 0; j < 4; ++j) {
            size_t row = m0 + wm * 64 + mi * 16 + g * 4 + j;
            int bb = (int)(row >> 9), t = (int)(row & 511);
            vTout[(((size_t)(bb * 16 + h)) * 80 + d) * 512 + t] =
                __float2bfloat16(acc[mi][ni][j] + bv);
          }
        }
      } else {
        #pragma unroll
        for (int mi = 0; mi < 4; ++mi) {
          #pragma unroll
          for (int j = 0; j < 4; ++j) {
            size_t row = m0 + wm * 64 + mi * 16 + g * 4 + j;
            float v = acc[mi][ni][j] + bv;
            if (EPI == 4) {
              ((__hip_bfloat16*)C)[row * (size_t)Nd + col] = __float2bfloat16(v);
            } else {
              epi_store<EPI>(C, res, Nd, row, col, v);
            }
          }
        }
      }
    }
  }
}

// ---------------- GEMM 128x128, 4 waves, 3 blk/CU, reg-double-buffered overlap ----------
template<int EPI>
__global__ __launch_bounds__(256, 3) void gemm128v_kernel(
    const __hip_bfloat16* __restrict__ A, const __hip_bfloat16* __restrict__ BT,
    const float* __restrict__ bias, const float* __restrict__ res,
    const int* __restrict__ keepIdx, const float* __restrict__ xsrc,
    void* __restrict__ C, int Md, int Nd, int Kd) {
  __shared__ __align__(16) __hip_bfloat16 As[3][128 * 32];
  __shared__ __align__(16) __hip_bfloat16 Bs[3][128 * 32];
  const int nb = Nd >> 7;
  const int q8 = gridDim.x >> 3;
  const int wg = (blockIdx.x & 7) * q8 + (blockIdx.x >> 3);
  const int bm = wg / nb, bnb = wg % nb;
  const int tid = threadIdx.x, wid = tid >> 6, lane = tid & 63;
  const int g = lane >> 4, lr = lane & 15;
  const int wm = wid >> 1, wn = wid & 1;  // wave tile 64x64
  const size_t m0 = (size_t)bm * 128, n0 = (size_t)bnb * 128;

  const int trow = tid >> 2;  // 0..63
  const int scol = (((tid & 3) ^ ((tid >> 3) & 3)) << 3);
  const char* Ab = (const char*)A;
  const char* Bb = (const char*)BT;

  auto stage = [&](int slot, int kt) {
    const size_t kb = ((size_t)kt << 5) + scol;
    #pragma unroll
    for (int c = 0; c < 2; ++c)
      gload_lds16(Ab + (((m0 + c * 64 + trow) * (size_t)Kd + kb) << 1),
                  (char*)As + slot * 8192 + c * 4096 + tid * 16);
    #pragma unroll
    for (int c = 0; c < 2; ++c)
      gload_lds16(Bb + (((n0 + c * 64 + trow) * (size_t)Kd + kb) << 1),
                  (char*)Bs + slot * 8192 + c * 4096 + tid * 16);
  };

  f32x4 acc[4][4];
  const f32x4 zf = {0.f, 0.f, 0.f, 0.f};
  #pragma unroll
  for (int mi = 0; mi < 4; ++mi)
    #pragma unroll
    for (int ni = 0; ni < 4; ++ni) acc[mi][ni] = zf;

  const int roff = ((g ^ ((lr >> 1) & 3)) << 3);
  const int nk = Kd >> 5;

  bf16x8 afA[4], bfA[4], afB[4], bfB[4];

#define DSREAD(AF, BF, SLOT) { \
  const __hip_bfloat16* Ac_ = As[SLOT]; \
  const __hip_bfloat16* Bc_ = Bs[SLOT]; \
  _Pragma("unroll") for (int mi_ = 0; mi_ < 4; ++mi_) \
    AF[mi_] = *(const bf16x8*)&Ac_[(wm * 64 + mi_ * 16 + lr) * 32 + roff]; \
  _Pragma("unroll") for (int ni_ = 0; ni_ < 4; ++ni_) \
    BF[ni_] = *(const bf16x8*)&Bc_[(wn * 64 + ni_ * 16 + lr) * 32 + roff]; }

#define MFMA16(AF, BF) { \
  __builtin_amdgcn_s_setprio(1); \
  _Pragma("unroll") for (int mi_ = 0; mi_ < 4; ++mi_) \
    _Pragma("unroll") for (int ni_ = 0; ni_ < 4; ++ni_) \
      acc[mi_][ni_] = __builtin_amdgcn_mfma_f32_16x16x32_bf16(AF[mi_], BF[ni_], acc[mi_][ni_], 0, 0, 0); \
  __builtin_amdgcn_s_setprio(0); }

#define GITER(KT, S0, S1, AFC, BFC, AFN, BFN) { \
  if ((KT) <= nk - 3)      { asm volatile("s_waitcnt vmcnt(4)" ::: "memory"); } \
  else if ((KT) == nk - 2) { asm volatile("s_waitcnt vmcnt(0)" ::: "memory"); } \
  asm volatile("s_waitcnt lgkmcnt(0)" ::: "memory"); \
  __builtin_amdgcn_s_barrier(); \
  asm volatile("" ::: "memory"); \
  if ((KT) + 1 < nk) DSREAD(AFN, BFN, (S1)); \
  if ((KT) + 3 < nk) stage((S0), (KT) + 3); \
  MFMA16(AFC, BFC); }

  stage(0, 0); stage(1, 1); stage(2, 2);
  asm volatile("s_waitcnt vmcnt(8)" ::: "memory");  // retire stage(0)
  __builtin_amdgcn_s_barrier();
  asm volatile("" ::: "memory");
  DSREAD(afA, bfA, 0);

  int s0 = 0, s1 = 1;
  for (int kt = 0; kt < nk; kt += 2) {
    GITER(kt, s0, s1, afA, bfA, afB, bfB);
    int s2 = (s1 == 2) ? 0 : s1 + 1;
    GITER(kt + 1, s1, s2, afB, bfB, afA, bfA);
    s0 = s2; s1 = (s2 == 2) ? 0 : s2 + 1;
  }
#undef GITER
#undef MFMA16
#undef DSREAD

  #pragma unroll
  for (int ni = 0; ni < 4; ++ni) {
    size_t col = n0 + wn * 64 + ni * 16 + lr;
    float bv = bias[col];
    #pragma unroll
    for (int mi = 0; mi < 4; ++mi) {
      #pragma unroll
      for (int j = 0; j < 4; ++j) {
        size_t row = m0 + wm * 64 + mi * 16 + g * 4 + j;
        float v = acc[mi][ni][j] + bv;
        if (EPI == 3) {
          int b = (int)(row >> 9);
          int tok = keepIdx[row];
          const float* rr = xsrc + ((size_t)(b << 10) + tok) * Dd;
          ((float*)C)[row * (size_t)Nd + col] = v + rr[col];
        } else {
          epi_store<EPI>(C, res, Nd, row, col, v);
        }
      }
    }
  }
}

// ---------------- flash attention per (b,h,q-tile 64) ----------------
// Qs/Ks stride 104 elem (208 B): conflict-free bank walk. Vs rows 72-79 zeroed
// in-kernel (vT rows 72-79 are never written by the fused qkv epilogue).
__global__ __launch_bounds__(256) void attn_kernel(const __hip_bfloat16* __restrict__ qkv,
    const __hip_bfloat16* __restrict__ vT, __hip_bfloat16* __restrict__ o) {
  const int blk = blockIdx.x;
  const int qt = blk & 7, bh = blk >> 3;
  const int b = bh >> 4, h = bh & 15;
  __shared__ __align__(16) __hip_bfloat16 Qs[64][104];
  __shared__ __align__(16) __hip_bfloat16 Ks[64][104];
  __shared__ __align__(16) __hip_bfloat16 Vs[80][72];
  __shared__ __align__(16) __hip_bfloat16 Ps[4][16][72];
  const int tid = threadIdx.x, wid = tid >> 6, lane = tid & 63;
  const int g = lane >> 4, lr = lane & 15;
  const __hip_bfloat16 zb = __float2bfloat16(0.0f);

  for (int idx = tid; idx < 64 * 18; idx += 256) {
    int r = idx / 18, c = idx % 18;
    *(ushort4*)&Qs[r][c * 4] =
        *(const ushort4*)&qkv[((size_t)(b * 512 + qt * 64 + r)) * 3456 + h * 72 + c * 4];
  }
  for (int idx = tid; idx < 64 * 32; idx += 256) {
    int r = idx / 32, d = 72 + idx % 32;
    Qs[r][d] = zb; Ks[r][d] = zb;
  }
  for (int idx = tid; idx < 8 * 72; idx += 256) {
    Vs[72 + idx / 72][idx % 72] = zb;  // pad rows, never re-written
  }

  f32x4 ov[5];
  const f32x4 zf = {0.f, 0.f, 0.f, 0.f};
  #pragma unroll
  for (int ni = 0; ni < 5; ++ni) ov[ni] = zf;
  float m_[4], l_[4];
  #pragma unroll
  for (int j = 0; j < 4; ++j) { m_[j] = -3.0e38f; l_[j] = 0.f; }
  const float scale = 0.11785113019775793f;  // 1/sqrt(72)

  for (int c = 0; c < 8; ++c) {
    __syncthreads();
    for (int idx = tid; idx < 64 * 18; idx += 256) {
      int r = idx / 18, cc = idx % 18;
      *(ushort4*)&Ks[r][cc * 4] =
          *(const ushort4*)&qkv[((size_t)(b * 512 + c * 64 + r)) * 3456 + 1152 + h * 72 + cc * 4];
    }
    for (int idx = tid; idx < 72 * 8; idx += 256) {
      int d = idx >> 3, t8 = idx & 7;
      *(uint4*)&Vs[d][t8 * 8] =
          *(const uint4*)&vT[((size_t)bh * 80 + d) * 512 + c * 64 + t8 * 8];
    }
    __syncthreads();

    f32x4 sf[4];
    #pragma unroll
    for (int nf = 0; nf < 4; ++nf) sf[nf] = zf;
    #pragma unroll
    for (int ks = 0; ks < 3; ++ks) {
      bf16x8 qa = *(const bf16x8*)&Qs[wid * 16 + lr][ks * 32 + g * 8];
      #pragma unroll
      for (int nf = 0; nf < 4; ++nf) {
        bf16x8 kb = *(const bf16x8*)&Ks[nf * 16 + lr][ks * 32 + g * 8];
        sf[nf] = __builtin_amdgcn_mfma_f32_16x16x32_bf16(qa, kb, sf[nf], 0, 0, 0);
      }
    }

    float cm[4];
    #pragma unroll
    for (int j = 0; j < 4; ++j)
      cm[j] = fmaxf(fmaxf(sf[0][j], sf[1][j]), fmaxf(sf[2][j], sf[3][j])) * scale;
    #pragma unroll
    for (int mm = 1; mm < 16; mm <<= 1)
      #pragma unroll
      for (int j = 0; j < 4; ++j) cm[j] = fmaxf(cm[j], __shfl_xor(cm[j], mm));
    float fac[4], rs[4];
    #pragma unroll
    for (int j = 0; j < 4; ++j) {
      float nm = fmaxf(m_[j], cm[j]);
      fac[j] = __expf(m_[j] - nm);
      m_[j] = nm;
      rs[j] = 0.f;
    }
    #pragma unroll
    for (int nf = 0; nf < 4; ++nf)
      #pragma unroll
      for (int j = 0; j < 4; ++j) {
        float pv = __expf(sf[nf][j] * scale - m_[j]);
        rs[j] += pv;
        Ps[wid][g * 4 + j][nf * 16 + lr] = __float2bfloat16(pv);
      }
    #pragma unroll
    for (int mm = 1; mm < 16; mm <<= 1)
      #pragma unroll
      for (int j = 0; j < 4; ++j) rs[j] += __shfl_xor(rs[j], mm);
    #pragma unroll
    for (int j = 0; j < 4; ++j) l_[j] = l_[j] * fac[j] + rs[j];
    #pragma unroll
    for (int ni = 0; ni < 5; ++ni)
      #pragma unroll
      for (int j = 0; j < 4; ++j) ov[ni][j] *= fac[j];

    #pragma unroll
    for (int k2 = 0; k2 < 2; ++k2) {
      bf16x8 pa = *(const bf16x8*)&Ps[wid][lr][k2 * 32 + g * 8];
      #pragma unroll
      for (int ni = 0; ni < 5; ++ni) {
        bf16x8 vb = *(const bf16x8*)&Vs[ni * 16 + lr][k2 * 32 + g * 8];
        ov[ni] = __builtin_amdgcn_mfma_f32_16x16x32_bf16(pa, vb, ov[ni], 0, 0, 0);
      }
    }
  }

  #pragma unroll
  for (int ni = 0; ni < 5; ++ni) {
    int d = ni * 16 + lr;
    if (d < 72) {
      #pragma unroll
      for (int j = 0; j < 4; ++j) {
        int t = qt * 64 + wid * 16 + g * 4 + j;
        o[((size_t)(b * 512 + t)) * 1152 + h * 72 + d] = __float2bfloat16(ov[ni][j] / l_[j]);
      }
    }
  }
}

// ---------------- final recovery: out[b,n,:] = yout[b, src_row[b,n], :] ----------------
__global__ __launch_bounds__(256) void recover_kernel(const float* __restrict__ yout,
    const int* __restrict__ srow, float* __restrict__ out) {
  int idx = blockIdx.x * 256 + threadIdx.x;  // over B*N*288 float4s
  int q = idx % 288;
  int bnv = idx / 288;  // b*1024+n
  int r = srow[bnv];
  int b = bnv >> 10;
  const float4* src = (const float4*)yout + ((size_t)((b << 9) + r)) * 288 + q;
  ((float4*)out)[idx] = *src;
}

}  // namespace

extern "C" void kernel_launch(void* const* d_in, const int* in_sizes, int n_in,
                              void* d_out, int out_size, void* d_ws, size_t ws_size,
                              hipStream_t stream) {
  (void)in_sizes; (void)n_in; (void)out_size; (void)ws_size;
  const float* x      = (const float*)d_in[0];
  const float* noise  = (const float*)d_in[1];
  const float* ln1_g  = (const float*)d_in[2];
  const float* ln1_b  = (const float*)d_in[3];
  const float* ln2_g  = (const float*)d_in[4];
  const float* ln2_b  = (const float*)d_in[5];
  const float* w_qkv  = (const float*)d_in[6];
  const float* b_qkv  = (const float*)d_in[7];
  const float* w_proj = (const float*)d_in[8];
  const float* b_proj = (const float*)d_in[9];
  const float* w_fc1  = (const float*)d_in[10];
  const float* b_fc1  = (const float*)d_in[11];
  const float* w_fc2  = (const float*)d_in[12];
  const float* b_fc2  = (const float*)d_in[13];
  float* out = (float*)d_out;

  char* p = (char*)d_ws;
  auto alloc = [&](size_t bytes) {
    char* r = p;
    p += (bytes + 255) & ~(size_t)255;
    return r;
  };
  __hip_bfloat16* wqkvT  = (__hip_bfloat16*)alloc((size_t)3584 * 1152 * 2);
  __hip_bfloat16* wprojT = (__hip_bfloat16*)alloc((size_t)1280 * 1152 * 2);
  __hip_bfloat16* wfc1T  = (__hip_bfloat16*)alloc((size_t)4608 * 1152 * 2);
  __hip_bfloat16* wfc2T  = (__hip_bfloat16*)alloc((size_t)1280 * 4608 * 2);
  float* inv = (float*)alloc(16384 * 4);
  int* dsti  = (int*)alloc(4096 * 4);
  int* srci  = (int*)alloc(12288 * 4);
  float* mx  = (float*)alloc(12288 * 4);
  int* best  = (int*)alloc(12288 * 4);
  int* keep  = (int*)alloc(8192 * 4);
  int* srow  = (int*)alloc(16384 * 4);
  float* yout = (float*)alloc((size_t)8192 * 1152 * 4);
  __hip_bfloat16* y1   = (__hip_bfloat16*)alloc((size_t)8192 * 1152 * 2);  // also y2
  __hip_bfloat16* qkvb = (__hip_bfloat16*)alloc((size_t)8192 * 4608 * 2);  // also h (fc1 out)
  __hip_bfloat16* vT   = (__hip_bfloat16*)alloc((size_t)256 * 80 * 512 * 2);
  __hip_bfloat16* ob   = (__hip_bfloat16*)alloc((size_t)8192 * 1152 * 2);
  float* x2 = (float*)alloc((size_t)8192 * 1152 * 4);

  // xn hi/lo planes alias qkvb (dead until gemm writes it, exactly 2x 37.75MB)
  __hip_bfloat16* xnh = qkvb;
  __hip_bfloat16* xnl = qkvb + (size_t)16 * 1024 * 1152;

  // weights -> bf16 transposed (single fused launch)
  wtrans_all_kernel<<<15552, 256, 0, stream>>>(w_qkv, wqkvT, w_proj, wprojT,
                                               w_fc1, wfc1T, w_fc2, wfc2T);

  // SiTo indices (norm + window fused)
  normwin_kernel<<<4096, 256, 0, stream>>>(x, noise, inv, xnh, xnl, dsti, srci);
  simgemm_kernel<<<16 * 12, 256, 0, stream>>>(xnh, xnl, dsti, srci, mx, best);
  rank_kernel<<<16, 256, 0, stream>>>(mx, best, dsti, srci, keep, srow);

  // DiT block on kept tokens
  ln_kernel<1><<<8192, 256, 0, stream>>>(x, keep, ln1_g, ln1_b, y1);
  gemm128_kernel<4><<<64 * 14, 512, 0, stream>>>(y1, wqkvT, b_qkv, nullptr, vT,
                                                 qkvb, 8192, 3456, 3584, 1152);
  attn_kernel<<<2048, 256, 0, stream>>>(qkvb, vT, ob);
  gemm128v_kernel<3><<<64 * 9, 256, 0, stream>>>(ob, wprojT, b_proj, nullptr, keep, x,
                                                 x2, 8192, 1152, 1152);
  ln_kernel<0><<<8192, 256, 0, stream>>>(x2, nullptr, ln2_g, ln2_b, y1);
  gemm128v_kernel<2><<<64 * 36, 256, 0, stream>>>(y1, wfc1T, b_fc1, nullptr, nullptr, nullptr,
                                                  qkvb, 8192, 4608, 1152);
  gemm128v_kernel<1><<<64 * 9, 256, 0, stream>>>(qkvb, wfc2T, b_fc2, x2, nullptr, nullptr,
                                                 yout, 8192, 1152, 4608);

  // scatter-as-gather recovery
  recover_kernel<<<18432, 256, 0, stream>>>(yout, srow, out);
}

// Round 18
// 697.469 us; speedup vs baseline: 1.0638x; 1.0045x over previous
//
#include <hip/hip_runtime.h>
#include <hip/hip_bf16.h>

namespace {

constexpr int Dd = 1152;

typedef __attribute__((ext_vector_type(8))) short bf16x8;
typedef __attribute__((ext_vector_type(4))) float f32x4;

__device__ __forceinline__ void gload_lds16(const void* g, void* l) {
  __builtin_amdgcn_global_load_lds(
      (const __attribute__((address_space(1))) void*)g,
      (__attribute__((address_space(3))) void*)l, 16, 0, 0);
}

__device__ __forceinline__ float gelu_f(float x) {
  float x3 = x * x * x;
  float z2 = 1.5957691216057308f * (x + 0.044715f * x3);
  float e = __expf(fminf(z2, 30.0f));
  return x * e / (e + 1.0f);
}

// ---------------- fused norm + window scoring ----------------
__global__ __launch_bounds__(256) void normwin_kernel(const float* __restrict__ x,
    const float* __restrict__ noise, float* __restrict__ inv,
    __hip_bfloat16* __restrict__ xnh, __hip_bfloat16* __restrict__ xnl,
    int* __restrict__ dsti, int* __restrict__ srci) {
  const int gidx = blockIdx.x;  // b*256 + w
  const int b = gidx >> 8, w = gidx & 255;
  const int wy = w >> 4, wx = w & 15;
  const int t0 = wy * 64 + wx * 2;
  const int wid = threadIdx.x >> 6, lane = threadIdx.x & 63;
  const int tok = t0 + (wid >> 1) * 32 + (wid & 1);
  const int row = (b << 10) + tok;

  const float2* xr = (const float2*)(x + (size_t)row * Dd);
  float2 v[9];
  float s = 0.f;
  #pragma unroll
  for (int e = 0; e < 9; ++e) {
    v[e] = xr[lane + 64 * e];
    s += v[e].x * v[e].x + v[e].y * v[e].y;
  }
  #pragma unroll
  for (int m = 1; m < 64; m <<= 1) s += __shfl_xor(s, m);
  float iv = 1.0f / (sqrtf(s) + 1e-6f);
  if (lane == 0) inv[row] = iv;

  __shared__ float2 xns[4][576];
  ushort2* ph = (ushort2*)(xnh + (size_t)row * Dd);
  ushort2* pl = (ushort2*)(xnl + (size_t)row * Dd);
  #pragma unroll
  for (int e = 0; e < 9; ++e) {
    float ax = v[e].x * iv, ay = v[e].y * iv;
    xns[wid][lane + 64 * e] = make_float2(ax, ay);
    __hip_bfloat16 hx = __float2bfloat16(ax), hy = __float2bfloat16(ay);
    __hip_bfloat16 lx = __float2bfloat16(ax - __bfloat162float(hx));
    __hip_bfloat16 ly = __float2bfloat16(ay - __bfloat162float(hy));
    ph[lane + 64 * e] = make_ushort2(*(ushort*)&hx, *(ushort*)&hy);
    pl[lane + 64 * e] = make_ushort2(*(ushort*)&lx, *(ushort*)&ly);
  }
  __syncthreads();

  float dot = 0.f;
  #pragma unroll
  for (int e = 0; e < 9; ++e) {
    int i = lane + 64 * e;
    float2 a0 = xns[0][i], a1 = xns[1][i], a2 = xns[2][i], a3 = xns[3][i];
    float sx = a0.x + a1.x + a2.x + a3.x;
    float sy = a0.y + a1.y + a2.y + a3.y;
    dot += (v[e].x * iv) * sx + (v[e].y * iv) * sy;
  }
  #pragma unroll
  for (int m = 1; m < 64; m <<= 1) dot += __shfl_xor(dot, m);
  __shared__ float dots[4];
  if (lane == 0) dots[wid] = dot;
  __syncthreads();
  if (threadIdx.x == 0) {
    float best = -1e30f; int bj = 0;
    #pragma unroll
    for (int j = 0; j < 4; ++j) {
      float sc = 0.25f * dots[j] + 0.1f * noise[(size_t)gidx * 4 + j];
      if (sc > best) { best = sc; bj = j; }  // strict > = first-max
    }
    int tk[4] = {t0, t0 + 1, t0 + 32, t0 + 33};
    dsti[b * 256 + w] = tk[bj];
    int m = 0;
    #pragma unroll
    for (int j = 0; j < 4; ++j) if (j != bj) srci[b * 768 + w * 3 + (m++)] = tk[j];
  }
}

// ---------------- sim GEMM (split-bf16 MFMA): per-src (max, argmax) over 256 dst ----------
__global__ __launch_bounds__(256) void simgemm_kernel(
    const __hip_bfloat16* __restrict__ xnh, const __hip_bfloat16* __restrict__ xnl,
    const int* __restrict__ dsti, const int* __restrict__ srci,
    float* __restrict__ mx, int* __restrict__ best) {
  int b = blockIdx.x / 12;
  int m0 = (blockIdx.x % 12) * 64;
  __shared__ __align__(16) __hip_bfloat16 AsH[2][64 * 32];
  __shared__ __align__(16) __hip_bfloat16 AsL[2][64 * 32];
  __shared__ __align__(16) __hip_bfloat16 BsH[2][256 * 32];
  __shared__ __align__(16) __hip_bfloat16 BsL[2][256 * 32];
  const int tid = threadIdx.x, wid = tid >> 6, lane = tid & 63;
  const int g = lane >> 4, lr = lane & 15;

  const int slotRow = tid >> 2;        // 0..63
  const int colByte = (((tid & 3) ^ ((tid >> 3) & 3)) << 4);
  size_t aRow = (size_t)((b << 10) + srci[b * 768 + m0 + slotRow]) * Dd;
  size_t bRow[4];
  #pragma unroll
  for (int p = 0; p < 4; ++p)
    bRow[p] = (size_t)((b << 10) + dsti[b * 256 + p * 64 + slotRow]) * Dd;
  const char* xh = (const char*)xnh;
  const char* xl = (const char*)xnl;

  auto stage = [&](int buf, int k0) {
    size_t ka = (aRow + k0) * 2 + colByte;
    gload_lds16(xh + ka, (char*)AsH + buf * 4096 + wid * 1024);
    gload_lds16(xl + ka, (char*)AsL + buf * 4096 + wid * 1024);
    #pragma unroll
    for (int p = 0; p < 4; ++p) {
      size_t kb = (bRow[p] + k0) * 2 + colByte;
      gload_lds16(xh + kb, (char*)BsH + buf * 16384 + p * 4096 + wid * 1024);
      gload_lds16(xl + kb, (char*)BsL + buf * 16384 + p * 4096 + wid * 1024);
    }
  };

  f32x4 hh[16], hx[16];
  const f32x4 zf = {0.f, 0.f, 0.f, 0.f};
  #pragma unroll
  for (int nf = 0; nf < 16; ++nf) { hh[nf] = zf; hx[nf] = zf; }

  const int roff = ((g ^ ((lr >> 1) & 3)) << 3);
  stage(0, 0);
  asm volatile("s_waitcnt vmcnt(0)" ::: "memory");
  __syncthreads();
  int buf = 0;
  for (int ks = 0; ks < 36; ++ks) {
    if (ks + 1 < 36) stage(buf ^ 1, (ks + 1) * 32);
    bf16x8 ah = *(const bf16x8*)&AsH[buf][(wid * 16 + lr) * 32 + roff];
    bf16x8 al = *(const bf16x8*)&AsL[buf][(wid * 16 + lr) * 32 + roff];
    #pragma unroll
    for (int nf = 0; nf < 16; ++nf) {
      bf16x8 bh = *(const bf16x8*)&BsH[buf][(nf * 16 + lr) * 32 + roff];
      bf16x8 bl = *(const bf16x8*)&BsL[buf][(nf * 16 + lr) * 32 + roff];
      hh[nf] = __builtin_amdgcn_mfma_f32_16x16x32_bf16(ah, bh, hh[nf], 0, 0, 0);
      hx[nf] = __builtin_amdgcn_mfma_f32_16x16x32_bf16(ah, bl, hx[nf], 0, 0, 0);
      hx[nf] = __builtin_amdgcn_mfma_f32_16x16x32_bf16(al, bh, hx[nf], 0, 0, 0);
    }
    asm volatile("s_waitcnt vmcnt(0)" ::: "memory");
    __syncthreads();
    buf ^= 1;
  }

  #pragma unroll
  for (int j = 0; j < 4; ++j) {
    float bv = -1e30f; int bi = 0;
    #pragma unroll
    for (int nf = 0; nf < 16; ++nf) {
      float v = hh[nf][j] + hx[nf][j];
      if (v > bv) { bv = v; bi = nf * 16 + lr; }
    }
    #pragma unroll
    for (int m = 1; m < 16; m <<= 1) {
      float ov = __shfl_xor(bv, m);
      int oi = __shfl_xor(bi, m);
      if (ov > bv || (ov == bv && oi < bi)) { bv = ov; bi = oi; }
    }
    if (lr == 0) {
      int row = m0 + wid * 16 + g * 4 + j;
      mx[b * 768 + row] = bv;
      best[b * 768 + row] = bi;
    }
  }
}

// ---------------- rank (stable argsort of -mx) -> keep_token + src_row ----------------
__global__ __launch_bounds__(256) void rank_kernel(const float* __restrict__ mx,
    const int* __restrict__ best, const int* __restrict__ dsti,
    const int* __restrict__ srci, int* __restrict__ keep, int* __restrict__ srow) {
  int b = blockIdx.x;
  int tid = threadIdx.x;
  __shared__ float smx[768];
  for (int i = tid; i < 768; i += 256) smx[i] = mx[b * 768 + i];
  __syncthreads();
  if (tid < 256) {
    int t = dsti[b * 256 + tid];
    keep[b * 512 + tid] = t;
    srow[b * 1024 + t] = tid;
  }
  for (int i = tid; i < 768; i += 256) {
    float v = smx[i];
    int r = 0;
    for (int s = 0; s < 768; ++s) {
      float u = smx[s];
      r += (u > v) || (u == v && s < i);
    }
    int tok = srci[b * 768 + i];
    if (r >= 512) {
      keep[b * 512 + (r - 256)] = tok;      // xk row = 256 + (r-512)
      srow[b * 1024 + tok] = r - 256;
    } else {
      srow[b * 1024 + tok] = best[b * 768 + i];  // copy dst-row output
    }
  }
}

// ---------------- LayerNorm (optionally gathered) ----------------
template<int GATHER>
__global__ __launch_bounds__(256) void ln_kernel(const float* __restrict__ xin,
    const int* __restrict__ keep, const float* __restrict__ gw,
    const float* __restrict__ bw, __hip_bfloat16* __restrict__ yout) {
  int row = blockIdx.x;  // 0..8191
  const float* xr;
  if (GATHER) {
    int b = row >> 9, t = row & 511;
    int tok = keep[(b << 9) + t];
    xr = xin + (size_t)((b << 10) + tok) * Dd;
  } else {
    xr = xin + (size_t)row * Dd;
  }
  int tid = threadIdx.x;
  float v[5];
  float s = 0.f, s2 = 0.f;
  #pragma unroll
  for (int e = 0; e < 5; ++e) {
    int i = tid + e * 256;
    float val = (i < Dd) ? xr[i] : 0.f;
    v[e] = val; s += val; s2 += val * val;
  }
  #pragma unroll
  for (int m = 1; m < 64; m <<= 1) { s += __shfl_xor(s, m); s2 += __shfl_xor(s2, m); }
  __shared__ float ps[4], ps2[4];
  int wid = tid >> 6, lane = tid & 63;
  if (lane == 0) { ps[wid] = s; ps2[wid] = s2; }
  __syncthreads();
  s = ps[0] + ps[1] + ps[2] + ps[3];
  s2 = ps2[0] + ps2[1] + ps2[2] + ps2[3];
  constexpr float inv_d = 1.0f / Dd;
  float mu = s * inv_d;
  float var = s2 * inv_d - mu * mu;
  float rstd = rsqrtf(var + 1e-6f);
  __hip_bfloat16* yr = yout + (size_t)row * Dd;
  #pragma unroll
  for (int e = 0; e < 5; ++e) {
    int i = tid + e * 256;
    if (i < Dd) {
      yr[i] = __float2bfloat16((v[e] - mu) * rstd * gw[i] + bw[i]);
    }
  }
}

// ---------------- fused weight transpose + bf16 cast for all four weights ----------------
__global__ __launch_bounds__(256) void wtrans_all_kernel(
    const float* __restrict__ w0, __hip_bfloat16* __restrict__ o0,
    const float* __restrict__ w1, __hip_bfloat16* __restrict__ o1,
    const float* __restrict__ w2, __hip_bfloat16* __restrict__ o2,
    const float* __restrict__ w3, __hip_bfloat16* __restrict__ o3) {
  __shared__ float tile[32][33];
  int bid = blockIdx.x;
  const float* w; __hip_bfloat16* wT; int K, N, local;
  if (bid < 3888)       { w = w0; wT = o0; K = 1152; N = 3456; local = bid; }
  else if (bid < 5184)  { w = w1; wT = o1; K = 1152; N = 1152; local = bid - 3888; }
  else if (bid < 10368) { w = w2; wT = o2; K = 1152; N = 4608; local = bid - 5184; }
  else                  { w = w3; wT = o3; K = 4608; N = 1152; local = bid - 10368; }
  int nt = N >> 5;
  int tk = local / nt, tn = local % nt;
  int tid = threadIdx.x;
  #pragma unroll
  for (int e = 0; e < 4; ++e) {
    int idx = tid + e * 256;
    int r = idx >> 5, c = idx & 31;
    tile[r][c] = w[(size_t)(tk * 32 + r) * N + tn * 32 + c];
  }
  __syncthreads();
  #pragma unroll
  for (int e = 0; e < 4; ++e) {
    int idx = tid + e * 256;
    int r = idx >> 5, c = idx & 31;
    wT[(size_t)(tn * 32 + r) * K + tk * 32 + c] = __float2bfloat16(tile[c][r]);
  }
}

// ============ GEMM epilogue helper ============
template<int EPI>
__device__ __forceinline__ void epi_store(void* C, const float* res, int Nd,
                                          size_t row, size_t col, float v) {
  if (EPI == 0) {
    ((__hip_bfloat16*)C)[row * (size_t)Nd + col] = __float2bfloat16(v);
  } else if (EPI == 1) {
    ((float*)C)[row * (size_t)Nd + col] = v + res[row * (size_t)Nd + col];
  } else if (EPI == 2) {
    ((__hip_bfloat16*)C)[row * (size_t)Nd + col] = __float2bfloat16(gelu_f(v));
  }
}

// ---------------- GEMM 128x256 lockstep (8 waves, 2 blk/CU) — qkv ----------
// EPI==4: cols < 2304 (Q,K) -> qkvb bf16; cols >= 2304 (V) -> direct transposed vT store.
template<int EPI>
__global__ __launch_bounds__(512, 4) void gemm128_kernel(
    const __hip_bfloat16* __restrict__ A, const __hip_bfloat16* __restrict__ BT,
    const float* __restrict__ bias, const float* __restrict__ res,
    __hip_bfloat16* __restrict__ vTout,
    void* __restrict__ C, int Md, int Nd, int NdPad, int Kd) {
  constexpr int BM = 128;
  __shared__ __align__(16) __hip_bfloat16 As[3][BM * 32];
  __shared__ __align__(16) __hip_bfloat16 Bs[3][256 * 32];
  const int nb = NdPad >> 8;
  const int q8 = gridDim.x >> 3;
  const int wg = (blockIdx.x & 7) * q8 + (blockIdx.x >> 3);
  const int bm = wg / nb, bnb = wg % nb;
  const int tid = threadIdx.x, wid = tid >> 6, lane = tid & 63;
  const int g = lane >> 4, lr = lane & 15;
  const int wm = wid >> 2, wn = wid & 3;
  const size_t m0 = (size_t)bm * BM, n0 = (size_t)bnb * 256;

  const int trow = tid >> 2;
  const int scol = (((tid & 3) ^ ((tid >> 3) & 3)) << 3);
  const char* Ab = (const char*)A;
  const char* Bb = (const char*)BT;

  auto stage = [&](int slot, int kt) {
    const size_t kb = ((size_t)kt << 5) + scol;
    gload_lds16(Ab + (((m0 + trow) * (size_t)Kd + kb) << 1),
                (char*)As + slot * 8192 + wid * 1024);
    gload_lds16(Bb + (((n0 + trow) * (size_t)Kd + kb) << 1),
                (char*)Bs + slot * 16384 + wid * 1024);
    gload_lds16(Bb + (((n0 + 128 + trow) * (size_t)Kd + kb) << 1),
                (char*)Bs + slot * 16384 + 8192 + wid * 1024);
  };

  f32x4 acc[4][4];
  const f32x4 zf = {0.f, 0.f, 0.f, 0.f};
  #pragma unroll
  for (int mi = 0; mi < 4; ++mi)
    #pragma unroll
    for (int ni = 0; ni < 4; ++ni) acc[mi][ni] = zf;

  const int nk = Kd >> 5;
  stage(0, 0);
  stage(1, 1);
  asm volatile("s_waitcnt vmcnt(3)" ::: "memory");
  __builtin_amdgcn_s_barrier();

  int cur = 0;
  const int roff = ((g ^ ((lr >> 1) & 3)) << 3);
  for (int kt = 0; kt < nk; ++kt) {
    const __hip_bfloat16* Ac = As[cur];
    const __hip_bfloat16* Bc = Bs[cur];
    bf16x8 af[4], bf[4];
    #pragma unroll
    for (int mi = 0; mi < 4; ++mi)
      af[mi] = *(const bf16x8*)&Ac[(wm * 64 + mi * 16 + lr) * 32 + roff];
    #pragma unroll
    for (int ni = 0; ni < 4; ++ni)
      bf[ni] = *(const bf16x8*)&Bc[(wn * 64 + ni * 16 + lr) * 32 + roff];
    if (kt + 2 < nk) stage(cur == 0 ? 2 : cur - 1, kt + 2);
    __builtin_amdgcn_s_barrier();
    __builtin_amdgcn_s_setprio(1);
    #pragma unroll
    for (int mi = 0; mi < 4; ++mi)
      #pragma unroll
      for (int ni = 0; ni < 4; ++ni)
        acc[mi][ni] = __builtin_amdgcn_mfma_f32_16x16x32_bf16(af[mi], bf[ni], acc[mi][ni], 0, 0, 0);
    __builtin_amdgcn_s_setprio(0);
    if (kt + 2 < nk)      asm volatile("s_waitcnt vmcnt(3)" ::: "memory");
    else if (kt + 1 < nk) asm volatile("s_waitcnt vmcnt(0)" ::: "memory");
    __builtin_amdgcn_s_barrier();
    cur = (cur == 2) ? 0 : cur + 1;
  }

  #pragma unroll
  for (int ni = 0; ni < 4; ++ni) {
    size_t col = n0 + wn * 64 + ni * 16 + lr;
    if (col < (size_t)Nd) {
      float bv = bias[col];
      if (EPI == 4 && col >= 2304) {
        int vc = (int)col - 2304;
        int h = vc / 72, d = vc % 72;
        #pragma unroll
        for (int mi = 0; mi < 4; ++mi) {
          #pragma unroll
          for (int j = 0; j < 4; ++j) {
            size_t row = m0 + wm * 64 + mi * 16 + g * 4 + j;
            int bb = (int)(row >> 9), t = (int)(row & 511);
            vTout[(((size_t)(bb * 16 + h)) * 80 + d) * 512 + t] =
                __float2bfloat16(acc[mi][ni][j] + bv);
          }
        }
      } else {
        #pragma unroll
        for (int mi = 0; mi < 4; ++mi) {
          #pragma unroll
          for (int j = 0; j < 4; ++j) {
            size_t row = m0 + wm * 64 + mi * 16 + g * 4 + j;
            float v = acc[mi][ni][j] + bv;
            if (EPI == 4) {
              ((__hip_bfloat16*)C)[row * (size_t)Nd + col] = __float2bfloat16(v);
            } else {
              epi_store<EPI>(C, res, Nd, row, col, v);
            }
          }
        }
      }
    }
  }
}

// ---------------- GEMM 128x128, 4 waves, 3 blk/CU, reg-double-buffered overlap ----------
template<int EPI>
__global__ __launch_bounds__(256, 3) void gemm128v_kernel(
    const __hip_bfloat16* __restrict__ A, const __hip_bfloat16* __restrict__ BT,
    const float* __restrict__ bias, const float* __restrict__ res,
    const int* __restrict__ keepIdx, const float* __restrict__ xsrc,
    void* __restrict__ C, int Md, int Nd, int Kd) {
  __shared__ __align__(16) __hip_bfloat16 As[3][128 * 32];
  __shared__ __align__(16) __hip_bfloat16 Bs[3][128 * 32];
  const int nb = Nd >> 7;
  const int q8 = gridDim.x >> 3;
  const int wg = (blockIdx.x & 7) * q8 + (blockIdx.x >> 3);
  const int bm = wg / nb, bnb = wg % nb;
  const int tid = threadIdx.x, wid = tid >> 6, lane = tid & 63;
  const int g = lane >> 4, lr = lane & 15;
  const int wm = wid >> 1, wn = wid & 1;  // wave tile 64x64
  const size_t m0 = (size_t)bm * 128, n0 = (size_t)bnb * 128;

  const int trow = tid >> 2;  // 0..63
  const int scol = (((tid & 3) ^ ((tid >> 3) & 3)) << 3);
  const char* Ab = (const char*)A;
  const char* Bb = (const char*)BT;

  auto stage = [&](int slot, int kt) {
    const size_t kb = ((size_t)kt << 5) + scol;
    #pragma unroll
    for (int c = 0; c < 2; ++c)
      gload_lds16(Ab + (((m0 + c * 64 + trow) * (size_t)Kd + kb) << 1),
                  (char*)As + slot * 8192 + c * 4096 + tid * 16);
    #pragma unroll
    for (int c = 0; c < 2; ++c)
      gload_lds16(Bb + (((n0 + c * 64 + trow) * (size_t)Kd + kb) << 1),
                  (char*)Bs + slot * 8192 + c * 4096 + tid * 16);
  };

  f32x4 acc[4][4];
  const f32x4 zf = {0.f, 0.f, 0.f, 0.f};
  #pragma unroll
  for (int mi = 0; mi < 4; ++mi)
    #pragma unroll
    for (int ni = 0; ni < 4; ++ni) acc[mi][ni] = zf;

  const int roff = ((g ^ ((lr >> 1) & 3)) << 3);
  const int nk = Kd >> 5;

  bf16x8 afA[4], bfA[4], afB[4], bfB[4];

#define DSREAD(AF, BF, SLOT) { \
  const __hip_bfloat16* Ac_ = As[SLOT]; \
  const __hip_bfloat16* Bc_ = Bs[SLOT]; \
  _Pragma("unroll") for (int mi_ = 0; mi_ < 4; ++mi_) \
    AF[mi_] = *(const bf16x8*)&Ac_[(wm * 64 + mi_ * 16 + lr) * 32 + roff]; \
  _Pragma("unroll") for (int ni_ = 0; ni_ < 4; ++ni_) \
    BF[ni_] = *(const bf16x8*)&Bc_[(wn * 64 + ni_ * 16 + lr) * 32 + roff]; }

#define MFMA16(AF, BF) { \
  __builtin_amdgcn_s_setprio(1); \
  _Pragma("unroll") for (int mi_ = 0; mi_ < 4; ++mi_) \
    _Pragma("unroll") for (int ni_ = 0; ni_ < 4; ++ni_) \
      acc[mi_][ni_] = __builtin_amdgcn_mfma_f32_16x16x32_bf16(AF[mi_], BF[ni_], acc[mi_][ni_], 0, 0, 0); \
  __builtin_amdgcn_s_setprio(0); }

#define GITER(KT, S0, S1, AFC, BFC, AFN, BFN) { \
  if ((KT) <= nk - 3)      { asm volatile("s_waitcnt vmcnt(4)" ::: "memory"); } \
  else if ((KT) == nk - 2) { asm volatile("s_waitcnt vmcnt(0)" ::: "memory"); } \
  asm volatile("s_waitcnt lgkmcnt(0)" ::: "memory"); \
  __builtin_amdgcn_s_barrier(); \
  asm volatile("" ::: "memory"); \
  if ((KT) + 1 < nk) DSREAD(AFN, BFN, (S1)); \
  if ((KT) + 3 < nk) stage((S0), (KT) + 3); \
  MFMA16(AFC, BFC); }

  stage(0, 0); stage(1, 1); stage(2, 2);
  asm volatile("s_waitcnt vmcnt(8)" ::: "memory");  // retire stage(0)
  __builtin_amdgcn_s_barrier();
  asm volatile("" ::: "memory");
  DSREAD(afA, bfA, 0);

  int s0 = 0, s1 = 1;
  for (int kt = 0; kt < nk; kt += 2) {
    GITER(kt, s0, s1, afA, bfA, afB, bfB);
    int s2 = (s1 == 2) ? 0 : s1 + 1;
    GITER(kt + 1, s1, s2, afB, bfB, afA, bfA);
    s0 = s2; s1 = (s2 == 2) ? 0 : s2 + 1;
  }
#undef GITER
#undef MFMA16
#undef DSREAD

  #pragma unroll
  for (int ni = 0; ni < 4; ++ni) {
    size_t col = n0 + wn * 64 + ni * 16 + lr;
    float bv = bias[col];
    #pragma unroll
    for (int mi = 0; mi < 4; ++mi) {
      #pragma unroll
      for (int j = 0; j < 4; ++j) {
        size_t row = m0 + wm * 64 + mi * 16 + g * 4 + j;
        float v = acc[mi][ni][j] + bv;
        if (EPI == 3) {
          int b = (int)(row >> 9);
          int tok = keepIdx[row];
          const float* rr = xsrc + ((size_t)(b << 10) + tok) * Dd;
          ((float*)C)[row * (size_t)Nd + col] = v + rr[col];
        } else {
          epi_store<EPI>(C, res, Nd, row, col, v);
        }
      }
    }
  }
}

// ---------------- flash attention per (b,h,q-PAIR of 64-row tiles) ----------------
// Block = (bh, qp): stages K/V once per c-iteration and runs both q-tiles against it
// (halves K/V staging + barriers per unit work). Qs/Ks stride 104 = conflict-free.
__global__ __launch_bounds__(256) void attn_kernel(const __hip_bfloat16* __restrict__ qkv,
    const __hip_bfloat16* __restrict__ vT, __hip_bfloat16* __restrict__ o) {
  const int blk = blockIdx.x;
  const int qp = blk & 3, bh = blk >> 2;  // qp: 128-row pair
  const int b = bh >> 4, h = bh & 15;
  __shared__ __align__(16) __hip_bfloat16 Qs[128][104];
  __shared__ __align__(16) __hip_bfloat16 Ks[64][104];
  __shared__ __align__(16) __hip_bfloat16 Vs[80][72];
  __shared__ __align__(16) __hip_bfloat16 Ps[4][16][72];
  const int tid = threadIdx.x, wid = tid >> 6, lane = tid & 63;
  const int g = lane >> 4, lr = lane & 15;
  const __hip_bfloat16 zb = __float2bfloat16(0.0f);

  for (int idx = tid; idx < 128 * 18; idx += 256) {
    int r = idx / 18, c = idx % 18;
    *(ushort4*)&Qs[r][c * 4] =
        *(const ushort4*)&qkv[((size_t)(b * 512 + qp * 128 + r)) * 3456 + h * 72 + c * 4];
  }
  for (int idx = tid; idx < 128 * 32; idx += 256) {
    int r = idx / 32, d = 72 + idx % 32;
    Qs[r][d] = zb;
    if (r < 64) Ks[r][d] = zb;
  }
  for (int idx = tid; idx < 8 * 72; idx += 256) {
    Vs[72 + idx / 72][idx % 72] = zb;  // pad rows, never re-written
  }

  f32x4 ov0[5], ov1[5];
  const f32x4 zf = {0.f, 0.f, 0.f, 0.f};
  #pragma unroll
  for (int ni = 0; ni < 5; ++ni) { ov0[ni] = zf; ov1[ni] = zf; }
  float m0_[4], l0_[4], m1_[4], l1_[4];
  #pragma unroll
  for (int j = 0; j < 4; ++j) {
    m0_[j] = -3.0e38f; l0_[j] = 0.f;
    m1_[j] = -3.0e38f; l1_[j] = 0.f;
  }
  const float scale = 0.11785113019775793f;  // 1/sqrt(72)

  for (int c = 0; c < 8; ++c) {
    __syncthreads();
    for (int idx = tid; idx < 64 * 18; idx += 256) {
      int r = idx / 18, cc = idx % 18;
      *(ushort4*)&Ks[r][cc * 4] =
          *(const ushort4*)&qkv[((size_t)(b * 512 + c * 64 + r)) * 3456 + 1152 + h * 72 + cc * 4];
    }
    for (int idx = tid; idx < 72 * 8; idx += 256) {
      int d = idx >> 3, t8 = idx & 7;
      *(uint4*)&Vs[d][t8 * 8] =
          *(const uint4*)&vT[((size_t)bh * 80 + d) * 512 + c * 64 + t8 * 8];
    }
    __syncthreads();

    #pragma unroll
    for (int qh = 0; qh < 2; ++qh) {
      float* m_ = qh ? m1_ : m0_;
      float* l_ = qh ? l1_ : l0_;
      f32x4* ov = qh ? ov1 : ov0;

      f32x4 sf[4];
      #pragma unroll
      for (int nf = 0; nf < 4; ++nf) sf[nf] = zf;
      #pragma unroll
      for (int ks = 0; ks < 3; ++ks) {
        bf16x8 qa = *(const bf16x8*)&Qs[qh * 64 + wid * 16 + lr][ks * 32 + g * 8];
        #pragma unroll
        for (int nf = 0; nf < 4; ++nf) {
          bf16x8 kb = *(const bf16x8*)&Ks[nf * 16 + lr][ks * 32 + g * 8];
          sf[nf] = __builtin_amdgcn_mfma_f32_16x16x32_bf16(qa, kb, sf[nf], 0, 0, 0);
        }
      }

      float cm[4];
      #pragma unroll
      for (int j = 0; j < 4; ++j)
        cm[j] = fmaxf(fmaxf(sf[0][j], sf[1][j]), fmaxf(sf[2][j], sf[3][j])) * scale;
      #pragma unroll
      for (int mm = 1; mm < 16; mm <<= 1)
        #pragma unroll
        for (int j = 0; j < 4; ++j) cm[j] = fmaxf(cm[j], __shfl_xor(cm[j], mm));
      float fac[4], rs[4];
      #pragma unroll
      for (int j = 0; j < 4; ++j) {
        float nm = fmaxf(m_[j], cm[j]);
        fac[j] = __expf(m_[j] - nm);
        m_[j] = nm;
        rs[j] = 0.f;
      }
      #pragma unroll
      for (int nf = 0; nf < 4; ++nf)
        #pragma unroll
        for (int j = 0; j < 4; ++j) {
          float pv = __expf(sf[nf][j] * scale - m_[j]);
          rs[j] += pv;
          Ps[wid][g * 4 + j][nf * 16 + lr] = __float2bfloat16(pv);
        }
      #pragma unroll
      for (int mm = 1; mm < 16; mm <<= 1)
        #pragma unroll
        for (int j = 0; j < 4; ++j) rs[j] += __shfl_xor(rs[j], mm);
      #pragma unroll
      for (int j = 0; j < 4; ++j) l_[j] = l_[j] * fac[j] + rs[j];
      #pragma unroll
      for (int ni = 0; ni < 5; ++ni)
        #pragma unroll
        for (int j = 0; j < 4; ++j) ov[ni][j] *= fac[j];

      #pragma unroll
      for (int k2 = 0; k2 < 2; ++k2) {
        bf16x8 pa = *(const bf16x8*)&Ps[wid][lr][k2 * 32 + g * 8];
        #pragma unroll
        for (int ni = 0; ni < 5; ++ni) {
          bf16x8 vb = *(const bf16x8*)&Vs[ni * 16 + lr][k2 * 32 + g * 8];
          ov[ni] = __builtin_amdgcn_mfma_f32_16x16x32_bf16(pa, vb, ov[ni], 0, 0, 0);
        }
      }
    }
  }

  #pragma unroll
  for (int qh = 0; qh < 2; ++qh) {
    const f32x4* ov = qh ? ov1 : ov0;
    const float* l_ = qh ? l1_ : l0_;
    #pragma unroll
    for (int ni = 0; ni < 5; ++ni) {
      int d = ni * 16 + lr;
      if (d < 72) {
        #pragma unroll
        for (int j = 0; j < 4; ++j) {
          int t = qp * 128 + qh * 64 + wid * 16 + g * 4 + j;
          o[((size_t)(b * 512 + t)) * 1152 + h * 72 + d] = __float2bfloat16(ov[ni][j] / l_[j]);
        }
      }
    }
  }
}

// ---------------- final recovery: out[b,n,:] = yout[b, src_row[b,n], :] ----------------
__global__ __launch_bounds__(256) void recover_kernel(const float* __restrict__ yout,
    const int* __restrict__ srow, float* __restrict__ out) {
  int idx = blockIdx.x * 256 + threadIdx.x;  // over B*N*288 float4s
  int q = idx % 288;
  int bnv = idx / 288;  // b*1024+n
  int r = srow[bnv];
  int b = bnv >> 10;
  const float4* src = (const float4*)yout + ((size_t)((b << 9) + r)) * 288 + q;
  ((float4*)out)[idx] = *src;
}

}  // namespace

extern "C" void kernel_launch(void* const* d_in, const int* in_sizes, int n_in,
                              void* d_out, int out_size, void* d_ws, size_t ws_size,
                              hipStream_t stream) {
  (void)in_sizes; (void)n_in; (void)out_size; (void)ws_size;
  const float* x      = (const float*)d_in[0];
  const float* noise  = (const float*)d_in[1];
  const float* ln1_g  = (const float*)d_in[2];
  const float* ln1_b  = (const float*)d_in[3];
  const float* ln2_g  = (const float*)d_in[4];
  const float* ln2_b  = (const float*)d_in[5];
  const float* w_qkv  = (const float*)d_in[6];
  const float* b_qkv  = (const float*)d_in[7];
  const float* w_proj = (const float*)d_in[8];
  const float* b_proj = (const float*)d_in[9];
  const float* w_fc1  = (const float*)d_in[10];
  const float* b_fc1  = (const float*)d_in[11];
  const float* w_fc2  = (const float*)d_in[12];
  const float* b_fc2  = (const float*)d_in[13];
  float* out = (float*)d_out;

  char* p = (char*)d_ws;
  auto alloc = [&](size_t bytes) {
    char* r = p;
    p += (bytes + 255) & ~(size_t)255;
    return r;
  };
  __hip_bfloat16* wqkvT  = (__hip_bfloat16*)alloc((size_t)3584 * 1152 * 2);
  __hip_bfloat16* wprojT = (__hip_bfloat16*)alloc((size_t)1280 * 1152 * 2);
  __hip_bfloat16* wfc1T  = (__hip_bfloat16*)alloc((size_t)4608 * 1152 * 2);
  __hip_bfloat16* wfc2T  = (__hip_bfloat16*)alloc((size_t)1280 * 4608 * 2);
  float* inv = (float*)alloc(16384 * 4);
  int* dsti  = (int*)alloc(4096 * 4);
  int* srci  = (int*)alloc(12288 * 4);
  float* mx  = (float*)alloc(12288 * 4);
  int* best  = (int*)alloc(12288 * 4);
  int* keep  = (int*)alloc(8192 * 4);
  int* srow  = (int*)alloc(16384 * 4);
  float* yout = (float*)alloc((size_t)8192 * 1152 * 4);
  __hip_bfloat16* y1   = (__hip_bfloat16*)alloc((size_t)8192 * 1152 * 2);  // also y2
  __hip_bfloat16* qkvb = (__hip_bfloat16*)alloc((size_t)8192 * 4608 * 2);  // also h (fc1 out)
  __hip_bfloat16* vT   = (__hip_bfloat16*)alloc((size_t)256 * 80 * 512 * 2);
  __hip_bfloat16* ob   = (__hip_bfloat16*)alloc((size_t)8192 * 1152 * 2);
  float* x2 = (float*)alloc((size_t)8192 * 1152 * 4);

  // xn hi/lo planes alias qkvb (dead until gemm writes it, exactly 2x 37.75MB)
  __hip_bfloat16* xnh = qkvb;
  __hip_bfloat16* xnl = qkvb + (size_t)16 * 1024 * 1152;

  // weights -> bf16 transposed (single fused launch)
  wtrans_all_kernel<<<15552, 256, 0, stream>>>(w_qkv, wqkvT, w_proj, wprojT,
                                               w_fc1, wfc1T, w_fc2, wfc2T);

  // SiTo indices (norm + window fused)
  normwin_kernel<<<4096, 256, 0, stream>>>(x, noise, inv, xnh, xnl, dsti, srci);
  simgemm_kernel<<<16 * 12, 256, 0, stream>>>(xnh, xnl, dsti, srci, mx, best);
  rank_kernel<<<16, 256, 0, stream>>>(mx, best, dsti, srci, keep, srow);

  // DiT block on kept tokens
  ln_kernel<1><<<8192, 256, 0, stream>>>(x, keep, ln1_g, ln1_b, y1);
  gemm128_kernel<4><<<64 * 14, 512, 0, stream>>>(y1, wqkvT, b_qkv, nullptr, vT,
                                                 qkvb, 8192, 3456, 3584, 1152);
  attn_kernel<<<1024, 256, 0, stream>>>(qkvb, vT, ob);
  gemm128v_kernel<3><<<64 * 9, 256, 0, stream>>>(ob, wprojT, b_proj, nullptr, keep, x,
                                                 x2, 8192, 1152, 1152);
  ln_kernel<0><<<8192, 256, 0, stream>>>(x2, nullptr, ln2_g, ln2_b, y1);
  gemm128v_kernel<2><<<64 * 36, 256, 0, stream>>>(y1, wfc1T, b_fc1, nullptr, nullptr, nullptr,
                                                  qkvb, 8192, 4608, 1152);
  gemm128v_kernel<1><<<64 * 9, 256, 0, stream>>>(qkvb, wfc2T, b_fc2, x2, nullptr, nullptr,
                                                 yout, 8192, 1152, 4608);

  // scatter-as-gather recovery
  recover_kernel<<<18432, 256, 0, stream>>>(yout, srow, out);
}

// Round 19
// 684.001 us; speedup vs baseline: 1.0848x; 1.0197x over previous
//
#include <hip/hip_runtime.h>
#include <hip/hip_bf16.h>

namespace {

constexpr int Dd = 1152;

typedef __attribute__((ext_vector_type(8))) short bf16x8;
typedef __attribute__((ext_vector_type(4))) float f32x4;

__device__ __forceinline__ void gload_lds16(const void* g, void* l) {
  __builtin_amdgcn_global_load_lds(
      (const __attribute__((address_space(1))) void*)g,
      (__attribute__((address_space(3))) void*)l, 16, 0, 0);
}

__device__ __forceinline__ float gelu_f(float x) {
  float x3 = x * x * x;
  float z2 = 1.5957691216057308f * (x + 0.044715f * x3);
  float e = __expf(fminf(z2, 30.0f));
  return x * e / (e + 1.0f);
}

// ---------------- fused norm + window scoring ----------------
__global__ __launch_bounds__(256) void normwin_kernel(const float* __restrict__ x,
    const float* __restrict__ noise, float* __restrict__ inv,
    __hip_bfloat16* __restrict__ xnh, __hip_bfloat16* __restrict__ xnl,
    int* __restrict__ dsti, int* __restrict__ srci) {
  const int gidx = blockIdx.x;  // b*256 + w
  const int b = gidx >> 8, w = gidx & 255;
  const int wy = w >> 4, wx = w & 15;
  const int t0 = wy * 64 + wx * 2;
  const int wid = threadIdx.x >> 6, lane = threadIdx.x & 63;
  const int tok = t0 + (wid >> 1) * 32 + (wid & 1);
  const int row = (b << 10) + tok;

  const float2* xr = (const float2*)(x + (size_t)row * Dd);
  float2 v[9];
  float s = 0.f;
  #pragma unroll
  for (int e = 0; e < 9; ++e) {
    v[e] = xr[lane + 64 * e];
    s += v[e].x * v[e].x + v[e].y * v[e].y;
  }
  #pragma unroll
  for (int m = 1; m < 64; m <<= 1) s += __shfl_xor(s, m);
  float iv = 1.0f / (sqrtf(s) + 1e-6f);
  if (lane == 0) inv[row] = iv;

  __shared__ float2 xns[4][576];
  ushort2* ph = (ushort2*)(xnh + (size_t)row * Dd);
  ushort2* pl = (ushort2*)(xnl + (size_t)row * Dd);
  #pragma unroll
  for (int e = 0; e < 9; ++e) {
    float ax = v[e].x * iv, ay = v[e].y * iv;
    xns[wid][lane + 64 * e] = make_float2(ax, ay);
    __hip_bfloat16 hx = __float2bfloat16(ax), hy = __float2bfloat16(ay);
    __hip_bfloat16 lx = __float2bfloat16(ax - __bfloat162float(hx));
    __hip_bfloat16 ly = __float2bfloat16(ay - __bfloat162float(hy));
    ph[lane + 64 * e] = make_ushort2(*(ushort*)&hx, *(ushort*)&hy);
    pl[lane + 64 * e] = make_ushort2(*(ushort*)&lx, *(ushort*)&ly);
  }
  __syncthreads();

  float dot = 0.f;
  #pragma unroll
  for (int e = 0; e < 9; ++e) {
    int i = lane + 64 * e;
    float2 a0 = xns[0][i], a1 = xns[1][i], a2 = xns[2][i], a3 = xns[3][i];
    float sx = a0.x + a1.x + a2.x + a3.x;
    float sy = a0.y + a1.y + a2.y + a3.y;
    dot += (v[e].x * iv) * sx + (v[e].y * iv) * sy;
  }
  #pragma unroll
  for (int m = 1; m < 64; m <<= 1) dot += __shfl_xor(dot, m);
  __shared__ float dots[4];
  if (lane == 0) dots[wid] = dot;
  __syncthreads();
  if (threadIdx.x == 0) {
    float best = -1e30f; int bj = 0;
    #pragma unroll
    for (int j = 0; j < 4; ++j) {
      float sc = 0.25f * dots[j] + 0.1f * noise[(size_t)gidx * 4 + j];
      if (sc > best) { best = sc; bj = j; }  // strict > = first-max
    }
    int tk[4] = {t0, t0 + 1, t0 + 32, t0 + 33};
    dsti[b * 256 + w] = tk[bj];
    int m = 0;
    #pragma unroll
    for (int j = 0; j < 4; ++j) if (j != bj) srci[b * 768 + w * 3 + (m++)] = tk[j];
  }
}

// ---------------- sim GEMM (split-bf16 MFMA), 3-ring counted-vmcnt schedule ----------
// Per K-step: {A-frag reads from slot cur; stage(ks+2)->slot (cur+2)%3; barrier;
//  setprio; 16x(2 B-frag reads + 3 MFMA); setprio; vmcnt(10) gate [retires
//  stage(ks+1): in-flight = stage(ks+1)+stage(ks+2) = 20]; barrier}.
__global__ __launch_bounds__(256) void simgemm_kernel(
    const __hip_bfloat16* __restrict__ xnh, const __hip_bfloat16* __restrict__ xnl,
    const int* __restrict__ dsti, const int* __restrict__ srci,
    float* __restrict__ mx, int* __restrict__ best) {
  const int q8 = gridDim.x >> 3;
  const int wg = (blockIdx.x & 7) * q8 + (blockIdx.x >> 3);
  int b = wg / 12;
  int m0 = (wg % 12) * 64;
  __shared__ __align__(16) __hip_bfloat16 AsH[3][64 * 32];
  __shared__ __align__(16) __hip_bfloat16 AsL[3][64 * 32];
  __shared__ __align__(16) __hip_bfloat16 BsH[3][256 * 32];
  __shared__ __align__(16) __hip_bfloat16 BsL[3][256 * 32];
  const int tid = threadIdx.x, wid = tid >> 6, lane = tid & 63;
  const int g = lane >> 4, lr = lane & 15;

  const int slotRow = tid >> 2;        // 0..63
  const int colByte = (((tid & 3) ^ ((tid >> 3) & 3)) << 4);
  size_t aRow = (size_t)((b << 10) + srci[b * 768 + m0 + slotRow]) * Dd;
  size_t bRow[4];
  #pragma unroll
  for (int p = 0; p < 4; ++p)
    bRow[p] = (size_t)((b << 10) + dsti[b * 256 + p * 64 + slotRow]) * Dd;
  const char* xh = (const char*)xnh;
  const char* xl = (const char*)xnl;

  auto stage = [&](int slot, int ks) {
    size_t ka = (aRow + ks * 32) * 2 + colByte;
    gload_lds16(xh + ka, (char*)AsH + slot * 4096 + wid * 1024);
    gload_lds16(xl + ka, (char*)AsL + slot * 4096 + wid * 1024);
    #pragma unroll
    for (int p = 0; p < 4; ++p) {
      size_t kb = (bRow[p] + ks * 32) * 2 + colByte;
      gload_lds16(xh + kb, (char*)BsH + slot * 16384 + p * 4096 + wid * 1024);
      gload_lds16(xl + kb, (char*)BsL + slot * 16384 + p * 4096 + wid * 1024);
    }
  };

  f32x4 hh[16], hx[16];
  const f32x4 zf = {0.f, 0.f, 0.f, 0.f};
  #pragma unroll
  for (int nf = 0; nf < 16; ++nf) { hh[nf] = zf; hx[nf] = zf; }

  const int roff = ((g ^ ((lr >> 1) & 3)) << 3);
  stage(0, 0);
  stage(1, 1);
  asm volatile("s_waitcnt vmcnt(10)" ::: "memory");  // retire stage(0)
  __builtin_amdgcn_s_barrier();

  int cur = 0;
  for (int ks = 0; ks < 36; ++ks) {
    bf16x8 ah = *(const bf16x8*)&AsH[cur][(wid * 16 + lr) * 32 + roff];
    bf16x8 al = *(const bf16x8*)&AsL[cur][(wid * 16 + lr) * 32 + roff];
    if (ks + 2 < 36) stage(cur == 0 ? 2 : cur - 1, ks + 2);
    __builtin_amdgcn_s_barrier();
    __builtin_amdgcn_s_setprio(1);
    #pragma unroll
    for (int nf = 0; nf < 16; ++nf) {
      bf16x8 bh = *(const bf16x8*)&BsH[cur][(nf * 16 + lr) * 32 + roff];
      bf16x8 bl = *(const bf16x8*)&BsL[cur][(nf * 16 + lr) * 32 + roff];
      hh[nf] = __builtin_amdgcn_mfma_f32_16x16x32_bf16(ah, bh, hh[nf], 0, 0, 0);
      hx[nf] = __builtin_amdgcn_mfma_f32_16x16x32_bf16(ah, bl, hx[nf], 0, 0, 0);
      hx[nf] = __builtin_amdgcn_mfma_f32_16x16x32_bf16(al, bh, hx[nf], 0, 0, 0);
    }
    __builtin_amdgcn_s_setprio(0);
    if (ks + 2 < 36)      asm volatile("s_waitcnt vmcnt(10)" ::: "memory");
    else if (ks + 1 < 36) asm volatile("s_waitcnt vmcnt(0)" ::: "memory");
    __builtin_amdgcn_s_barrier();
    cur = (cur == 2) ? 0 : cur + 1;
  }

  #pragma unroll
  for (int j = 0; j < 4; ++j) {
    float bv = -1e30f; int bi = 0;
    #pragma unroll
    for (int nf = 0; nf < 16; ++nf) {
      float v = hh[nf][j] + hx[nf][j];
      if (v > bv) { bv = v; bi = nf * 16 + lr; }
    }
    #pragma unroll
    for (int m = 1; m < 16; m <<= 1) {
      float ov = __shfl_xor(bv, m);
      int oi = __shfl_xor(bi, m);
      if (ov > bv || (ov == bv && oi < bi)) { bv = ov; bi = oi; }
    }
    if (lr == 0) {
      int row = m0 + wid * 16 + g * 4 + j;
      mx[b * 768 + row] = bv;
      best[b * 768 + row] = bi;
    }
  }
}

// ---------------- rank (stable argsort of -mx) -> keep_token + src_row ----------------
__global__ __launch_bounds__(256) void rank_kernel(const float* __restrict__ mx,
    const int* __restrict__ best, const int* __restrict__ dsti,
    const int* __restrict__ srci, int* __restrict__ keep, int* __restrict__ srow) {
  int b = blockIdx.x;
  int tid = threadIdx.x;
  __shared__ float smx[768];
  for (int i = tid; i < 768; i += 256) smx[i] = mx[b * 768 + i];
  __syncthreads();
  if (tid < 256) {
    int t = dsti[b * 256 + tid];
    keep[b * 512 + tid] = t;
    srow[b * 1024 + t] = tid;
  }
  for (int i = tid; i < 768; i += 256) {
    float v = smx[i];
    int r = 0;
    for (int s = 0; s < 768; ++s) {
      float u = smx[s];
      r += (u > v) || (u == v && s < i);
    }
    int tok = srci[b * 768 + i];
    if (r >= 512) {
      keep[b * 512 + (r - 256)] = tok;      // xk row = 256 + (r-512)
      srow[b * 1024 + tok] = r - 256;
    } else {
      srow[b * 1024 + tok] = best[b * 768 + i];  // copy dst-row output
    }
  }
}

// ---------------- LayerNorm (optionally gathered) ----------------
template<int GATHER>
__global__ __launch_bounds__(256) void ln_kernel(const float* __restrict__ xin,
    const int* __restrict__ keep, const float* __restrict__ gw,
    const float* __restrict__ bw, __hip_bfloat16* __restrict__ yout) {
  int row = blockIdx.x;  // 0..8191
  const float* xr;
  if (GATHER) {
    int b = row >> 9, t = row & 511;
    int tok = keep[(b << 9) + t];
    xr = xin + (size_t)((b << 10) + tok) * Dd;
  } else {
    xr = xin + (size_t)row * Dd;
  }
  int tid = threadIdx.x;
  float v[5];
  float s = 0.f, s2 = 0.f;
  #pragma unroll
  for (int e = 0; e < 5; ++e) {
    int i = tid + e * 256;
    float val = (i < Dd) ? xr[i] : 0.f;
    v[e] = val; s += val; s2 += val * val;
  }
  #pragma unroll
  for (int m = 1; m < 64; m <<= 1) { s += __shfl_xor(s, m); s2 += __shfl_xor(s2, m); }
  __shared__ float ps[4], ps2[4];
  int wid = tid >> 6, lane = tid & 63;
  if (lane == 0) { ps[wid] = s; ps2[wid] = s2; }
  __syncthreads();
  s = ps[0] + ps[1] + ps[2] + ps[3];
  s2 = ps2[0] + ps2[1] + ps2[2] + ps2[3];
  constexpr float inv_d = 1.0f / Dd;
  float mu = s * inv_d;
  float var = s2 * inv_d - mu * mu;
  float rstd = rsqrtf(var + 1e-6f);
  __hip_bfloat16* yr = yout + (size_t)row * Dd;
  #pragma unroll
  for (int e = 0; e < 5; ++e) {
    int i = tid + e * 256;
    if (i < Dd) {
      yr[i] = __float2bfloat16((v[e] - mu) * rstd * gw[i] + bw[i]);
    }
  }
}

// ---------------- fused weight transpose + bf16 cast for all four weights ----------------
__global__ __launch_bounds__(256) void wtrans_all_kernel(
    const float* __restrict__ w0, __hip_bfloat16* __restrict__ o0,
    const float* __restrict__ w1, __hip_bfloat16* __restrict__ o1,
    const float* __restrict__ w2, __hip_bfloat16* __restrict__ o2,
    const float* __restrict__ w3, __hip_bfloat16* __restrict__ o3) {
  __shared__ float tile[32][33];
  int bid = blockIdx.x;
  const float* w; __hip_bfloat16* wT; int K, N, local;
  if (bid < 3888)       { w = w0; wT = o0; K = 1152; N = 3456; local = bid; }
  else if (bid < 5184)  { w = w1; wT = o1; K = 1152; N = 1152; local = bid - 3888; }
  else if (bid < 10368) { w = w2; wT = o2; K = 1152; N = 4608; local = bid - 5184; }
  else                  { w = w3; wT = o3; K = 4608; N = 1152; local = bid - 10368; }
  int nt = N >> 5;
  int tk = local / nt, tn = local % nt;
  int tid = threadIdx.x;
  #pragma unroll
  for (int e = 0; e < 4; ++e) {
    int idx = tid + e * 256;
    int r = idx >> 5, c = idx & 31;
    tile[r][c] = w[(size_t)(tk * 32 + r) * N + tn * 32 + c];
  }
  __syncthreads();
  #pragma unroll
  for (int e = 0; e < 4; ++e) {
    int idx = tid + e * 256;
    int r = idx >> 5, c = idx & 31;
    wT[(size_t)(tn * 32 + r) * K + tk * 32 + c] = __float2bfloat16(tile[c][r]);
  }
}

// ============ GEMM epilogue helper ============
template<int EPI>
__device__ __forceinline__ void epi_store(void* C, const float* res, int Nd,
                                          size_t row, size_t col, float v) {
  if (EPI == 0) {
    ((__hip_bfloat16*)C)[row * (size_t)Nd + col] = __float2bfloat16(v);
  } else if (EPI == 1) {
    ((float*)C)[row * (size_t)Nd + col] = v + res[row * (size_t)Nd + col];
  } else if (EPI == 2) {
    ((__hip_bfloat16*)C)[row * (size_t)Nd + col] = __float2bfloat16(gelu_f(v));
  }
}

// ---------------- GEMM 128x256 lockstep (8 waves, 2 blk/CU) — qkv ----------
// EPI==4: cols < 2304 (Q,K) -> qkvb bf16; cols >= 2304 (V) -> direct transposed vT store.
template<int EPI>
__global__ __launch_bounds__(512, 4) void gemm128_kernel(
    const __hip_bfloat16* __restrict__ A, const __hip_bfloat16* __restrict__ BT,
    const float* __restrict__ bias, const float* __restrict__ res,
    __hip_bfloat16* __restrict__ vTout,
    void* __restrict__ C, int Md, int Nd, int NdPad, int Kd) {
  constexpr int BM = 128;
  __shared__ __align__(16) __hip_bfloat16 As[3][BM * 32];
  __shared__ __align__(16) __hip_bfloat16 Bs[3][256 * 32];
  const int nb = NdPad >> 8;
  const int q8 = gridDim.x >> 3;
  const int wg = (blockIdx.x & 7) * q8 + (blockIdx.x >> 3);
  const int bm = wg / nb, bnb = wg % nb;
  const int tid = threadIdx.x, wid = tid >> 6, lane = tid & 63;
  const int g = lane >> 4, lr = lane & 15;
  const int wm = wid >> 2, wn = wid & 3;
  const size_t m0 = (size_t)bm * BM, n0 = (size_t)bnb * 256;

  const int trow = tid >> 2;
  const int scol = (((tid & 3) ^ ((tid >> 3) & 3)) << 3);
  const char* Ab = (const char*)A;
  const char* Bb = (const char*)BT;

  auto stage = [&](int slot, int kt) {
    const size_t kb = ((size_t)kt << 5) + scol;
    gload_lds16(Ab + (((m0 + trow) * (size_t)Kd + kb) << 1),
                (char*)As + slot * 8192 + wid * 1024);
    gload_lds16(Bb + (((n0 + trow) * (size_t)Kd + kb) << 1),
                (char*)Bs + slot * 16384 + wid * 1024);
    gload_lds16(Bb + (((n0 + 128 + trow) * (size_t)Kd + kb) << 1),
                (char*)Bs + slot * 16384 + 8192 + wid * 1024);
  };

  f32x4 acc[4][4];
  const f32x4 zf = {0.f, 0.f, 0.f, 0.f};
  #pragma unroll
  for (int mi = 0; mi < 4; ++mi)
    #pragma unroll
    for (int ni = 0; ni < 4; ++ni) acc[mi][ni] = zf;

  const int nk = Kd >> 5;
  stage(0, 0);
  stage(1, 1);
  asm volatile("s_waitcnt vmcnt(3)" ::: "memory");
  __builtin_amdgcn_s_barrier();

  int cur = 0;
  const int roff = ((g ^ ((lr >> 1) & 3)) << 3);
  for (int kt = 0; kt < nk; ++kt) {
    const __hip_bfloat16* Ac = As[cur];
    const __hip_bfloat16* Bc = Bs[cur];
    bf16x8 af[4], bf[4];
    #pragma unroll
    for (int mi = 0; mi < 4; ++mi)
      af[mi] = *(const bf16x8*)&Ac[(wm * 64 + mi * 16 + lr) * 32 + roff];
    #pragma unroll
    for (int ni = 0; ni < 4; ++ni)
      bf[ni] = *(const bf16x8*)&Bc[(wn * 64 + ni * 16 + lr) * 32 + roff];
    if (kt + 2 < nk) stage(cur == 0 ? 2 : cur - 1, kt + 2);
    __builtin_amdgcn_s_barrier();
    __builtin_amdgcn_s_setprio(1);
    #pragma unroll
    for (int mi = 0; mi < 4; ++mi)
      #pragma unroll
      for (int ni = 0; ni < 4; ++ni)
        acc[mi][ni] = __builtin_amdgcn_mfma_f32_16x16x32_bf16(af[mi], bf[ni], acc[mi][ni], 0, 0, 0);
    __builtin_amdgcn_s_setprio(0);
    if (kt + 2 < nk)      asm volatile("s_waitcnt vmcnt(3)" ::: "memory");
    else if (kt + 1 < nk) asm volatile("s_waitcnt vmcnt(0)" ::: "memory");
    __builtin_amdgcn_s_barrier();
    cur = (cur == 2) ? 0 : cur + 1;
  }

  #pragma unroll
  for (int ni = 0; ni < 4; ++ni) {
    size_t col = n0 + wn * 64 + ni * 16 + lr;
    if (col < (size_t)Nd) {
      float bv = bias[col];
      if (EPI == 4 && col >= 2304) {
        int vc = (int)col - 2304;
        int h = vc / 72, d = vc % 72;
        #pragma unroll
        for (int mi = 0; mi < 4; ++mi) {
          #pragma unroll
          for (int j = 0; j < 4; ++j) {
            size_t row = m0 + wm * 64 + mi * 16 + g * 4 + j;
            int bb = (int)(row >> 9), t = (int)(row & 511);
            vTout[(((size_t)(bb * 16 + h)) * 80 + d) * 512 + t] =
                __float2bfloat16(acc[mi][ni][j] + bv);
          }
        }
      } else {
        #pragma unroll
        for (int mi = 0; mi < 4; ++mi) {
          #pragma unroll
          for (int j = 0; j < 4; ++j) {
            size_t row = m0 + wm * 64 + mi * 16 + g * 4 + j;
            float v = acc[mi][ni][j] + bv;
            if (EPI == 4) {
              ((__hip_bfloat16*)C)[row * (size_t)Nd + col] = __float2bfloat16(v);
            } else {
              epi_store<EPI>(C, res, Nd, row, col, v);
            }
          }
        }
      }
    }
  }
}

// ---------------- GEMM 128x128, 4 waves, 3 blk/CU, reg-double-buffered overlap ----------
template<int EPI>
__global__ __launch_bounds__(256, 3) void gemm128v_kernel(
    const __hip_bfloat16* __restrict__ A, const __hip_bfloat16* __restrict__ BT,
    const float* __restrict__ bias, const float* __restrict__ res,
    const int* __restrict__ keepIdx, const float* __restrict__ xsrc,
    void* __restrict__ C, int Md, int Nd, int Kd) {
  __shared__ __align__(16) __hip_bfloat16 As[3][128 * 32];
  __shared__ __align__(16) __hip_bfloat16 Bs[3][128 * 32];
  const int nb = Nd >> 7;
  const int q8 = gridDim.x >> 3;
  const int wg = (blockIdx.x & 7) * q8 + (blockIdx.x >> 3);
  const int bm = wg / nb, bnb = wg % nb;
  const int tid = threadIdx.x, wid = tid >> 6, lane = tid & 63;
  const int g = lane >> 4, lr = lane & 15;
  const int wm = wid >> 1, wn = wid & 1;  // wave tile 64x64
  const size_t m0 = (size_t)bm * 128, n0 = (size_t)bnb * 128;

  const int trow = tid >> 2;  // 0..63
  const int scol = (((tid & 3) ^ ((tid >> 3) & 3)) << 3);
  const char* Ab = (const char*)A;
  const char* Bb = (const char*)BT;

  auto stage = [&](int slot, int kt) {
    const size_t kb = ((size_t)kt << 5) + scol;
    #pragma unroll
    for (int c = 0; c < 2; ++c)
      gload_lds16(Ab + (((m0 + c * 64 + trow) * (size_t)Kd + kb) << 1),
                  (char*)As + slot * 8192 + c * 4096 + tid * 16);
    #pragma unroll
    for (int c = 0; c < 2; ++c)
      gload_lds16(Bb + (((n0 + c * 64 + trow) * (size_t)Kd + kb) << 1),
                  (char*)Bs + slot * 8192 + c * 4096 + tid * 16);
  };

  f32x4 acc[4][4];
  const f32x4 zf = {0.f, 0.f, 0.f, 0.f};
  #pragma unroll
  for (int mi = 0; mi < 4; ++mi)
    #pragma unroll
    for (int ni = 0; ni < 4; ++ni) acc[mi][ni] = zf;

  const int roff = ((g ^ ((lr >> 1) & 3)) << 3);
  const int nk = Kd >> 5;

  bf16x8 afA[4], bfA[4], afB[4], bfB[4];

#define DSREAD(AF, BF, SLOT) { \
  const __hip_bfloat16* Ac_ = As[SLOT]; \
  const __hip_bfloat16* Bc_ = Bs[SLOT]; \
  _Pragma("unroll") for (int mi_ = 0; mi_ < 4; ++mi_) \
    AF[mi_] = *(const bf16x8*)&Ac_[(wm * 64 + mi_ * 16 + lr) * 32 + roff]; \
  _Pragma("unroll") for (int ni_ = 0; ni_ < 4; ++ni_) \
    BF[ni_] = *(const bf16x8*)&Bc_[(wn * 64 + ni_ * 16 + lr) * 32 + roff]; }

#define MFMA16(AF, BF) { \
  __builtin_amdgcn_s_setprio(1); \
  _Pragma("unroll") for (int mi_ = 0; mi_ < 4; ++mi_) \
    _Pragma("unroll") for (int ni_ = 0; ni_ < 4; ++ni_) \
      acc[mi_][ni_] = __builtin_amdgcn_mfma_f32_16x16x32_bf16(AF[mi_], BF[ni_], acc[mi_][ni_], 0, 0, 0); \
  __builtin_amdgcn_s_setprio(0); }

#define GITER(KT, S0, S1, AFC, BFC, AFN, BFN) { \
  if ((KT) <= nk - 3)      { asm volatile("s_waitcnt vmcnt(4)" ::: "memory"); } \
  else if ((KT) == nk - 2) { asm volatile("s_waitcnt vmcnt(0)" ::: "memory"); } \
  asm volatile("s_waitcnt lgkmcnt(0)" ::: "memory"); \
  __builtin_amdgcn_s_barrier(); \
  asm volatile("" ::: "memory"); \
  if ((KT) + 1 < nk) DSREAD(AFN, BFN, (S1)); \
  if ((KT) + 3 < nk) stage((S0), (KT) + 3); \
  MFMA16(AFC, BFC); }

  stage(0, 0); stage(1, 1); stage(2, 2);
  asm volatile("s_waitcnt vmcnt(8)" ::: "memory");  // retire stage(0)
  __builtin_amdgcn_s_barrier();
  asm volatile("" ::: "memory");
  DSREAD(afA, bfA, 0);

  int s0 = 0, s1 = 1;
  for (int kt = 0; kt < nk; kt += 2) {
    GITER(kt, s0, s1, afA, bfA, afB, bfB);
    int s2 = (s1 == 2) ? 0 : s1 + 1;
    GITER(kt + 1, s1, s2, afB, bfB, afA, bfA);
    s0 = s2; s1 = (s2 == 2) ? 0 : s2 + 1;
  }
#undef GITER
#undef MFMA16
#undef DSREAD

  #pragma unroll
  for (int ni = 0; ni < 4; ++ni) {
    size_t col = n0 + wn * 64 + ni * 16 + lr;
    float bv = bias[col];
    #pragma unroll
    for (int mi = 0; mi < 4; ++mi) {
      #pragma unroll
      for (int j = 0; j < 4; ++j) {
        size_t row = m0 + wm * 64 + mi * 16 + g * 4 + j;
        float v = acc[mi][ni][j] + bv;
        if (EPI == 3) {
          int b = (int)(row >> 9);
          int tok = keepIdx[row];
          const float* rr = xsrc + ((size_t)(b << 10) + tok) * Dd;
          ((float*)C)[row * (size_t)Nd + col] = v + rr[col];
        } else {
          epi_store<EPI>(C, res, Nd, row, col, v);
        }
      }
    }
  }
}

// ---------------- flash attention per (b,h,q-PAIR of 64-row tiles) ----------------
__global__ __launch_bounds__(256) void attn_kernel(const __hip_bfloat16* __restrict__ qkv,
    const __hip_bfloat16* __restrict__ vT, __hip_bfloat16* __restrict__ o) {
  const int blk = blockIdx.x;
  const int qp = blk & 3, bh = blk >> 2;  // qp: 128-row pair
  const int b = bh >> 4, h = bh & 15;
  __shared__ __align__(16) __hip_bfloat16 Qs[128][104];
  __shared__ __align__(16) __hip_bfloat16 Ks[64][104];
  __shared__ __align__(16) __hip_bfloat16 Vs[80][72];
  __shared__ __align__(16) __hip_bfloat16 Ps[4][16][72];
  const int tid = threadIdx.x, wid = tid >> 6, lane = tid & 63;
  const int g = lane >> 4, lr = lane & 15;
  const __hip_bfloat16 zb = __float2bfloat16(0.0f);

  for (int idx = tid; idx < 128 * 18; idx += 256) {
    int r = idx / 18, c = idx % 18;
    *(ushort4*)&Qs[r][c * 4] =
        *(const ushort4*)&qkv[((size_t)(b * 512 + qp * 128 + r)) * 3456 + h * 72 + c * 4];
  }
  for (int idx = tid; idx < 128 * 32; idx += 256) {
    int r = idx / 32, d = 72 + idx % 32;
    Qs[r][d] = zb;
    if (r < 64) Ks[r][d] = zb;
  }
  for (int idx = tid; idx < 8 * 72; idx += 256) {
    Vs[72 + idx / 72][idx % 72] = zb;  // pad rows, never re-written
  }

  f32x4 ov0[5], ov1[5];
  const f32x4 zf = {0.f, 0.f, 0.f, 0.f};
  #pragma unroll
  for (int ni = 0; ni < 5; ++ni) { ov0[ni] = zf; ov1[ni] = zf; }
  float m0_[4], l0_[4], m1_[4], l1_[4];
  #pragma unroll
  for (int j = 0; j < 4; ++j) {
    m0_[j] = -3.0e38f; l0_[j] = 0.f;
    m1_[j] = -3.0e38f; l1_[j] = 0.f;
  }
  const float scale = 0.11785113019775793f;  // 1/sqrt(72)

  for (int c = 0; c < 8; ++c) {
    __syncthreads();
    for (int idx = tid; idx < 64 * 18; idx += 256) {
      int r = idx / 18, cc = idx % 18;
      *(ushort4*)&Ks[r][cc * 4] =
          *(const ushort4*)&qkv[((size_t)(b * 512 + c * 64 + r)) * 3456 + 1152 + h * 72 + cc * 4];
    }
    for (int idx = tid; idx < 72 * 8; idx += 256) {
      int d = idx >> 3, t8 = idx & 7;
      *(uint4*)&Vs[d][t8 * 8] =
          *(const uint4*)&vT[((size_t)bh * 80 + d) * 512 + c * 64 + t8 * 8];
    }
    __syncthreads();

    #pragma unroll
    for (int qh = 0; qh < 2; ++qh) {
      float* m_ = qh ? m1_ : m0_;
      float* l_ = qh ? l1_ : l0_;
      f32x4* ov = qh ? ov1 : ov0;

      f32x4 sf[4];
      #pragma unroll
      for (int nf = 0; nf < 4; ++nf) sf[nf] = zf;
      #pragma unroll
      for (int ks = 0; ks < 3; ++ks) {
        bf16x8 qa = *(const bf16x8*)&Qs[qh * 64 + wid * 16 + lr][ks * 32 + g * 8];
        #pragma unroll
        for (int nf = 0; nf < 4; ++nf) {
          bf16x8 kb = *(const bf16x8*)&Ks[nf * 16 + lr][ks * 32 + g * 8];
          sf[nf] = __builtin_amdgcn_mfma_f32_16x16x32_bf16(qa, kb, sf[nf], 0, 0, 0);
        }
      }

      float cm[4];
      #pragma unroll
      for (int j = 0; j < 4; ++j)
        cm[j] = fmaxf(fmaxf(sf[0][j], sf[1][j]), fmaxf(sf[2][j], sf[3][j])) * scale;
      #pragma unroll
      for (int mm = 1; mm < 16; mm <<= 1)
        #pragma unroll
        for (int j = 0; j < 4; ++j) cm[j] = fmaxf(cm[j], __shfl_xor(cm[j], mm));
      float fac[4], rs[4];
      #pragma unroll
      for (int j = 0; j < 4; ++j) {
        float nm = fmaxf(m_[j], cm[j]);
        fac[j] = __expf(m_[j] - nm);
        m_[j] = nm;
        rs[j] = 0.f;
      }
      #pragma unroll
      for (int nf = 0; nf < 4; ++nf)
        #pragma unroll
        for (int j = 0; j < 4; ++j) {
          float pv = __expf(sf[nf][j] * scale - m_[j]);
          rs[j] += pv;
          Ps[wid][g * 4 + j][nf * 16 + lr] = __float2bfloat16(pv);
        }
      #pragma unroll
      for (int mm = 1; mm < 16; mm <<= 1)
        #pragma unroll
        for (int j = 0; j < 4; ++j) rs[j] += __shfl_xor(rs[j], mm);
      #pragma unroll
      for (int j = 0; j < 4; ++j) l_[j] = l_[j] * fac[j] + rs[j];
      #pragma unroll
      for (int ni = 0; ni < 5; ++ni)
        #pragma unroll
        for (int j = 0; j < 4; ++j) ov[ni][j] *= fac[j];

      #pragma unroll
      for (int k2 = 0; k2 < 2; ++k2) {
        bf16x8 pa = *(const bf16x8*)&Ps[wid][lr][k2 * 32 + g * 8];
        #pragma unroll
        for (int ni = 0; ni < 5; ++ni) {
          bf16x8 vb = *(const bf16x8*)&Vs[ni * 16 + lr][k2 * 32 + g * 8];
          ov[ni] = __builtin_amdgcn_mfma_f32_16x16x32_bf16(pa, vb, ov[ni], 0, 0, 0);
        }
      }
    }
  }

  #pragma unroll
  for (int qh = 0; qh < 2; ++qh) {
    const f32x4* ov = qh ? ov1 : ov0;
    const float* l_ = qh ? l1_ : l0_;
    #pragma unroll
    for (int ni = 0; ni < 5; ++ni) {
      int d = ni * 16 + lr;
      if (d < 72) {
        #pragma unroll
        for (int j = 0; j < 4; ++j) {
          int t = qp * 128 + qh * 64 + wid * 16 + g * 4 + j;
          o[((size_t)(b * 512 + t)) * 1152 + h * 72 + d] = __float2bfloat16(ov[ni][j] / l_[j]);
        }
      }
    }
  }
}

// ---------------- final recovery: out[b,n,:] = yout[b, src_row[b,n], :] ----------------
__global__ __launch_bounds__(256) void recover_kernel(const float* __restrict__ yout,
    const int* __restrict__ srow, float* __restrict__ out) {
  int idx = blockIdx.x * 256 + threadIdx.x;  // over B*N*288 float4s
  int q = idx % 288;
  int bnv = idx / 288;  // b*1024+n
  int r = srow[bnv];
  int b = bnv >> 10;
  const float4* src = (const float4*)yout + ((size_t)((b << 9) + r)) * 288 + q;
  ((float4*)out)[idx] = *src;
}

}  // namespace

extern "C" void kernel_launch(void* const* d_in, const int* in_sizes, int n_in,
                              void* d_out, int out_size, void* d_ws, size_t ws_size,
                              hipStream_t stream) {
  (void)in_sizes; (void)n_in; (void)out_size; (void)ws_size;
  const float* x      = (const float*)d_in[0];
  const float* noise  = (const float*)d_in[1];
  const float* ln1_g  = (const float*)d_in[2];
  const float* ln1_b  = (const float*)d_in[3];
  const float* ln2_g  = (const float*)d_in[4];
  const float* ln2_b  = (const float*)d_in[5];
  const float* w_qkv  = (const float*)d_in[6];
  const float* b_qkv  = (const float*)d_in[7];
  const float* w_proj = (const float*)d_in[8];
  const float* b_proj = (const float*)d_in[9];
  const float* w_fc1  = (const float*)d_in[10];
  const float* b_fc1  = (const float*)d_in[11];
  const float* w_fc2  = (const float*)d_in[12];
  const float* b_fc2  = (const float*)d_in[13];
  float* out = (float*)d_out;

  char* p = (char*)d_ws;
  auto alloc = [&](size_t bytes) {
    char* r = p;
    p += (bytes + 255) & ~(size_t)255;
    return r;
  };
  __hip_bfloat16* wqkvT  = (__hip_bfloat16*)alloc((size_t)3584 * 1152 * 2);
  __hip_bfloat16* wprojT = (__hip_bfloat16*)alloc((size_t)1280 * 1152 * 2);
  __hip_bfloat16* wfc1T  = (__hip_bfloat16*)alloc((size_t)4608 * 1152 * 2);
  __hip_bfloat16* wfc2T  = (__hip_bfloat16*)alloc((size_t)1280 * 4608 * 2);
  float* inv = (float*)alloc(16384 * 4);
  int* dsti  = (int*)alloc(4096 * 4);
  int* srci  = (int*)alloc(12288 * 4);
  float* mx  = (float*)alloc(12288 * 4);
  int* best  = (int*)alloc(12288 * 4);
  int* keep  = (int*)alloc(8192 * 4);
  int* srow  = (int*)alloc(16384 * 4);
  float* yout = (float*)alloc((size_t)8192 * 1152 * 4);
  __hip_bfloat16* y1   = (__hip_bfloat16*)alloc((size_t)8192 * 1152 * 2);  // also y2
  __hip_bfloat16* qkvb = (__hip_bfloat16*)alloc((size_t)8192 * 4608 * 2);  // also h (fc1 out)
  __hip_bfloat16* vT   = (__hip_bfloat16*)alloc((size_t)256 * 80 * 512 * 2);
  __hip_bfloat16* ob   = (__hip_bfloat16*)alloc((size_t)8192 * 1152 * 2);
  float* x2 = (float*)alloc((size_t)8192 * 1152 * 4);

  // xn hi/lo planes alias qkvb (dead until gemm writes it, exactly 2x 37.75MB)
  __hip_bfloat16* xnh = qkvb;
  __hip_bfloat16* xnl = qkvb + (size_t)16 * 1024 * 1152;

  // weights -> bf16 transposed (single fused launch)
  wtrans_all_kernel<<<15552, 256, 0, stream>>>(w_qkv, wqkvT, w_proj, wprojT,
                                               w_fc1, wfc1T, w_fc2, wfc2T);

  // SiTo indices (norm + window fused)
  normwin_kernel<<<4096, 256, 0, stream>>>(x, noise, inv, xnh, xnl, dsti, srci);
  simgemm_kernel<<<16 * 12, 256, 0, stream>>>(xnh, xnl, dsti, srci, mx, best);
  rank_kernel<<<16, 256, 0, stream>>>(mx, best, dsti, srci, keep, srow);

  // DiT block on kept tokens
  ln_kernel<1><<<8192, 256, 0, stream>>>(x, keep, ln1_g, ln1_b, y1);
  gemm128_kernel<4><<<64 * 14, 512, 0, stream>>>(y1, wqkvT, b_qkv, nullptr, vT,
                                                 qkvb, 8192, 3456, 3584, 1152);
  attn_kernel<<<1024, 256, 0, stream>>>(qkvb, vT, ob);
  gemm128v_kernel<3><<<64 * 9, 256, 0, stream>>>(ob, wprojT, b_proj, nullptr, keep, x,
                                                 x2, 8192, 1152, 1152);
  ln_kernel<0><<<8192, 256, 0, stream>>>(x2, nullptr, ln2_g, ln2_b, y1);
  gemm128v_kernel<2><<<64 * 36, 256, 0, stream>>>(y1, wfc1T, b_fc1, nullptr, nullptr, nullptr,
                                                  qkvb, 8192, 4608, 1152);
  gemm128v_kernel<1><<<64 * 9, 256, 0, stream>>>(qkvb, wfc2T, b_fc2, x2, nullptr, nullptr,
                                                 yout, 8192, 1152, 4608);

  // scatter-as-gather recovery
  recover_kernel<<<18432, 256, 0, stream>>>(yout, srow, out);
}

// Round 20
// 680.663 us; speedup vs baseline: 1.0901x; 1.0049x over previous
//
#include <hip/hip_runtime.h>
#include <hip/hip_bf16.h>

namespace {

constexpr int Dd = 1152;

typedef __attribute__((ext_vector_type(8))) short bf16x8;
typedef __attribute__((ext_vector_type(4))) float f32x4;

__device__ __forceinline__ void gload_lds16(const void* g, void* l) {
  __builtin_amdgcn_global_load_lds(
      (const __attribute__((address_space(1))) void*)g,
      (__attribute__((address_space(3))) void*)l, 16, 0, 0);
}

__device__ __forceinline__ float gelu_f(float x) {
  float x3 = x * x * x;
  float z2 = 1.5957691216057308f * (x + 0.044715f * x3);
  float e = __expf(fminf(z2, 30.0f));
  return x * e / (e + 1.0f);
}

__device__ __forceinline__ ushort4 bf4(float4 v) {
  __hip_bfloat16 a = __float2bfloat16(v.x), b = __float2bfloat16(v.y);
  __hip_bfloat16 c = __float2bfloat16(v.z), d = __float2bfloat16(v.w);
  return make_ushort4(*(ushort*)&a, *(ushort*)&b, *(ushort*)&c, *(ushort*)&d);
}

// ---------------- fused norm + window scoring (float4 loads) ----------------
__global__ __launch_bounds__(256) void normwin_kernel(const float* __restrict__ x,
    const float* __restrict__ noise, float* __restrict__ inv,
    __hip_bfloat16* __restrict__ xnh, __hip_bfloat16* __restrict__ xnl,
    int* __restrict__ dsti, int* __restrict__ srci) {
  const int gidx = blockIdx.x;  // b*256 + w
  const int b = gidx >> 8, w = gidx & 255;
  const int wy = w >> 4, wx = w & 15;
  const int t0 = wy * 64 + wx * 2;
  const int wid = threadIdx.x >> 6, lane = threadIdx.x & 63;
  const int tok = t0 + (wid >> 1) * 32 + (wid & 1);
  const int row = (b << 10) + tok;

  const float4* xr = (const float4*)(x + (size_t)row * Dd);  // 288 float4
  float4 v[5];
  float s = 0.f;
  #pragma unroll
  for (int e = 0; e < 4; ++e) {
    v[e] = xr[lane + 64 * e];
    s += v[e].x * v[e].x + v[e].y * v[e].y + v[e].z * v[e].z + v[e].w * v[e].w;
  }
  if (lane < 32) {
    v[4] = xr[256 + lane];
    s += v[4].x * v[4].x + v[4].y * v[4].y + v[4].z * v[4].z + v[4].w * v[4].w;
  } else {
    v[4] = make_float4(0.f, 0.f, 0.f, 0.f);
  }
  #pragma unroll
  for (int m = 1; m < 64; m <<= 1) s += __shfl_xor(s, m);
  float iv = 1.0f / (sqrtf(s) + 1e-6f);
  if (lane == 0) inv[row] = iv;

  __shared__ float4 xns[4][288];
  ushort4* ph = (ushort4*)(xnh + (size_t)row * Dd);
  ushort4* pl = (ushort4*)(xnl + (size_t)row * Dd);
  #pragma unroll
  for (int e = 0; e < 5; ++e) {
    int i = lane + 64 * e;
    if (e < 4 || lane < 32) {
      float4 xn = make_float4(v[e].x * iv, v[e].y * iv, v[e].z * iv, v[e].w * iv);
      xns[wid][i] = xn;
      ushort4 h = bf4(xn);
      __hip_bfloat16 hx = *(__hip_bfloat16*)&h.x, hy = *(__hip_bfloat16*)&h.y;
      __hip_bfloat16 hz = *(__hip_bfloat16*)&h.z, hw = *(__hip_bfloat16*)&h.w;
      float4 lo = make_float4(xn.x - __bfloat162float(hx), xn.y - __bfloat162float(hy),
                              xn.z - __bfloat162float(hz), xn.w - __bfloat162float(hw));
      ph[i] = h;
      pl[i] = bf4(lo);
    }
  }
  __syncthreads();

  float dot = 0.f;
  #pragma unroll
  for (int e = 0; e < 5; ++e) {
    int i = lane + 64 * e;
    if (e < 4 || lane < 32) {
      float4 a0 = xns[0][i], a1 = xns[1][i], a2 = xns[2][i], a3 = xns[3][i];
      float4 sm = make_float4(a0.x + a1.x + a2.x + a3.x, a0.y + a1.y + a2.y + a3.y,
                              a0.z + a1.z + a2.z + a3.z, a0.w + a1.w + a2.w + a3.w);
      dot += (v[e].x * iv) * sm.x + (v[e].y * iv) * sm.y +
             (v[e].z * iv) * sm.z + (v[e].w * iv) * sm.w;
    }
  }
  #pragma unroll
  for (int m = 1; m < 64; m <<= 1) dot += __shfl_xor(dot, m);
  __shared__ float dots[4];
  if (lane == 0) dots[wid] = dot;
  __syncthreads();
  if (threadIdx.x == 0) {
    float best = -1e30f; int bj = 0;
    #pragma unroll
    for (int j = 0; j < 4; ++j) {
      float sc = 0.25f * dots[j] + 0.1f * noise[(size_t)gidx * 4 + j];
      if (sc > best) { best = sc; bj = j; }  // strict > = first-max
    }
    int tk[4] = {t0, t0 + 1, t0 + 32, t0 + 33};
    dsti[b * 256 + w] = tk[bj];
    int m = 0;
    #pragma unroll
    for (int j = 0; j < 4; ++j) if (j != bj) srci[b * 768 + w * 3 + (m++)] = tk[j];
  }
}

// ---------------- sim GEMM (split-bf16 MFMA), 3-ring counted-vmcnt schedule ----------
__global__ __launch_bounds__(256) void simgemm_kernel(
    const __hip_bfloat16* __restrict__ xnh, const __hip_bfloat16* __restrict__ xnl,
    const int* __restrict__ dsti, const int* __restrict__ srci,
    float* __restrict__ mx, int* __restrict__ best) {
  const int q8 = gridDim.x >> 3;
  const int wg = (blockIdx.x & 7) * q8 + (blockIdx.x >> 3);
  int b = wg / 12;
  int m0 = (wg % 12) * 64;
  __shared__ __align__(16) __hip_bfloat16 AsH[3][64 * 32];
  __shared__ __align__(16) __hip_bfloat16 AsL[3][64 * 32];
  __shared__ __align__(16) __hip_bfloat16 BsH[3][256 * 32];
  __shared__ __align__(16) __hip_bfloat16 BsL[3][256 * 32];
  const int tid = threadIdx.x, wid = tid >> 6, lane = tid & 63;
  const int g = lane >> 4, lr = lane & 15;

  const int slotRow = tid >> 2;        // 0..63
  const int colByte = (((tid & 3) ^ ((tid >> 3) & 3)) << 4);
  size_t aRow = (size_t)((b << 10) + srci[b * 768 + m0 + slotRow]) * Dd;
  size_t bRow[4];
  #pragma unroll
  for (int p = 0; p < 4; ++p)
    bRow[p] = (size_t)((b << 10) + dsti[b * 256 + p * 64 + slotRow]) * Dd;
  const char* xh = (const char*)xnh;
  const char* xl = (const char*)xnl;

  auto stage = [&](int slot, int ks) {
    size_t ka = (aRow + ks * 32) * 2 + colByte;
    gload_lds16(xh + ka, (char*)AsH + slot * 4096 + wid * 1024);
    gload_lds16(xl + ka, (char*)AsL + slot * 4096 + wid * 1024);
    #pragma unroll
    for (int p = 0; p < 4; ++p) {
      size_t kb = (bRow[p] + ks * 32) * 2 + colByte;
      gload_lds16(xh + kb, (char*)BsH + slot * 16384 + p * 4096 + wid * 1024);
      gload_lds16(xl + kb, (char*)BsL + slot * 16384 + p * 4096 + wid * 1024);
    }
  };

  f32x4 hh[16], hx[16];
  const f32x4 zf = {0.f, 0.f, 0.f, 0.f};
  #pragma unroll
  for (int nf = 0; nf < 16; ++nf) { hh[nf] = zf; hx[nf] = zf; }

  const int roff = ((g ^ ((lr >> 1) & 3)) << 3);
  stage(0, 0);
  stage(1, 1);
  asm volatile("s_waitcnt vmcnt(10)" ::: "memory");  // retire stage(0)
  __builtin_amdgcn_s_barrier();

  int cur = 0;
  for (int ks = 0; ks < 36; ++ks) {
    bf16x8 ah = *(const bf16x8*)&AsH[cur][(wid * 16 + lr) * 32 + roff];
    bf16x8 al = *(const bf16x8*)&AsL[cur][(wid * 16 + lr) * 32 + roff];
    if (ks + 2 < 36) stage(cur == 0 ? 2 : cur - 1, ks + 2);
    __builtin_amdgcn_s_barrier();
    __builtin_amdgcn_s_setprio(1);
    #pragma unroll
    for (int nf = 0; nf < 16; ++nf) {
      bf16x8 bh = *(const bf16x8*)&BsH[cur][(nf * 16 + lr) * 32 + roff];
      bf16x8 bl = *(const bf16x8*)&BsL[cur][(nf * 16 + lr) * 32 + roff];
      hh[nf] = __builtin_amdgcn_mfma_f32_16x16x32_bf16(ah, bh, hh[nf], 0, 0, 0);
      hx[nf] = __builtin_amdgcn_mfma_f32_16x16x32_bf16(ah, bl, hx[nf], 0, 0, 0);
      hx[nf] = __builtin_amdgcn_mfma_f32_16x16x32_bf16(al, bh, hx[nf], 0, 0, 0);
    }
    __builtin_amdgcn_s_setprio(0);
    if (ks + 2 < 36)      asm volatile("s_waitcnt vmcnt(10)" ::: "memory");
    else if (ks + 1 < 36) asm volatile("s_waitcnt vmcnt(0)" ::: "memory");
    __builtin_amdgcn_s_barrier();
    cur = (cur == 2) ? 0 : cur + 1;
  }

  #pragma unroll
  for (int j = 0; j < 4; ++j) {
    float bv = -1e30f; int bi = 0;
    #pragma unroll
    for (int nf = 0; nf < 16; ++nf) {
      float v = hh[nf][j] + hx[nf][j];
      if (v > bv) { bv = v; bi = nf * 16 + lr; }
    }
    #pragma unroll
    for (int m = 1; m < 16; m <<= 1) {
      float ov = __shfl_xor(bv, m);
      int oi = __shfl_xor(bi, m);
      if (ov > bv || (ov == bv && oi < bi)) { bv = ov; bi = oi; }
    }
    if (lr == 0) {
      int row = m0 + wid * 16 + g * 4 + j;
      mx[b * 768 + row] = bv;
      best[b * 768 + row] = bi;
    }
  }
}

// ---------------- rank (stable argsort of -mx) -> keep_token + src_row ----------------
__global__ __launch_bounds__(256) void rank_kernel(const float* __restrict__ mx,
    const int* __restrict__ best, const int* __restrict__ dsti,
    const int* __restrict__ srci, int* __restrict__ keep, int* __restrict__ srow) {
  int b = blockIdx.x;
  int tid = threadIdx.x;
  __shared__ float smx[768];
  for (int i = tid; i < 768; i += 256) smx[i] = mx[b * 768 + i];
  __syncthreads();
  if (tid < 256) {
    int t = dsti[b * 256 + tid];
    keep[b * 512 + tid] = t;
    srow[b * 1024 + t] = tid;
  }
  for (int i = tid; i < 768; i += 256) {
    float v = smx[i];
    int r = 0;
    for (int s = 0; s < 768; ++s) {
      float u = smx[s];
      r += (u > v) || (u == v && s < i);
    }
    int tok = srci[b * 768 + i];
    if (r >= 512) {
      keep[b * 512 + (r - 256)] = tok;      // xk row = 256 + (r-512)
      srow[b * 1024 + tok] = r - 256;
    } else {
      srow[b * 1024 + tok] = best[b * 768 + i];  // copy dst-row output
    }
  }
}

// ---------------- LayerNorm (optionally gathered), float4 loads ----------------
template<int GATHER>
__global__ __launch_bounds__(256) void ln_kernel(const float* __restrict__ xin,
    const int* __restrict__ keep, const float* __restrict__ gw,
    const float* __restrict__ bw, __hip_bfloat16* __restrict__ yout) {
  int row = blockIdx.x;  // 0..8191
  const float* xr;
  if (GATHER) {
    int b = row >> 9, t = row & 511;
    int tok = keep[(b << 9) + t];
    xr = xin + (size_t)((b << 10) + tok) * Dd;
  } else {
    xr = xin + (size_t)row * Dd;
  }
  int tid = threadIdx.x;
  const float4* xr4 = (const float4*)xr;  // 288 float4
  float4 v0 = xr4[tid];
  float4 v1 = (tid < 32) ? xr4[256 + tid] : make_float4(0.f, 0.f, 0.f, 0.f);
  float s = v0.x + v0.y + v0.z + v0.w + v1.x + v1.y + v1.z + v1.w;
  float s2 = v0.x * v0.x + v0.y * v0.y + v0.z * v0.z + v0.w * v0.w +
             v1.x * v1.x + v1.y * v1.y + v1.z * v1.z + v1.w * v1.w;
  #pragma unroll
  for (int m = 1; m < 64; m <<= 1) { s += __shfl_xor(s, m); s2 += __shfl_xor(s2, m); }
  __shared__ float ps[4], ps2[4];
  int wid = tid >> 6, lane = tid & 63;
  if (lane == 0) { ps[wid] = s; ps2[wid] = s2; }
  __syncthreads();
  s = ps[0] + ps[1] + ps[2] + ps[3];
  s2 = ps2[0] + ps2[1] + ps2[2] + ps2[3];
  constexpr float inv_d = 1.0f / Dd;
  float mu = s * inv_d;
  float var = s2 * inv_d - mu * mu;
  float rstd = rsqrtf(var + 1e-6f);
  const float4* gw4 = (const float4*)gw;
  const float4* bw4 = (const float4*)bw;
  ushort4* yr4 = (ushort4*)(yout + (size_t)row * Dd);
  {
    float4 gv = gw4[tid], bv = bw4[tid];
    float4 o = make_float4((v0.x - mu) * rstd * gv.x + bv.x,
                           (v0.y - mu) * rstd * gv.y + bv.y,
                           (v0.z - mu) * rstd * gv.z + bv.z,
                           (v0.w - mu) * rstd * gv.w + bv.w);
    yr4[tid] = bf4(o);
  }
  if (tid < 32) {
    float4 gv = gw4[256 + tid], bv = bw4[256 + tid];
    float4 o = make_float4((v1.x - mu) * rstd * gv.x + bv.x,
                           (v1.y - mu) * rstd * gv.y + bv.y,
                           (v1.z - mu) * rstd * gv.z + bv.z,
                           (v1.w - mu) * rstd * gv.w + bv.w);
    yr4[256 + tid] = bf4(o);
  }
}

// ---------------- fused weight transpose + bf16 cast for all four weights ----------------
__global__ __launch_bounds__(256) void wtrans_all_kernel(
    const float* __restrict__ w0, __hip_bfloat16* __restrict__ o0,
    const float* __restrict__ w1, __hip_bfloat16* __restrict__ o1,
    const float* __restrict__ w2, __hip_bfloat16* __restrict__ o2,
    const float* __restrict__ w3, __hip_bfloat16* __restrict__ o3) {
  __shared__ float tile[32][33];
  int bid = blockIdx.x;
  const float* w; __hip_bfloat16* wT; int K, N, local;
  if (bid < 3888)       { w = w0; wT = o0; K = 1152; N = 3456; local = bid; }
  else if (bid < 5184)  { w = w1; wT = o1; K = 1152; N = 1152; local = bid - 3888; }
  else if (bid < 10368) { w = w2; wT = o2; K = 1152; N = 4608; local = bid - 5184; }
  else                  { w = w3; wT = o3; K = 4608; N = 1152; local = bid - 10368; }
  int nt = N >> 5;
  int tk = local / nt, tn = local % nt;
  int tid = threadIdx.x;
  #pragma unroll
  for (int e = 0; e < 4; ++e) {
    int idx = tid + e * 256;
    int r = idx >> 5, c = idx & 31;
    tile[r][c] = w[(size_t)(tk * 32 + r) * N + tn * 32 + c];
  }
  __syncthreads();
  #pragma unroll
  for (int e = 0; e < 4; ++e) {
    int idx = tid + e * 256;
    int r = idx >> 5, c = idx & 31;
    wT[(size_t)(tn * 32 + r) * K + tk * 32 + c] = __float2bfloat16(tile[c][r]);
  }
}

// ============ GEMM epilogue helper ============
template<int EPI>
__device__ __forceinline__ void epi_store(void* C, const float* res, int Nd,
                                          size_t row, size_t col, float v) {
  if (EPI == 0) {
    ((__hip_bfloat16*)C)[row * (size_t)Nd + col] = __float2bfloat16(v);
  } else if (EPI == 1) {
    ((float*)C)[row * (size_t)Nd + col] = v + res[row * (size_t)Nd + col];
  } else if (EPI == 2) {
    ((__hip_bfloat16*)C)[row * (size_t)Nd + col] = __float2bfloat16(gelu_f(v));
  }
}

// ---------------- GEMM 128x256 lockstep (8 waves, 2 blk/CU) — qkv ----------
// EPI==4: cols < 2304 (Q,K) -> qkvb bf16; cols >= 2304 (V) -> direct transposed vT store.
template<int EPI>
__global__ __launch_bounds__(512, 4) void gemm128_kernel(
    const __hip_bfloat16* __restrict__ A, const __hip_bfloat16* __restrict__ BT,
    const float* __restrict__ bias, const float* __restrict__ res,
    __hip_bfloat16* __restrict__ vTout,
    void* __restrict__ C, int Md, int Nd, int NdPad, int Kd) {
  constexpr int BM = 128;
  __shared__ __align__(16) __hip_bfloat16 As[3][BM * 32];
  __shared__ __align__(16) __hip_bfloat16 Bs[3][256 * 32];
  const int nb = NdPad >> 8;
  const int q8 = gridDim.x >> 3;
  const int wg = (blockIdx.x & 7) * q8 + (blockIdx.x >> 3);
  const int bm = wg / nb, bnb = wg % nb;
  const int tid = threadIdx.x, wid = tid >> 6, lane = tid & 63;
  const int g = lane >> 4, lr = lane & 15;
  const int wm = wid >> 2, wn = wid & 3;
  const size_t m0 = (size_t)bm * BM, n0 = (size_t)bnb * 256;

  const int trow = tid >> 2;
  const int scol = (((tid & 3) ^ ((tid >> 3) & 3)) << 3);
  const char* Ab = (const char*)A;
  const char* Bb = (const char*)BT;

  auto stage = [&](int slot, int kt) {
    const size_t kb = ((size_t)kt << 5) + scol;
    gload_lds16(Ab + (((m0 + trow) * (size_t)Kd + kb) << 1),
                (char*)As + slot * 8192 + wid * 1024);
    gload_lds16(Bb + (((n0 + trow) * (size_t)Kd + kb) << 1),
                (char*)Bs + slot * 16384 + wid * 1024);
    gload_lds16(Bb + (((n0 + 128 + trow) * (size_t)Kd + kb) << 1),
                (char*)Bs + slot * 16384 + 8192 + wid * 1024);
  };

  f32x4 acc[4][4];
  const f32x4 zf = {0.f, 0.f, 0.f, 0.f};
  #pragma unroll
  for (int mi = 0; mi < 4; ++mi)
    #pragma unroll
    for (int ni = 0; ni < 4; ++ni) acc[mi][ni] = zf;

  const int nk = Kd >> 5;
  stage(0, 0);
  stage(1, 1);
  asm volatile("s_waitcnt vmcnt(3)" ::: "memory");
  __builtin_amdgcn_s_barrier();

  int cur = 0;
  const int roff = ((g ^ ((lr >> 1) & 3)) << 3);
  for (int kt = 0; kt < nk; ++kt) {
    const __hip_bfloat16* Ac = As[cur];
    const __hip_bfloat16* Bc = Bs[cur];
    bf16x8 af[4], bf[4];
    #pragma unroll
    for (int mi = 0; mi < 4; ++mi)
      af[mi] = *(const bf16x8*)&Ac[(wm * 64 + mi * 16 + lr) * 32 + roff];
    #pragma unroll
    for (int ni = 0; ni < 4; ++ni)
      bf[ni] = *(const bf16x8*)&Bc[(wn * 64 + ni * 16 + lr) * 32 + roff];
    if (kt + 2 < nk) stage(cur == 0 ? 2 : cur - 1, kt + 2);
    __builtin_amdgcn_s_barrier();
    __builtin_amdgcn_s_setprio(1);
    #pragma unroll
    for (int mi = 0; mi < 4; ++mi)
      #pragma unroll
      for (int ni = 0; ni < 4; ++ni)
        acc[mi][ni] = __builtin_amdgcn_mfma_f32_16x16x32_bf16(af[mi], bf[ni], acc[mi][ni], 0, 0, 0);
    __builtin_amdgcn_s_setprio(0);
    if (kt + 2 < nk)      asm volatile("s_waitcnt vmcnt(3)" ::: "memory");
    else if (kt + 1 < nk) asm volatile("s_waitcnt vmcnt(0)" ::: "memory");
    __builtin_amdgcn_s_barrier();
    cur = (cur == 2) ? 0 : cur + 1;
  }

  #pragma unroll
  for (int ni = 0; ni < 4; ++ni) {
    size_t col = n0 + wn * 64 + ni * 16 + lr;
    if (col < (size_t)Nd) {
      float bv = bias[col];
      if (EPI == 4 && col >= 2304) {
        int vc = (int)col - 2304;
        int h = vc / 72, d = vc % 72;
        #pragma unroll
        for (int mi = 0; mi < 4; ++mi) {
          #pragma unroll
          for (int j = 0; j < 4; ++j) {
            size_t row = m0 + wm * 64 + mi * 16 + g * 4 + j;
            int bb = (int)(row >> 9), t = (int)(row & 511);
            vTout[(((size_t)(bb * 16 + h)) * 80 + d) * 512 + t] =
                __float2bfloat16(acc[mi][ni][j] + bv);
          }
        }
      } else {
        #pragma unroll
        for (int mi = 0; mi < 4; ++mi) {
          #pragma unroll
          for (int j = 0; j < 4; ++j) {
            size_t row = m0 + wm * 64 + mi * 16 + g * 4 + j;
            float v = acc[mi][ni][j] + bv;
            if (EPI == 4) {
              ((__hip_bfloat16*)C)[row * (size_t)Nd + col] = __float2bfloat16(v);
            } else {
              epi_store<EPI>(C, res, Nd, row, col, v);
            }
          }
        }
      }
    }
  }
}

// ---------------- GEMM 128x128, 4 waves, 3 blk/CU, reg-double-buffered overlap ----------
template<int EPI>
__global__ __launch_bounds__(256, 3) void gemm128v_kernel(
    const __hip_bfloat16* __restrict__ A, const __hip_bfloat16* __restrict__ BT,
    const float* __restrict__ bias, const float* __restrict__ res,
    const int* __restrict__ keepIdx, const float* __restrict__ xsrc,
    void* __restrict__ C, int Md, int Nd, int Kd) {
  __shared__ __align__(16) __hip_bfloat16 As[3][128 * 32];
  __shared__ __align__(16) __hip_bfloat16 Bs[3][128 * 32];
  const int nb = Nd >> 7;
  const int q8 = gridDim.x >> 3;
  const int wg = (blockIdx.x & 7) * q8 + (blockIdx.x >> 3);
  const int bm = wg / nb, bnb = wg % nb;
  const int tid = threadIdx.x, wid = tid >> 6, lane = tid & 63;
  const int g = lane >> 4, lr = lane & 15;
  const int wm = wid >> 1, wn = wid & 1;  // wave tile 64x64
  const size_t m0 = (size_t)bm * 128, n0 = (size_t)bnb * 128;

  const int trow = tid >> 2;  // 0..63
  const int scol = (((tid & 3) ^ ((tid >> 3) & 3)) << 3);
  const char* Ab = (const char*)A;
  const char* Bb = (const char*)BT;

  auto stage = [&](int slot, int kt) {
    const size_t kb = ((size_t)kt << 5) + scol;
    #pragma unroll
    for (int c = 0; c < 2; ++c)
      gload_lds16(Ab + (((m0 + c * 64 + trow) * (size_t)Kd + kb) << 1),
                  (char*)As + slot * 8192 + c * 4096 + tid * 16);
    #pragma unroll
    for (int c = 0; c < 2; ++c)
      gload_lds16(Bb + (((n0 + c * 64 + trow) * (size_t)Kd + kb) << 1),
                  (char*)Bs + slot * 8192 + c * 4096 + tid * 16);
  };

  f32x4 acc[4][4];
  const f32x4 zf = {0.f, 0.f, 0.f, 0.f};
  #pragma unroll
  for (int mi = 0; mi < 4; ++mi)
    #pragma unroll
    for (int ni = 0; ni < 4; ++ni) acc[mi][ni] = zf;

  const int roff = ((g ^ ((lr >> 1) & 3)) << 3);
  const int nk = Kd >> 5;

  bf16x8 afA[4], bfA[4], afB[4], bfB[4];

#define DSREAD(AF, BF, SLOT) { \
  const __hip_bfloat16* Ac_ = As[SLOT]; \
  const __hip_bfloat16* Bc_ = Bs[SLOT]; \
  _Pragma("unroll") for (int mi_ = 0; mi_ < 4; ++mi_) \
    AF[mi_] = *(const bf16x8*)&Ac_[(wm * 64 + mi_ * 16 + lr) * 32 + roff]; \
  _Pragma("unroll") for (int ni_ = 0; ni_ < 4; ++ni_) \
    BF[ni_] = *(const bf16x8*)&Bc_[(wn * 64 + ni_ * 16 + lr) * 32 + roff]; }

#define MFMA16(AF, BF) { \
  __builtin_amdgcn_s_setprio(1); \
  _Pragma("unroll") for (int mi_ = 0; mi_ < 4; ++mi_) \
    _Pragma("unroll") for (int ni_ = 0; ni_ < 4; ++ni_) \
      acc[mi_][ni_] = __builtin_amdgcn_mfma_f32_16x16x32_bf16(AF[mi_], BF[ni_], acc[mi_][ni_], 0, 0, 0); \
  __builtin_amdgcn_s_setprio(0); }

#define GITER(KT, S0, S1, AFC, BFC, AFN, BFN) { \
  if ((KT) <= nk - 3)      { asm volatile("s_waitcnt vmcnt(4)" ::: "memory"); } \
  else if ((KT) == nk - 2) { asm volatile("s_waitcnt vmcnt(0)" ::: "memory"); } \
  asm volatile("s_waitcnt lgkmcnt(0)" ::: "memory"); \
  __builtin_amdgcn_s_barrier(); \
  asm volatile("" ::: "memory"); \
  if ((KT) + 1 < nk) DSREAD(AFN, BFN, (S1)); \
  if ((KT) + 3 < nk) stage((S0), (KT) + 3); \
  MFMA16(AFC, BFC); }

  stage(0, 0); stage(1, 1); stage(2, 2);
  asm volatile("s_waitcnt vmcnt(8)" ::: "memory");  // retire stage(0)
  __builtin_amdgcn_s_barrier();
  asm volatile("" ::: "memory");
  DSREAD(afA, bfA, 0);

  int s0 = 0, s1 = 1;
  for (int kt = 0; kt < nk; kt += 2) {
    GITER(kt, s0, s1, afA, bfA, afB, bfB);
    int s2 = (s1 == 2) ? 0 : s1 + 1;
    GITER(kt + 1, s1, s2, afB, bfB, afA, bfA);
    s0 = s2; s1 = (s2 == 2) ? 0 : s2 + 1;
  }
#undef GITER
#undef MFMA16
#undef DSREAD

  #pragma unroll
  for (int ni = 0; ni < 4; ++ni) {
    size_t col = n0 + wn * 64 + ni * 16 + lr;
    float bv = bias[col];
    #pragma unroll
    for (int mi = 0; mi < 4; ++mi) {
      #pragma unroll
      for (int j = 0; j < 4; ++j) {
        size_t row = m0 + wm * 64 + mi * 16 + g * 4 + j;
        float v = acc[mi][ni][j] + bv;
        if (EPI == 3) {
          int b = (int)(row >> 9);
          int tok = keepIdx[row];
          const float* rr = xsrc + ((size_t)(b << 10) + tok) * Dd;
          ((float*)C)[row * (size_t)Nd + col] = v + rr[col];
        } else {
          epi_store<EPI>(C, res, Nd, row, col, v);
        }
      }
    }
  }
}

// ---------------- flash attention per (b,h,q-PAIR of 64-row tiles) ----------------
__global__ __launch_bounds__(256) void attn_kernel(const __hip_bfloat16* __restrict__ qkv,
    const __hip_bfloat16* __restrict__ vT, __hip_bfloat16* __restrict__ o) {
  const int blk = blockIdx.x;
  const int qp = blk & 3, bh = blk >> 2;  // qp: 128-row pair
  const int b = bh >> 4, h = bh & 15;
  __shared__ __align__(16) __hip_bfloat16 Qs[128][104];
  __shared__ __align__(16) __hip_bfloat16 Ks[64][104];
  __shared__ __align__(16) __hip_bfloat16 Vs[80][72];
  __shared__ __align__(16) __hip_bfloat16 Ps[4][16][72];
  const int tid = threadIdx.x, wid = tid >> 6, lane = tid & 63;
  const int g = lane >> 4, lr = lane & 15;
  const __hip_bfloat16 zb = __float2bfloat16(0.0f);

  for (int idx = tid; idx < 128 * 18; idx += 256) {
    int r = idx / 18, c = idx % 18;
    *(ushort4*)&Qs[r][c * 4] =
        *(const ushort4*)&qkv[((size_t)(b * 512 + qp * 128 + r)) * 3456 + h * 72 + c * 4];
  }
  for (int idx = tid; idx < 128 * 32; idx += 256) {
    int r = idx / 32, d = 72 + idx % 32;
    Qs[r][d] = zb;
    if (r < 64) Ks[r][d] = zb;
  }
  for (int idx = tid; idx < 8 * 72; idx += 256) {
    Vs[72 + idx / 72][idx % 72] = zb;  // pad rows, never re-written
  }

  f32x4 ov0[5], ov1[5];
  const f32x4 zf = {0.f, 0.f, 0.f, 0.f};
  #pragma unroll
  for (int ni = 0; ni < 5; ++ni) { ov0[ni] = zf; ov1[ni] = zf; }
  float m0_[4], l0_[4], m1_[4], l1_[4];
  #pragma unroll
  for (int j = 0; j < 4; ++j) {
    m0_[j] = -3.0e38f; l0_[j] = 0.f;
    m1_[j] = -3.0e38f; l1_[j] = 0.f;
  }
  const float scale = 0.11785113019775793f;  // 1/sqrt(72)

  for (int c = 0; c < 8; ++c) {
    __syncthreads();
    for (int idx = tid; idx < 64 * 18; idx += 256) {
      int r = idx / 18, cc = idx % 18;
      *(ushort4*)&Ks[r][cc * 4] =
          *(const ushort4*)&qkv[((size_t)(b * 512 + c * 64 + r)) * 3456 + 1152 + h * 72 + cc * 4];
    }
    for (int idx = tid; idx < 72 * 8; idx += 256) {
      int d = idx >> 3, t8 = idx & 7;
      *(uint4*)&Vs[d][t8 * 8] =
          *(const uint4*)&vT[((size_t)bh * 80 + d) * 512 + c * 64 + t8 * 8];
    }
    __syncthreads();

    #pragma unroll
    for (int qh = 0; qh < 2; ++qh) {
      float* m_ = qh ? m1_ : m0_;
      float* l_ = qh ? l1_ : l0_;
      f32x4* ov = qh ? ov1 : ov0;

      f32x4 sf[4];
      #pragma unroll
      for (int nf = 0; nf < 4; ++nf) sf[nf] = zf;
      #pragma unroll
      for (int ks = 0; ks < 3; ++ks) {
        bf16x8 qa = *(const bf16x8*)&Qs[qh * 64 + wid * 16 + lr][ks * 32 + g * 8];
        #pragma unroll
        for (int nf = 0; nf < 4; ++nf) {
          bf16x8 kb = *(const bf16x8*)&Ks[nf * 16 + lr][ks * 32 + g * 8];
          sf[nf] = __builtin_amdgcn_mfma_f32_16x16x32_bf16(qa, kb, sf[nf], 0, 0, 0);
        }
      }

      float cm[4];
      #pragma unroll
      for (int j = 0; j < 4; ++j)
        cm[j] = fmaxf(fmaxf(sf[0][j], sf[1][j]), fmaxf(sf[2][j], sf[3][j])) * scale;
      #pragma unroll
      for (int mm = 1; mm < 16; mm <<= 1)
        #pragma unroll
        for (int j = 0; j < 4; ++j) cm[j] = fmaxf(cm[j], __shfl_xor(cm[j], mm));
      float fac[4], rs[4];
      #pragma unroll
      for (int j = 0; j < 4; ++j) {
        float nm = fmaxf(m_[j], cm[j]);
        fac[j] = __expf(m_[j] - nm);
        m_[j] = nm;
        rs[j] = 0.f;
      }
      #pragma unroll
      for (int nf = 0; nf < 4; ++nf)
        #pragma unroll
        for (int j = 0; j < 4; ++j) {
          float pv = __expf(sf[nf][j] * scale - m_[j]);
          rs[j] += pv;
          Ps[wid][g * 4 + j][nf * 16 + lr] = __float2bfloat16(pv);
        }
      #pragma unroll
      for (int mm = 1; mm < 16; mm <<= 1)
        #pragma unroll
        for (int j = 0; j < 4; ++j) rs[j] += __shfl_xor(rs[j], mm);
      #pragma unroll
      for (int j = 0; j < 4; ++j) l_[j] = l_[j] * fac[j] + rs[j];
      #pragma unroll
      for (int ni = 0; ni < 5; ++ni)
        #pragma unroll
        for (int j = 0; j < 4; ++j) ov[ni][j] *= fac[j];

      #pragma unroll
      for (int k2 = 0; k2 < 2; ++k2) {
        bf16x8 pa = *(const bf16x8*)&Ps[wid][lr][k2 * 32 + g * 8];
        #pragma unroll
        for (int ni = 0; ni < 5; ++ni) {
          bf16x8 vb = *(const bf16x8*)&Vs[ni * 16 + lr][k2 * 32 + g * 8];
          ov[ni] = __builtin_amdgcn_mfma_f32_16x16x32_bf16(pa, vb, ov[ni], 0, 0, 0);
        }
      }
    }
  }

  #pragma unroll
  for (int qh = 0; qh < 2; ++qh) {
    const f32x4* ov = qh ? ov1 : ov0;
    const float* l_ = qh ? l1_ : l0_;
    #pragma unroll
    for (int ni = 0; ni < 5; ++ni) {
      int d = ni * 16 + lr;
      if (d < 72) {
        #pragma unroll
        for (int j = 0; j < 4; ++j) {
          int t = qp * 128 + qh * 64 + wid * 16 + g * 4 + j;
          o[((size_t)(b * 512 + t)) * 1152 + h * 72 + d] = __float2bfloat16(ov[ni][j] / l_[j]);
        }
      }
    }
  }
}

// ---------------- final recovery: out[b,n,:] = yout[b, src_row[b,n], :] ----------------
__global__ __launch_bounds__(256) void recover_kernel(const float* __restrict__ yout,
    const int* __restrict__ srow, float* __restrict__ out) {
  int idx = blockIdx.x * 256 + threadIdx.x;  // over B*N*288 float4s
  int q = idx % 288;
  int bnv = idx / 288;  // b*1024+n
  int r = srow[bnv];
  int b = bnv >> 10;
  const float4* src = (const float4*)yout + ((size_t)((b << 9) + r)) * 288 + q;
  ((float4*)out)[idx] = *src;
}

}  // namespace

extern "C" void kernel_launch(void* const* d_in, const int* in_sizes, int n_in,
                              void* d_out, int out_size, void* d_ws, size_t ws_size,
                              hipStream_t stream) {
  (void)in_sizes; (void)n_in; (void)out_size; (void)ws_size;
  const float* x      = (const float*)d_in[0];
  const float* noise  = (const float*)d_in[1];
  const float* ln1_g  = (const float*)d_in[2];
  const float* ln1_b  = (const float*)d_in[3];
  const float* ln2_g  = (const float*)d_in[4];
  const float* ln2_b  = (const float*)d_in[5];
  const float* w_qkv  = (const float*)d_in[6];
  const float* b_qkv  = (const float*)d_in[7];
  const float* w_proj = (const float*)d_in[8];
  const float* b_proj = (const float*)d_in[9];
  const float* w_fc1  = (const float*)d_in[10];
  const float* b_fc1  = (const float*)d_in[11];
  const float* w_fc2  = (const float*)d_in[12];
  const float* b_fc2  = (const float*)d_in[13];
  float* out = (float*)d_out;

  char* p = (char*)d_ws;
  auto alloc = [&](size_t bytes) {
    char* r = p;
    p += (bytes + 255) & ~(size_t)255;
    return r;
  };
  __hip_bfloat16* wqkvT  = (__hip_bfloat16*)alloc((size_t)3584 * 1152 * 2);
  __hip_bfloat16* wprojT = (__hip_bfloat16*)alloc((size_t)1280 * 1152 * 2);
  __hip_bfloat16* wfc1T  = (__hip_bfloat16*)alloc((size_t)4608 * 1152 * 2);
  __hip_bfloat16* wfc2T  = (__hip_bfloat16*)alloc((size_t)1280 * 4608 * 2);
  float* inv = (float*)alloc(16384 * 4);
  int* dsti  = (int*)alloc(4096 * 4);
  int* srci  = (int*)alloc(12288 * 4);
  float* mx  = (float*)alloc(12288 * 4);
  int* best  = (int*)alloc(12288 * 4);
  int* keep  = (int*)alloc(8192 * 4);
  int* srow  = (int*)alloc(16384 * 4);
  float* yout = (float*)alloc((size_t)8192 * 1152 * 4);
  __hip_bfloat16* y1   = (__hip_bfloat16*)alloc((size_t)8192 * 1152 * 2);  // also y2
  __hip_bfloat16* qkvb = (__hip_bfloat16*)alloc((size_t)8192 * 4608 * 2);  // also h (fc1 out)
  __hip_bfloat16* vT   = (__hip_bfloat16*)alloc((size_t)256 * 80 * 512 * 2);
  __hip_bfloat16* ob   = (__hip_bfloat16*)alloc((size_t)8192 * 1152 * 2);
  float* x2 = (float*)alloc((size_t)8192 * 1152 * 4);

  // xn hi/lo planes alias qkvb (dead until gemm writes it, exactly 2x 37.75MB)
  __hip_bfloat16* xnh = qkvb;
  __hip_bfloat16* xnl = qkvb + (size_t)16 * 1024 * 1152;

  // weights -> bf16 transposed (single fused launch)
  wtrans_all_kernel<<<15552, 256, 0, stream>>>(w_qkv, wqkvT, w_proj, wprojT,
                                               w_fc1, wfc1T, w_fc2, wfc2T);

  // SiTo indices (norm + window fused)
  normwin_kernel<<<4096, 256, 0, stream>>>(x, noise, inv, xnh, xnl, dsti, srci);
  simgemm_kernel<<<16 * 12, 256, 0, stream>>>(xnh, xnl, dsti, srci, mx, best);
  rank_kernel<<<16, 256, 0, stream>>>(mx, best, dsti, srci, keep, srow);

  // DiT block on kept tokens
  ln_kernel<1><<<8192, 256, 0, stream>>>(x, keep, ln1_g, ln1_b, y1);
  gemm128_kernel<4><<<64 * 14, 512, 0, stream>>>(y1, wqkvT, b_qkv, nullptr, vT,
                                                 qkvb, 8192, 3456, 3584, 1152);
  attn_kernel<<<1024, 256, 0, stream>>>(qkvb, vT, ob);
  gemm128v_kernel<3><<<64 * 9, 256, 0, stream>>>(ob, wprojT, b_proj, nullptr, keep, x,
                                                 x2, 8192, 1152, 1152);
  ln_kernel<0><<<8192, 256, 0, stream>>>(x2, nullptr, ln2_g, ln2_b, y1);
  gemm128v_kernel<2><<<64 * 36, 256, 0, stream>>>(y1, wfc1T, b_fc1, nullptr, nullptr, nullptr,
                                                  qkvb, 8192, 4608, 1152);
  gemm128v_kernel<1><<<64 * 9, 256, 0, stream>>>(qkvb, wfc2T, b_fc2, x2, nullptr, nullptr,
                                                 yout, 8192, 1152, 4608);

  // scatter-as-gather recovery
  recover_kernel<<<18432, 256, 0, stream>>>(yout, srow, out);
}

// Round 21
// 668.907 us; speedup vs baseline: 1.1092x; 1.0176x over previous
//
#include <hip/hip_runtime.h>
#include <hip/hip_bf16.h>

namespace {

constexpr int Dd = 1152;

typedef __attribute__((ext_vector_type(8))) short bf16x8;
typedef __attribute__((ext_vector_type(4))) float f32x4;

__device__ __forceinline__ void gload_lds16(const void* g, void* l) {
  __builtin_amdgcn_global_load_lds(
      (const __attribute__((address_space(1))) void*)g,
      (__attribute__((address_space(3))) void*)l, 16, 0, 0);
}

__device__ __forceinline__ float gelu_f(float x) {
  float x3 = x * x * x;
  float z2 = 1.5957691216057308f * (x + 0.044715f * x3);
  float e = __expf(fminf(z2, 30.0f));
  return x * e / (e + 1.0f);
}

__device__ __forceinline__ ushort4 bf4(float4 v) {
  __hip_bfloat16 a = __float2bfloat16(v.x), b = __float2bfloat16(v.y);
  __hip_bfloat16 c = __float2bfloat16(v.z), d = __float2bfloat16(v.w);
  return make_ushort4(*(ushort*)&a, *(ushort*)&b, *(ushort*)&c, *(ushort*)&d);
}

__device__ __forceinline__ float4 f4(ushort4 v) {
  return make_float4(__bfloat162float(*(__hip_bfloat16*)&v.x),
                     __bfloat162float(*(__hip_bfloat16*)&v.y),
                     __bfloat162float(*(__hip_bfloat16*)&v.z),
                     __bfloat162float(*(__hip_bfloat16*)&v.w));
}

// ---------------- fused norm + window scoring (float4 loads) ----------------
__global__ __launch_bounds__(256) void normwin_kernel(const float* __restrict__ x,
    const float* __restrict__ noise, float* __restrict__ inv,
    __hip_bfloat16* __restrict__ xnh, __hip_bfloat16* __restrict__ xnl,
    int* __restrict__ dsti, int* __restrict__ srci) {
  const int gidx = blockIdx.x;  // b*256 + w
  const int b = gidx >> 8, w = gidx & 255;
  const int wy = w >> 4, wx = w & 15;
  const int t0 = wy * 64 + wx * 2;
  const int wid = threadIdx.x >> 6, lane = threadIdx.x & 63;
  const int tok = t0 + (wid >> 1) * 32 + (wid & 1);
  const int row = (b << 10) + tok;

  const float4* xr = (const float4*)(x + (size_t)row * Dd);  // 288 float4
  float4 v[5];
  float s = 0.f;
  #pragma unroll
  for (int e = 0; e < 4; ++e) {
    v[e] = xr[lane + 64 * e];
    s += v[e].x * v[e].x + v[e].y * v[e].y + v[e].z * v[e].z + v[e].w * v[e].w;
  }
  if (lane < 32) {
    v[4] = xr[256 + lane];
    s += v[4].x * v[4].x + v[4].y * v[4].y + v[4].z * v[4].z + v[4].w * v[4].w;
  } else {
    v[4] = make_float4(0.f, 0.f, 0.f, 0.f);
  }
  #pragma unroll
  for (int m = 1; m < 64; m <<= 1) s += __shfl_xor(s, m);
  float iv = 1.0f / (sqrtf(s) + 1e-6f);
  if (lane == 0) inv[row] = iv;

  __shared__ float4 xns[4][288];
  ushort4* ph = (ushort4*)(xnh + (size_t)row * Dd);
  ushort4* pl = (ushort4*)(xnl + (size_t)row * Dd);
  #pragma unroll
  for (int e = 0; e < 5; ++e) {
    int i = lane + 64 * e;
    if (e < 4 || lane < 32) {
      float4 xn = make_float4(v[e].x * iv, v[e].y * iv, v[e].z * iv, v[e].w * iv);
      xns[wid][i] = xn;
      ushort4 h = bf4(xn);
      __hip_bfloat16 hx = *(__hip_bfloat16*)&h.x, hy = *(__hip_bfloat16*)&h.y;
      __hip_bfloat16 hz = *(__hip_bfloat16*)&h.z, hw = *(__hip_bfloat16*)&h.w;
      float4 lo = make_float4(xn.x - __bfloat162float(hx), xn.y - __bfloat162float(hy),
                              xn.z - __bfloat162float(hz), xn.w - __bfloat162float(hw));
      ph[i] = h;
      pl[i] = bf4(lo);
    }
  }
  __syncthreads();

  float dot = 0.f;
  #pragma unroll
  for (int e = 0; e < 5; ++e) {
    int i = lane + 64 * e;
    if (e < 4 || lane < 32) {
      float4 a0 = xns[0][i], a1 = xns[1][i], a2 = xns[2][i], a3 = xns[3][i];
      float4 sm = make_float4(a0.x + a1.x + a2.x + a3.x, a0.y + a1.y + a2.y + a3.y,
                              a0.z + a1.z + a2.z + a3.z, a0.w + a1.w + a2.w + a3.w);
      dot += (v[e].x * iv) * sm.x + (v[e].y * iv) * sm.y +
             (v[e].z * iv) * sm.z + (v[e].w * iv) * sm.w;
    }
  }
  #pragma unroll
  for (int m = 1; m < 64; m <<= 1) dot += __shfl_xor(dot, m);
  __shared__ float dots[4];
  if (lane == 0) dots[wid] = dot;
  __syncthreads();
  if (threadIdx.x == 0) {
    float best = -1e30f; int bj = 0;
    #pragma unroll
    for (int j = 0; j < 4; ++j) {
      float sc = 0.25f * dots[j] + 0.1f * noise[(size_t)gidx * 4 + j];
      if (sc > best) { best = sc; bj = j; }  // strict > = first-max
    }
    int tk[4] = {t0, t0 + 1, t0 + 32, t0 + 33};
    dsti[b * 256 + w] = tk[bj];
    int m = 0;
    #pragma unroll
    for (int j = 0; j < 4; ++j) if (j != bj) srci[b * 768 + w * 3 + (m++)] = tk[j];
  }
}

// ---------------- sim GEMM (split-bf16 MFMA), 3-ring counted-vmcnt schedule ----------
__global__ __launch_bounds__(256) void simgemm_kernel(
    const __hip_bfloat16* __restrict__ xnh, const __hip_bfloat16* __restrict__ xnl,
    const int* __restrict__ dsti, const int* __restrict__ srci,
    float* __restrict__ mx, int* __restrict__ best) {
  const int q8 = gridDim.x >> 3;
  const int wg = (blockIdx.x & 7) * q8 + (blockIdx.x >> 3);
  int b = wg / 12;
  int m0 = (wg % 12) * 64;
  __shared__ __align__(16) __hip_bfloat16 AsH[3][64 * 32];
  __shared__ __align__(16) __hip_bfloat16 AsL[3][64 * 32];
  __shared__ __align__(16) __hip_bfloat16 BsH[3][256 * 32];
  __shared__ __align__(16) __hip_bfloat16 BsL[3][256 * 32];
  const int tid = threadIdx.x, wid = tid >> 6, lane = tid & 63;
  const int g = lane >> 4, lr = lane & 15;

  const int slotRow = tid >> 2;        // 0..63
  const int colByte = (((tid & 3) ^ ((tid >> 3) & 3)) << 4);
  size_t aRow = (size_t)((b << 10) + srci[b * 768 + m0 + slotRow]) * Dd;
  size_t bRow[4];
  #pragma unroll
  for (int p = 0; p < 4; ++p)
    bRow[p] = (size_t)((b << 10) + dsti[b * 256 + p * 64 + slotRow]) * Dd;
  const char* xh = (const char*)xnh;
  const char* xl = (const char*)xnl;

  auto stage = [&](int slot, int ks) {
    size_t ka = (aRow + ks * 32) * 2 + colByte;
    gload_lds16(xh + ka, (char*)AsH + slot * 4096 + wid * 1024);
    gload_lds16(xl + ka, (char*)AsL + slot * 4096 + wid * 1024);
    #pragma unroll
    for (int p = 0; p < 4; ++p) {
      size_t kb = (bRow[p] + ks * 32) * 2 + colByte;
      gload_lds16(xh + kb, (char*)BsH + slot * 16384 + p * 4096 + wid * 1024);
      gload_lds16(xl + kb, (char*)BsL + slot * 16384 + p * 4096 + wid * 1024);
    }
  };

  f32x4 hh[16], hx[16];
  const f32x4 zf = {0.f, 0.f, 0.f, 0.f};
  #pragma unroll
  for (int nf = 0; nf < 16; ++nf) { hh[nf] = zf; hx[nf] = zf; }

  const int roff = ((g ^ ((lr >> 1) & 3)) << 3);
  stage(0, 0);
  stage(1, 1);
  asm volatile("s_waitcnt vmcnt(10)" ::: "memory");  // retire stage(0)
  __builtin_amdgcn_s_barrier();

  int cur = 0;
  for (int ks = 0; ks < 36; ++ks) {
    bf16x8 ah = *(const bf16x8*)&AsH[cur][(wid * 16 + lr) * 32 + roff];
    bf16x8 al = *(const bf16x8*)&AsL[cur][(wid * 16 + lr) * 32 + roff];
    if (ks + 2 < 36) stage(cur == 0 ? 2 : cur - 1, ks + 2);
    __builtin_amdgcn_s_barrier();
    __builtin_amdgcn_s_setprio(1);
    #pragma unroll
    for (int nf = 0; nf < 16; ++nf) {
      bf16x8 bh = *(const bf16x8*)&BsH[cur][(nf * 16 + lr) * 32 + roff];
      bf16x8 bl = *(const bf16x8*)&BsL[cur][(nf * 16 + lr) * 32 + roff];
      hh[nf] = __builtin_amdgcn_mfma_f32_16x16x32_bf16(ah, bh, hh[nf], 0, 0, 0);
      hx[nf] = __builtin_amdgcn_mfma_f32_16x16x32_bf16(ah, bl, hx[nf], 0, 0, 0);
      hx[nf] = __builtin_amdgcn_mfma_f32_16x16x32_bf16(al, bh, hx[nf], 0, 0, 0);
    }
    __builtin_amdgcn_s_setprio(0);
    if (ks + 2 < 36)      asm volatile("s_waitcnt vmcnt(10)" ::: "memory");
    else if (ks + 1 < 36) asm volatile("s_waitcnt vmcnt(0)" ::: "memory");
    __builtin_amdgcn_s_barrier();
    cur = (cur == 2) ? 0 : cur + 1;
  }

  #pragma unroll
  for (int j = 0; j < 4; ++j) {
    float bv = -1e30f; int bi = 0;
    #pragma unroll
    for (int nf = 0; nf < 16; ++nf) {
      float v = hh[nf][j] + hx[nf][j];
      if (v > bv) { bv = v; bi = nf * 16 + lr; }
    }
    #pragma unroll
    for (int m = 1; m < 16; m <<= 1) {
      float ov = __shfl_xor(bv, m);
      int oi = __shfl_xor(bi, m);
      if (ov > bv || (ov == bv && oi < bi)) { bv = ov; bi = oi; }
    }
    if (lr == 0) {
      int row = m0 + wid * 16 + g * 4 + j;
      mx[b * 768 + row] = bv;
      best[b * 768 + row] = bi;
    }
  }
}

// ---------------- rank (stable argsort of -mx) -> keep_token + src_row ----------------
__global__ __launch_bounds__(256) void rank_kernel(const float* __restrict__ mx,
    const int* __restrict__ best, const int* __restrict__ dsti,
    const int* __restrict__ srci, int* __restrict__ keep, int* __restrict__ srow) {
  int b = blockIdx.x;
  int tid = threadIdx.x;
  __shared__ float smx[768];
  for (int i = tid; i < 768; i += 256) smx[i] = mx[b * 768 + i];
  __syncthreads();
  if (tid < 256) {
    int t = dsti[b * 256 + tid];
    keep[b * 512 + tid] = t;
    srow[b * 1024 + t] = tid;
  }
  for (int i = tid; i < 768; i += 256) {
    float v = smx[i];
    int r = 0;
    for (int s = 0; s < 768; ++s) {
      float u = smx[s];
      r += (u > v) || (u == v && s < i);
    }
    int tok = srci[b * 768 + i];
    if (r >= 512) {
      keep[b * 512 + (r - 256)] = tok;      // xk row = 256 + (r-512)
      srow[b * 1024 + tok] = r - 256;
    } else {
      srow[b * 1024 + tok] = best[b * 768 + i];  // copy dst-row output
    }
  }
}

// ---------------- LayerNorm (optionally gathered / bf16 input), float4-class loads -------
template<int GATHER, int BFIN>
__global__ __launch_bounds__(256) void ln_kernel(const void* __restrict__ xin,
    const int* __restrict__ keep, const float* __restrict__ gw,
    const float* __restrict__ bw, __hip_bfloat16* __restrict__ yout) {
  int row = blockIdx.x;  // 0..8191
  size_t srow_;
  if (GATHER) {
    int b = row >> 9, t = row & 511;
    int tok = keep[(b << 9) + t];
    srow_ = (size_t)((b << 10) + tok);
  } else {
    srow_ = (size_t)row;
  }
  int tid = threadIdx.x;
  float4 v0, v1;
  if (BFIN) {
    const ushort4* xr4 = (const ushort4*)((const __hip_bfloat16*)xin + srow_ * Dd);
    v0 = f4(xr4[tid]);
    v1 = (tid < 32) ? f4(xr4[256 + tid]) : make_float4(0.f, 0.f, 0.f, 0.f);
  } else {
    const float4* xr4 = (const float4*)((const float*)xin + srow_ * Dd);
    v0 = xr4[tid];
    v1 = (tid < 32) ? xr4[256 + tid] : make_float4(0.f, 0.f, 0.f, 0.f);
  }
  float s = v0.x + v0.y + v0.z + v0.w + v1.x + v1.y + v1.z + v1.w;
  float s2 = v0.x * v0.x + v0.y * v0.y + v0.z * v0.z + v0.w * v0.w +
             v1.x * v1.x + v1.y * v1.y + v1.z * v1.z + v1.w * v1.w;
  #pragma unroll
  for (int m = 1; m < 64; m <<= 1) { s += __shfl_xor(s, m); s2 += __shfl_xor(s2, m); }
  __shared__ float ps[4], ps2[4];
  int wid = tid >> 6, lane = tid & 63;
  if (lane == 0) { ps[wid] = s; ps2[wid] = s2; }
  __syncthreads();
  s = ps[0] + ps[1] + ps[2] + ps[3];
  s2 = ps2[0] + ps2[1] + ps2[2] + ps2[3];
  constexpr float inv_d = 1.0f / Dd;
  float mu = s * inv_d;
  float var = s2 * inv_d - mu * mu;
  float rstd = rsqrtf(var + 1e-6f);
  const float4* gw4 = (const float4*)gw;
  const float4* bw4 = (const float4*)bw;
  ushort4* yr4 = (ushort4*)(yout + (size_t)row * Dd);
  {
    float4 gv = gw4[tid], bv = bw4[tid];
    float4 o = make_float4((v0.x - mu) * rstd * gv.x + bv.x,
                           (v0.y - mu) * rstd * gv.y + bv.y,
                           (v0.z - mu) * rstd * gv.z + bv.z,
                           (v0.w - mu) * rstd * gv.w + bv.w);
    yr4[tid] = bf4(o);
  }
  if (tid < 32) {
    float4 gv = gw4[256 + tid], bv = bw4[256 + tid];
    float4 o = make_float4((v1.x - mu) * rstd * gv.x + bv.x,
                           (v1.y - mu) * rstd * gv.y + bv.y,
                           (v1.z - mu) * rstd * gv.z + bv.z,
                           (v1.w - mu) * rstd * gv.w + bv.w);
    yr4[256 + tid] = bf4(o);
  }
}

// ---------------- fused weight transpose + bf16 cast for all four weights ----------------
__global__ __launch_bounds__(256) void wtrans_all_kernel(
    const float* __restrict__ w0, __hip_bfloat16* __restrict__ o0,
    const float* __restrict__ w1, __hip_bfloat16* __restrict__ o1,
    const float* __restrict__ w2, __hip_bfloat16* __restrict__ o2,
    const float* __restrict__ w3, __hip_bfloat16* __restrict__ o3) {
  __shared__ float tile[32][33];
  int bid = blockIdx.x;
  const float* w; __hip_bfloat16* wT; int K, N, local;
  if (bid < 3888)       { w = w0; wT = o0; K = 1152; N = 3456; local = bid; }
  else if (bid < 5184)  { w = w1; wT = o1; K = 1152; N = 1152; local = bid - 3888; }
  else if (bid < 10368) { w = w2; wT = o2; K = 1152; N = 4608; local = bid - 5184; }
  else                  { w = w3; wT = o3; K = 4608; N = 1152; local = bid - 10368; }
  int nt = N >> 5;
  int tk = local / nt, tn = local % nt;
  int tid = threadIdx.x;
  #pragma unroll
  for (int e = 0; e < 4; ++e) {
    int idx = tid + e * 256;
    int r = idx >> 5, c = idx & 31;
    tile[r][c] = w[(size_t)(tk * 32 + r) * N + tn * 32 + c];
  }
  __syncthreads();
  #pragma unroll
  for (int e = 0; e < 4; ++e) {
    int idx = tid + e * 256;
    int r = idx >> 5, c = idx & 31;
    wT[(size_t)(tn * 32 + r) * K + tk * 32 + c] = __float2bfloat16(tile[c][r]);
  }
}

// ============ GEMM epilogue helper ============
template<int EPI>
__device__ __forceinline__ void epi_store(void* C, const float* res, int Nd,
                                          size_t row, size_t col, float v) {
  if (EPI == 0) {
    ((__hip_bfloat16*)C)[row * (size_t)Nd + col] = __float2bfloat16(v);
  } else if (EPI == 1) {
    ((float*)C)[row * (size_t)Nd + col] = v + res[row * (size_t)Nd + col];
  } else if (EPI == 2) {
    ((__hip_bfloat16*)C)[row * (size_t)Nd + col] = __float2bfloat16(gelu_f(v));
  }
}

// ---------------- GEMM 128x256 lockstep (8 waves, 2 blk/CU) — qkv ----------
// EPI==4: cols < 2304 (Q,K) -> qkvb bf16; cols >= 2304 (V) -> direct transposed vT store.
template<int EPI>
__global__ __launch_bounds__(512, 4) void gemm128_kernel(
    const __hip_bfloat16* __restrict__ A, const __hip_bfloat16* __restrict__ BT,
    const float* __restrict__ bias, const float* __restrict__ res,
    __hip_bfloat16* __restrict__ vTout,
    void* __restrict__ C, int Md, int Nd, int NdPad, int Kd) {
  constexpr int BM = 128;
  __shared__ __align__(16) __hip_bfloat16 As[3][BM * 32];
  __shared__ __align__(16) __hip_bfloat16 Bs[3][256 * 32];
  const int nb = NdPad >> 8;
  const int q8 = gridDim.x >> 3;
  const int wg = (blockIdx.x & 7) * q8 + (blockIdx.x >> 3);
  const int bm = wg / nb, bnb = wg % nb;
  const int tid = threadIdx.x, wid = tid >> 6, lane = tid & 63;
  const int g = lane >> 4, lr = lane & 15;
  const int wm = wid >> 2, wn = wid & 3;
  const size_t m0 = (size_t)bm * BM, n0 = (size_t)bnb * 256;

  const int trow = tid >> 2;
  const int scol = (((tid & 3) ^ ((tid >> 3) & 3)) << 3);
  const char* Ab = (const char*)A;
  const char* Bb = (const char*)BT;

  auto stage = [&](int slot, int kt) {
    const size_t kb = ((size_t)kt << 5) + scol;
    gload_lds16(Ab + (((m0 + trow) * (size_t)Kd + kb) << 1),
                (char*)As + slot * 8192 + wid * 1024);
    gload_lds16(Bb + (((n0 + trow) * (size_t)Kd + kb) << 1),
                (char*)Bs + slot * 16384 + wid * 1024);
    gload_lds16(Bb + (((n0 + 128 + trow) * (size_t)Kd + kb) << 1),
                (char*)Bs + slot * 16384 + 8192 + wid * 1024);
  };

  f32x4 acc[4][4];
  const f32x4 zf = {0.f, 0.f, 0.f, 0.f};
  #pragma unroll
  for (int mi = 0; mi < 4; ++mi)
    #pragma unroll
    for (int ni = 0; ni < 4; ++ni) acc[mi][ni] = zf;

  const int nk = Kd >> 5;
  stage(0, 0);
  stage(1, 1);
  asm volatile("s_waitcnt vmcnt(3)" ::: "memory");
  __builtin_amdgcn_s_barrier();

  int cur = 0;
  const int roff = ((g ^ ((lr >> 1) & 3)) << 3);
  for (int kt = 0; kt < nk; ++kt) {
    const __hip_bfloat16* Ac = As[cur];
    const __hip_bfloat16* Bc = Bs[cur];
    bf16x8 af[4], bf[4];
    #pragma unroll
    for (int mi = 0; mi < 4; ++mi)
      af[mi] = *(const bf16x8*)&Ac[(wm * 64 + mi * 16 + lr) * 32 + roff];
    #pragma unroll
    for (int ni = 0; ni < 4; ++ni)
      bf[ni] = *(const bf16x8*)&Bc[(wn * 64 + ni * 16 + lr) * 32 + roff];
    if (kt + 2 < nk) stage(cur == 0 ? 2 : cur - 1, kt + 2);
    __builtin_amdgcn_s_barrier();
    __builtin_amdgcn_s_setprio(1);
    #pragma unroll
    for (int mi = 0; mi < 4; ++mi)
      #pragma unroll
      for (int ni = 0; ni < 4; ++ni)
        acc[mi][ni] = __builtin_amdgcn_mfma_f32_16x16x32_bf16(af[mi], bf[ni], acc[mi][ni], 0, 0, 0);
    __builtin_amdgcn_s_setprio(0);
    if (kt + 2 < nk)      asm volatile("s_waitcnt vmcnt(3)" ::: "memory");
    else if (kt + 1 < nk) asm volatile("s_waitcnt vmcnt(0)" ::: "memory");
    __builtin_amdgcn_s_barrier();
    cur = (cur == 2) ? 0 : cur + 1;
  }

  #pragma unroll
  for (int ni = 0; ni < 4; ++ni) {
    size_t col = n0 + wn * 64 + ni * 16 + lr;
    if (col < (size_t)Nd) {
      float bv = bias[col];
      if (EPI == 4 && col >= 2304) {
        int vc = (int)col - 2304;
        int h = vc / 72, d = vc % 72;
        #pragma unroll
        for (int mi = 0; mi < 4; ++mi) {
          #pragma unroll
          for (int j = 0; j < 4; ++j) {
            size_t row = m0 + wm * 64 + mi * 16 + g * 4 + j;
            int bb = (int)(row >> 9), t = (int)(row & 511);
            vTout[(((size_t)(bb * 16 + h)) * 80 + d) * 512 + t] =
                __float2bfloat16(acc[mi][ni][j] + bv);
          }
        }
      } else {
        #pragma unroll
        for (int mi = 0; mi < 4; ++mi) {
          #pragma unroll
          for (int j = 0; j < 4; ++j) {
            size_t row = m0 + wm * 64 + mi * 16 + g * 4 + j;
            float v = acc[mi][ni][j] + bv;
            if (EPI == 4) {
              ((__hip_bfloat16*)C)[row * (size_t)Nd + col] = __float2bfloat16(v);
            } else {
              epi_store<EPI>(C, res, Nd, row, col, v);
            }
          }
        }
      }
    }
  }
}

// ---------------- GEMM 128x128, 4 waves, 3 blk/CU, reg-double-buffered overlap ----------
// EPI==3: bf16 out = v + gathered f32 residual (x via keep) [proj -> x2 bf16]
// EPI==5: bf16 out = v + bf16 residual (x2) [fc2 -> yout bf16]
template<int EPI>
__global__ __launch_bounds__(256, 3) void gemm128v_kernel(
    const __hip_bfloat16* __restrict__ A, const __hip_bfloat16* __restrict__ BT,
    const float* __restrict__ bias, const void* __restrict__ res,
    const int* __restrict__ keepIdx, const float* __restrict__ xsrc,
    void* __restrict__ C, int Md, int Nd, int Kd) {
  __shared__ __align__(16) __hip_bfloat16 As[3][128 * 32];
  __shared__ __align__(16) __hip_bfloat16 Bs[3][128 * 32];
  const int nb = Nd >> 7;
  const int q8 = gridDim.x >> 3;
  const int wg = (blockIdx.x & 7) * q8 + (blockIdx.x >> 3);
  const int bm = wg / nb, bnb = wg % nb;
  const int tid = threadIdx.x, wid = tid >> 6, lane = tid & 63;
  const int g = lane >> 4, lr = lane & 15;
  const int wm = wid >> 1, wn = wid & 1;  // wave tile 64x64
  const size_t m0 = (size_t)bm * 128, n0 = (size_t)bnb * 128;

  const int trow = tid >> 2;  // 0..63
  const int scol = (((tid & 3) ^ ((tid >> 3) & 3)) << 3);
  const char* Ab = (const char*)A;
  const char* Bb = (const char*)BT;

  auto stage = [&](int slot, int kt) {
    const size_t kb = ((size_t)kt << 5) + scol;
    #pragma unroll
    for (int c = 0; c < 2; ++c)
      gload_lds16(Ab + (((m0 + c * 64 + trow) * (size_t)Kd + kb) << 1),
                  (char*)As + slot * 8192 + c * 4096 + tid * 16);
    #pragma unroll
    for (int c = 0; c < 2; ++c)
      gload_lds16(Bb + (((n0 + c * 64 + trow) * (size_t)Kd + kb) << 1),
                  (char*)Bs + slot * 8192 + c * 4096 + tid * 16);
  };

  f32x4 acc[4][4];
  const f32x4 zf = {0.f, 0.f, 0.f, 0.f};
  #pragma unroll
  for (int mi = 0; mi < 4; ++mi)
    #pragma unroll
    for (int ni = 0; ni < 4; ++ni) acc[mi][ni] = zf;

  const int roff = ((g ^ ((lr >> 1) & 3)) << 3);
  const int nk = Kd >> 5;

  bf16x8 afA[4], bfA[4], afB[4], bfB[4];

#define DSREAD(AF, BF, SLOT) { \
  const __hip_bfloat16* Ac_ = As[SLOT]; \
  const __hip_bfloat16* Bc_ = Bs[SLOT]; \
  _Pragma("unroll") for (int mi_ = 0; mi_ < 4; ++mi_) \
    AF[mi_] = *(const bf16x8*)&Ac_[(wm * 64 + mi_ * 16 + lr) * 32 + roff]; \
  _Pragma("unroll") for (int ni_ = 0; ni_ < 4; ++ni_) \
    BF[ni_] = *(const bf16x8*)&Bc_[(wn * 64 + ni_ * 16 + lr) * 32 + roff]; }

#define MFMA16(AF, BF) { \
  __builtin_amdgcn_s_setprio(1); \
  _Pragma("unroll") for (int mi_ = 0; mi_ < 4; ++mi_) \
    _Pragma("unroll") for (int ni_ = 0; ni_ < 4; ++ni_) \
      acc[mi_][ni_] = __builtin_amdgcn_mfma_f32_16x16x32_bf16(AF[mi_], BF[ni_], acc[mi_][ni_], 0, 0, 0); \
  __builtin_amdgcn_s_setprio(0); }

#define GITER(KT, S0, S1, AFC, BFC, AFN, BFN) { \
  if ((KT) <= nk - 3)      { asm volatile("s_waitcnt vmcnt(4)" ::: "memory"); } \
  else if ((KT) == nk - 2) { asm volatile("s_waitcnt vmcnt(0)" ::: "memory"); } \
  asm volatile("s_waitcnt lgkmcnt(0)" ::: "memory"); \
  __builtin_amdgcn_s_barrier(); \
  asm volatile("" ::: "memory"); \
  if ((KT) + 1 < nk) DSREAD(AFN, BFN, (S1)); \
  if ((KT) + 3 < nk) stage((S0), (KT) + 3); \
  MFMA16(AFC, BFC); }

  stage(0, 0); stage(1, 1); stage(2, 2);
  asm volatile("s_waitcnt vmcnt(8)" ::: "memory");  // retire stage(0)
  __builtin_amdgcn_s_barrier();
  asm volatile("" ::: "memory");
  DSREAD(afA, bfA, 0);

  int s0 = 0, s1 = 1;
  for (int kt = 0; kt < nk; kt += 2) {
    GITER(kt, s0, s1, afA, bfA, afB, bfB);
    int s2 = (s1 == 2) ? 0 : s1 + 1;
    GITER(kt + 1, s1, s2, afB, bfB, afA, bfA);
    s0 = s2; s1 = (s2 == 2) ? 0 : s2 + 1;
  }
#undef GITER
#undef MFMA16
#undef DSREAD

  #pragma unroll
  for (int ni = 0; ni < 4; ++ni) {
    size_t col = n0 + wn * 64 + ni * 16 + lr;
    float bv = bias[col];
    #pragma unroll
    for (int mi = 0; mi < 4; ++mi) {
      #pragma unroll
      for (int j = 0; j < 4; ++j) {
        size_t row = m0 + wm * 64 + mi * 16 + g * 4 + j;
        float v = acc[mi][ni][j] + bv;
        if (EPI == 3) {
          int b = (int)(row >> 9);
          int tok = keepIdx[row];
          const float* rr = xsrc + ((size_t)(b << 10) + tok) * Dd;
          ((__hip_bfloat16*)C)[row * (size_t)Nd + col] = __float2bfloat16(v + rr[col]);
        } else if (EPI == 5) {
          float rv = __bfloat162float(((const __hip_bfloat16*)res)[row * (size_t)Nd + col]);
          ((__hip_bfloat16*)C)[row * (size_t)Nd + col] = __float2bfloat16(v + rv);
        } else {
          epi_store<EPI>(C, (const float*)res, Nd, row, col, v);
        }
      }
    }
  }
}

// ---------------- flash attention per (b,h,q-PAIR of 64-row tiles) ----------------
__global__ __launch_bounds__(256) void attn_kernel(const __hip_bfloat16* __restrict__ qkv,
    const __hip_bfloat16* __restrict__ vT, __hip_bfloat16* __restrict__ o) {
  const int blk = blockIdx.x;
  const int qp = blk & 3, bh = blk >> 2;  // qp: 128-row pair
  const int b = bh >> 4, h = bh & 15;
  __shared__ __align__(16) __hip_bfloat16 Qs[128][104];
  __shared__ __align__(16) __hip_bfloat16 Ks[64][104];
  __shared__ __align__(16) __hip_bfloat16 Vs[80][72];
  __shared__ __align__(16) __hip_bfloat16 Ps[4][16][72];
  const int tid = threadIdx.x, wid = tid >> 6, lane = tid & 63;
  const int g = lane >> 4, lr = lane & 15;
  const __hip_bfloat16 zb = __float2bfloat16(0.0f);

  for (int idx = tid; idx < 128 * 18; idx += 256) {
    int r = idx / 18, c = idx % 18;
    *(ushort4*)&Qs[r][c * 4] =
        *(const ushort4*)&qkv[((size_t)(b * 512 + qp * 128 + r)) * 3456 + h * 72 + c * 4];
  }
  for (int idx = tid; idx < 128 * 32; idx += 256) {
    int r = idx / 32, d = 72 + idx % 32;
    Qs[r][d] = zb;
    if (r < 64) Ks[r][d] = zb;
  }
  for (int idx = tid; idx < 8 * 72; idx += 256) {
    Vs[72 + idx / 72][idx % 72] = zb;  // pad rows, never re-written
  }

  f32x4 ov0[5], ov1[5];
  const f32x4 zf = {0.f, 0.f, 0.f, 0.f};
  #pragma unroll
  for (int ni = 0; ni < 5; ++ni) { ov0[ni] = zf; ov1[ni] = zf; }
  float m0_[4], l0_[4], m1_[4], l1_[4];
  #pragma unroll
  for (int j = 0; j < 4; ++j) {
    m0_[j] = -3.0e38f; l0_[j] = 0.f;
    m1_[j] = -3.0e38f; l1_[j] = 0.f;
  }
  const float scale = 0.11785113019775793f;  // 1/sqrt(72)

  for (int c = 0; c < 8; ++c) {
    __syncthreads();
    for (int idx = tid; idx < 64 * 18; idx += 256) {
      int r = idx / 18, cc = idx % 18;
      *(ushort4*)&Ks[r][cc * 4] =
          *(const ushort4*)&qkv[((size_t)(b * 512 + c * 64 + r)) * 3456 + 1152 + h * 72 + cc * 4];
    }
    for (int idx = tid; idx < 72 * 8; idx += 256) {
      int d = idx >> 3, t8 = idx & 7;
      *(uint4*)&Vs[d][t8 * 8] =
          *(const uint4*)&vT[((size_t)bh * 80 + d) * 512 + c * 64 + t8 * 8];
    }
    __syncthreads();

    #pragma unroll
    for (int qh = 0; qh < 2; ++qh) {
      float* m_ = qh ? m1_ : m0_;
      float* l_ = qh ? l1_ : l0_;
      f32x4* ov = qh ? ov1 : ov0;

      f32x4 sf[4];
      #pragma unroll
      for (int nf = 0; nf < 4; ++nf) sf[nf] = zf;
      #pragma unroll
      for (int ks = 0; ks < 3; ++ks) {
        bf16x8 qa = *(const bf16x8*)&Qs[qh * 64 + wid * 16 + lr][ks * 32 + g * 8];
        #pragma unroll
        for (int nf = 0; nf < 4; ++nf) {
          bf16x8 kb = *(const bf16x8*)&Ks[nf * 16 + lr][ks * 32 + g * 8];
          sf[nf] = __builtin_amdgcn_mfma_f32_16x16x32_bf16(qa, kb, sf[nf], 0, 0, 0);
        }
      }

      float cm[4];
      #pragma unroll
      for (int j = 0; j < 4; ++j)
        cm[j] = fmaxf(fmaxf(sf[0][j], sf[1][j]), fmaxf(sf[2][j], sf[3][j])) * scale;
      #pragma unroll
      for (int mm = 1; mm < 16; mm <<= 1)
        #pragma unroll
        for (int j = 0; j < 4; ++j) cm[j] = fmaxf(cm[j], __shfl_xor(cm[j], mm));
      float fac[4], rs[4];
      #pragma unroll
      for (int j = 0; j < 4; ++j) {
        float nm = fmaxf(m_[j], cm[j]);
        fac[j] = __expf(m_[j] - nm);
        m_[j] = nm;
        rs[j] = 0.f;
      }
      #pragma unroll
      for (int nf = 0; nf < 4; ++nf)
        #pragma unroll
        for (int j = 0; j < 4; ++j) {
          float pv = __expf(sf[nf][j] * scale - m_[j]);
          rs[j] += pv;
          Ps[wid][g * 4 + j][nf * 16 + lr] = __float2bfloat16(pv);
        }
      #pragma unroll
      for (int mm = 1; mm < 16; mm <<= 1)
        #pragma unroll
        for (int j = 0; j < 4; ++j) rs[j] += __shfl_xor(rs[j], mm);
      #pragma unroll
      for (int j = 0; j < 4; ++j) l_[j] = l_[j] * fac[j] + rs[j];
      #pragma unroll
      for (int ni = 0; ni < 5; ++ni)
        #pragma unroll
        for (int j = 0; j < 4; ++j) ov[ni][j] *= fac[j];

      #pragma unroll
      for (int k2 = 0; k2 < 2; ++k2) {
        bf16x8 pa = *(const bf16x8*)&Ps[wid][lr][k2 * 32 + g * 8];
        #pragma unroll
        for (int ni = 0; ni < 5; ++ni) {
          bf16x8 vb = *(const bf16x8*)&Vs[ni * 16 + lr][k2 * 32 + g * 8];
          ov[ni] = __builtin_amdgcn_mfma_f32_16x16x32_bf16(pa, vb, ov[ni], 0, 0, 0);
        }
      }
    }
  }

  #pragma unroll
  for (int qh = 0; qh < 2; ++qh) {
    const f32x4* ov = qh ? ov1 : ov0;
    const float* l_ = qh ? l1_ : l0_;
    #pragma unroll
    for (int ni = 0; ni < 5; ++ni) {
      int d = ni * 16 + lr;
      if (d < 72) {
        #pragma unroll
        for (int j = 0; j < 4; ++j) {
          int t = qp * 128 + qh * 64 + wid * 16 + g * 4 + j;
          o[((size_t)(b * 512 + t)) * 1152 + h * 72 + d] = __float2bfloat16(ov[ni][j] / l_[j]);
        }
      }
    }
  }
}

// ---------------- final recovery: out[b,n,:] = f32(yout_bf16[b, src_row[b,n], :]) --------
__global__ __launch_bounds__(256) void recover_kernel(
    const __hip_bfloat16* __restrict__ yout, const int* __restrict__ srow,
    float* __restrict__ out) {
  int idx = blockIdx.x * 256 + threadIdx.x;  // over B*N*288 groups of 4
  int q = idx % 288;
  int bnv = idx / 288;  // b*1024+n
  int r = srow[bnv];
  int b = bnv >> 10;
  const ushort4* src = (const ushort4*)(yout + ((size_t)((b << 9) + r)) * Dd) + q;
  ((float4*)out)[idx] = f4(*src);
}

}  // namespace

extern "C" void kernel_launch(void* const* d_in, const int* in_sizes, int n_in,
                              void* d_out, int out_size, void* d_ws, size_t ws_size,
                              hipStream_t stream) {
  (void)in_sizes; (void)n_in; (void)out_size; (void)ws_size;
  const float* x      = (const float*)d_in[0];
  const float* noise  = (const float*)d_in[1];
  const float* ln1_g  = (const float*)d_in[2];
  const float* ln1_b  = (const float*)d_in[3];
  const float* ln2_g  = (const float*)d_in[4];
  const float* ln2_b  = (const float*)d_in[5];
  const float* w_qkv  = (const float*)d_in[6];
  const float* b_qkv  = (const float*)d_in[7];
  const float* w_proj = (const float*)d_in[8];
  const float* b_proj = (const float*)d_in[9];
  const float* w_fc1  = (const float*)d_in[10];
  const float* b_fc1  = (const float*)d_in[11];
  const float* w_fc2  = (const float*)d_in[12];
  const float* b_fc2  = (const float*)d_in[13];
  float* out = (float*)d_out;

  char* p = (char*)d_ws;
  auto alloc = [&](size_t bytes) {
    char* r = p;
    p += (bytes + 255) & ~(size_t)255;
    return r;
  };
  __hip_bfloat16* wqkvT  = (__hip_bfloat16*)alloc((size_t)3584 * 1152 * 2);
  __hip_bfloat16* wprojT = (__hip_bfloat16*)alloc((size_t)1280 * 1152 * 2);
  __hip_bfloat16* wfc1T  = (__hip_bfloat16*)alloc((size_t)4608 * 1152 * 2);
  __hip_bfloat16* wfc2T  = (__hip_bfloat16*)alloc((size_t)1280 * 4608 * 2);
  float* inv = (float*)alloc(16384 * 4);
  int* dsti  = (int*)alloc(4096 * 4);
  int* srci  = (int*)alloc(12288 * 4);
  float* mx  = (float*)alloc(12288 * 4);
  int* best  = (int*)alloc(12288 * 4);
  int* keep  = (int*)alloc(8192 * 4);
  int* srow  = (int*)alloc(16384 * 4);
  __hip_bfloat16* yout = (__hip_bfloat16*)alloc((size_t)8192 * 1152 * 2);
  __hip_bfloat16* y1   = (__hip_bfloat16*)alloc((size_t)8192 * 1152 * 2);  // also y2
  __hip_bfloat16* qkvb = (__hip_bfloat16*)alloc((size_t)8192 * 4608 * 2);  // also h (fc1 out)
  __hip_bfloat16* vT   = (__hip_bfloat16*)alloc((size_t)256 * 80 * 512 * 2);
  __hip_bfloat16* ob   = (__hip_bfloat16*)alloc((size_t)8192 * 1152 * 2);
  __hip_bfloat16* x2   = (__hip_bfloat16*)alloc((size_t)8192 * 1152 * 2);

  // xn hi/lo planes alias qkvb (dead until gemm writes it, exactly 2x 37.75MB)
  __hip_bfloat16* xnh = qkvb;
  __hip_bfloat16* xnl = qkvb + (size_t)16 * 1024 * 1152;

  // weights -> bf16 transposed (single fused launch)
  wtrans_all_kernel<<<15552, 256, 0, stream>>>(w_qkv, wqkvT, w_proj, wprojT,
                                               w_fc1, wfc1T, w_fc2, wfc2T);

  // SiTo indices (norm + window fused)
  normwin_kernel<<<4096, 256, 0, stream>>>(x, noise, inv, xnh, xnl, dsti, srci);
  simgemm_kernel<<<16 * 12, 256, 0, stream>>>(xnh, xnl, dsti, srci, mx, best);
  rank_kernel<<<16, 256, 0, stream>>>(mx, best, dsti, srci, keep, srow);

  // DiT block on kept tokens (residual stream in bf16: proj->x2, fc2->yout)
  ln_kernel<1, 0><<<8192, 256, 0, stream>>>(x, keep, ln1_g, ln1_b, y1);
  gemm128_kernel<4><<<64 * 14, 512, 0, stream>>>(y1, wqkvT, b_qkv, nullptr, vT,
                                                 qkvb, 8192, 3456, 3584, 1152);
  attn_kernel<<<1024, 256, 0, stream>>>(qkvb, vT, ob);
  gemm128v_kernel<3><<<64 * 9, 256, 0, stream>>>(ob, wprojT, b_proj, nullptr, keep, x,
                                                 x2, 8192, 1152, 1152);
  ln_kernel<0, 1><<<8192, 256, 0, stream>>>(x2, nullptr, ln2_g, ln2_b, y1);
  gemm128v_kernel<2><<<64 * 36, 256, 0, stream>>>(y1, wfc1T, b_fc1, nullptr, nullptr, nullptr,
                                                  qkvb, 8192, 4608, 1152);
  gemm128v_kernel<5><<<64 * 9, 256, 0, stream>>>(qkvb, wfc2T, b_fc2, x2, nullptr, nullptr,
                                                 yout, 8192, 1152, 4608);

  // scatter-as-gather recovery (bf16 -> f32)
  recover_kernel<<<18432, 256, 0, stream>>>(yout, srow, out);
}